// Round 1
// baseline (2570.420 us; speedup 1.0000x reference)
//
#include <hip/hip_runtime.h>

// ---------------------------------------------------------------------------
// SNN (SLAYER/Loihi CUBA LIF) forward:
//   conv1(5x5,p1) -> LIF -> d -> pool2x2 -> LIF -> d
//   conv2(3x3,p1) -> LIF -> d -> pool2x2 -> LIF -> d
//   conv3(3x3,p1) -> LIF -> d -> pool2x2 -> LIF -> d
//   fc(288->512)  -> LIF -> d -> fc(512->2) -> LIF -> d  -> out [B,2,T]
// Each stage: per-neuron thread, t-loop inside, reads producer spikes at t-1.
// Spike buffers are uint8 in t-major layout; conv inputs zero-padded.
// ---------------------------------------------------------------------------

#define THETA 5120.0f

__device__ __forceinline__ float dyn_step(float x, float& u, float& v, float& r) {
#pragma clang fp contract(off)
    u = 0.75f * u + 64.0f * x;          // current decay (1024/4096), W_SCALE=64
    float vn = 0.96875f * v + u;        // voltage decay (128/4096)
    vn = (r > 0.0f) ? 0.0f : vn;        // refractory clamp
    float s;
    if (vn >= THETA) { s = 1.0f; v = 0.0f; r = 1.0f; }
    else             { s = 0.0f; v = vn; r = fmaxf(r - 1.0f, 0.0f); }
    return s;
}

// ---------------------------------------------------------------------------
// Pack + transpose: in [B=48,C=4,26,26,T=128] f32 -> xin [t][b][c][28][28] u8
// (interior at +1; borders pre-zeroed by memset). LDS transpose for coalescing.
// ---------------------------------------------------------------------------
__global__ __launch_bounds__(256) void k_pack(const float* __restrict__ in,
                                              unsigned char* __restrict__ xin) {
    __shared__ unsigned char lds[64][132];
    const int tid = threadIdx.x;
    const int lane = tid & 63, w = tid >> 6;
    const int site0 = blockIdx.x * 64;              // 129792 sites total
    // Phase A: read t-contiguous rows (float2 per lane), write LDS [site][t]
    for (int rep = 0; rep < 16; ++rep) {
        int sl = w * 16 + rep;
        const float2* p = (const float2*)(in + (site0 + sl) * 128) + lane;
        float2 f = *p;
        lds[sl][lane * 2]     = (f.x != 0.0f) ? 1 : 0;
        lds[sl][lane * 2 + 1] = (f.y != 0.0f) ? 1 : 0;
    }
    __syncthreads();
    // Phase B: per-lane site, loop t; byte stores are site-contiguous per t.
    int site = site0 + lane;
    int x = site % 26; int r = site / 26;
    int y = r % 26; r /= 26;
    int c = r & 3; int b = r >> 2;
    int obase = (b * 4 + c) * 784 + (y + 1) * 28 + (x + 1);
    for (int rep = 0; rep < 32; ++rep) {
        int t = w * 32 + rep;
        xin[t * 150528 + obase] = lds[lane][t];
    }
}

// ---------------------------------------------------------------------------
// conv1: 4->8 ch, 5x5 pad1, 26->24. One oc per thread (weights in VGPRs).
// threads = 48*8*24*24 = 221184. Input read at t (no delay before conv1).
// ---------------------------------------------------------------------------
__global__ __launch_bounds__(256) void k_conv1(const unsigned char* __restrict__ xin,
                                               const float* __restrict__ w1,
                                               unsigned char* __restrict__ s1) {
    int gid = blockIdx.x * 256 + threadIdx.x;
    int ox = gid % 24; int r = gid / 24;
    int oy = r % 24; r /= 24;
    int oc = r & 7; int b = r >> 3;
    float wr[100];
    const float* wp = w1 + oc * 100;
#pragma unroll
    for (int i = 0; i < 100; ++i) wr[i] = wp[i];
    float u = 0.f, v = 0.f, rf = 0.f;
    const unsigned char* base = xin + b * 3136 + oy * 28 + ox;
    unsigned char* op = s1 + (b * 8 + oc) * 576 + oy * 24 + ox;
    for (int t = 0; t < 128; ++t) {
        const unsigned char* pt = base + t * 150528;
        float acc = 0.f;
#pragma unroll
        for (int c = 0; c < 4; ++c)
#pragma unroll
            for (int ky = 0; ky < 5; ++ky) {
                const unsigned char* prow = pt + c * 784 + ky * 28;
#pragma unroll
                for (int kx = 0; kx < 5; ++kx)
                    acc += wr[c * 25 + ky * 5 + kx] * (float)prow[kx];
            }
        float s = dyn_step(acc, u, v, rf);
        op[t * 221184] = (unsigned char)s;
    }
}

// pool1: 2x2 sum * 88, 24->12, LIF. threads = 48*8*12*12 = 55296.
__global__ __launch_bounds__(256) void k_pool1(const unsigned char* __restrict__ s1,
                                               unsigned char* __restrict__ p1) {
    int gid = blockIdx.x * 256 + threadIdx.x;
    int px = gid % 12; int r = gid / 12;
    int py = r % 12; r /= 12;
    int c = r & 7; int b = r >> 3;
    const unsigned char* base = s1 + (b * 8 + c) * 576 + py * 48 + px * 2;
    unsigned char* op = p1 + (b * 8 + c) * 196 + (py + 1) * 14 + (px + 1);
    float u = 0.f, v = 0.f, rf = 0.f;
    for (int t = 0; t < 128; ++t) {
        float x = 0.f;
        if (t > 0) {
            const unsigned char* p = base + (t - 1) * 221184;
            int cnt = (int)p[0] + (int)p[1] + (int)p[24] + (int)p[25];
            x = 88.0f * (float)cnt;
        }
        float s = dyn_step(x, u, v, rf);
        op[t * 75264] = (unsigned char)s;
    }
}

// conv2: 8->16 ch, 3x3 pad1, 12->12. One oc per thread. threads = 110592.
__global__ __launch_bounds__(256) void k_conv2(const unsigned char* __restrict__ p1,
                                               const float* __restrict__ w2,
                                               unsigned char* __restrict__ s2) {
    int gid = blockIdx.x * 256 + threadIdx.x;
    int ox = gid % 12; int r = gid / 12;
    int oy = r % 12; r /= 12;
    int oc = r & 15; int b = r >> 4;
    float wr[72];
    const float* wp = w2 + oc * 72;
#pragma unroll
    for (int i = 0; i < 72; ++i) wr[i] = wp[i];
    float u = 0.f, v = 0.f, rf = 0.f;
    const unsigned char* base = p1 + b * 1568 + oy * 14 + ox;
    unsigned char* op = s2 + (b * 16 + oc) * 144 + oy * 12 + ox;
    for (int t = 0; t < 128; ++t) {
        float acc = 0.f;
        if (t > 0) {
            const unsigned char* pt = base + (t - 1) * 75264;
#pragma unroll
            for (int ic = 0; ic < 8; ++ic)
#pragma unroll
                for (int ky = 0; ky < 3; ++ky) {
                    const unsigned char* prow = pt + ic * 196 + ky * 14;
#pragma unroll
                    for (int kx = 0; kx < 3; ++kx)
                        acc += wr[ic * 9 + ky * 3 + kx] * (float)prow[kx];
                }
        }
        float s = dyn_step(acc, u, v, rf);
        op[t * 110592] = (unsigned char)s;
    }
}

// pool2: 12->6. threads = 48*16*6*6 = 27648.
__global__ __launch_bounds__(256) void k_pool2(const unsigned char* __restrict__ s2,
                                               unsigned char* __restrict__ p2) {
    int gid = blockIdx.x * 256 + threadIdx.x;
    int px = gid % 6; int r = gid / 6;
    int py = r % 6; r /= 6;
    int c = r & 15; int b = r >> 4;
    const unsigned char* base = s2 + (b * 16 + c) * 144 + py * 24 + px * 2;
    unsigned char* op = p2 + (b * 16 + c) * 64 + (py + 1) * 8 + (px + 1);
    float u = 0.f, v = 0.f, rf = 0.f;
    for (int t = 0; t < 128; ++t) {
        float x = 0.f;
        if (t > 0) {
            const unsigned char* p = base + (t - 1) * 110592;
            int cnt = (int)p[0] + (int)p[1] + (int)p[12] + (int)p[13];
            x = 88.0f * (float)cnt;
        }
        float s = dyn_step(x, u, v, rf);
        op[t * 49152] = (unsigned char)s;
    }
}

// conv3: 16->32 ch, 3x3 pad1, 6->6. K-split by 2 across lane pairs.
// threads = 2 * 48*32*6*6 = 110592.
__global__ __launch_bounds__(256) void k_conv3(const unsigned char* __restrict__ p2,
                                               const float* __restrict__ w3,
                                               unsigned char* __restrict__ s3) {
    int gid = blockIdx.x * 256 + threadIdx.x;
    int kh = gid & 1; int r = gid >> 1;
    int ox = r % 6; r /= 6;
    int oy = r % 6; r /= 6;
    int oc = r & 31; int b = r >> 5;
    float wr[72];
    const float* wp = w3 + oc * 144 + kh * 72;
#pragma unroll
    for (int i = 0; i < 72; ++i) wr[i] = wp[i];
    float u = 0.f, v = 0.f, rf = 0.f;
    const unsigned char* base = p2 + b * 1024 + kh * 512 + oy * 8 + ox;
    unsigned char* op = s3 + (b * 32 + oc) * 36 + oy * 6 + ox;
    for (int t = 0; t < 128; ++t) {
        float acc = 0.f;
        if (t > 0) {
            const unsigned char* pt = base + (t - 1) * 49152;
#pragma unroll
            for (int ic = 0; ic < 8; ++ic)
#pragma unroll
                for (int ky = 0; ky < 3; ++ky) {
                    const unsigned char* prow = pt + ic * 64 + ky * 8;
#pragma unroll
                    for (int kx = 0; kx < 3; ++kx)
                        acc += wr[ic * 9 + ky * 3 + kx] * (float)prow[kx];
                }
        }
        float tot = acc + __shfl_xor(acc, 1, 64);
        float s = dyn_step(tot, u, v, rf);
        if (kh == 0) op[t * 55296] = (unsigned char)s;
    }
}

// pool3: 6->3. threads = 48*32*3*3 = 13824. Output flat [t][b][288].
__global__ __launch_bounds__(256) void k_pool3(const unsigned char* __restrict__ s3,
                                               unsigned char* __restrict__ p3) {
    int gid = blockIdx.x * 256 + threadIdx.x;
    int px = gid % 3; int r = gid / 3;
    int py = r % 3; r /= 3;
    int c = r & 31; int b = r >> 5;
    const unsigned char* base = s3 + (b * 32 + c) * 36 + py * 12 + px * 2;
    unsigned char* op = p3 + b * 288 + c * 9 + py * 3 + px;
    float u = 0.f, v = 0.f, rf = 0.f;
    for (int t = 0; t < 128; ++t) {
        float x = 0.f;
        if (t > 0) {
            const unsigned char* p = base + (t - 1) * 55296;
            int cnt = (int)p[0] + (int)p[1] + (int)p[6] + (int)p[7];
            x = 88.0f * (float)cnt;
        }
        float s = dyn_step(x, u, v, rf);
        op[t * 13824] = (unsigned char)s;
    }
}

// fc1: 288->512. K-split by 4 across lane quads; weights live in VGPRs for
// all 128 steps (no per-t weight refetch). threads = 4 * 48*512 = 98304.
__global__ __launch_bounds__(256) void k_fc1(const unsigned char* __restrict__ p3,
                                             const float* __restrict__ wfc1,
                                             unsigned char* __restrict__ f1) {
    int gid = blockIdx.x * 256 + threadIdx.x;
    int kq = gid & 3; int r = gid >> 2;
    int o = r & 511; int b = r >> 9;
    float wr[72];
    const float* wp = wfc1 + o * 288 + kq * 72;
#pragma unroll
    for (int i = 0; i < 72; ++i) wr[i] = wp[i];
    float u = 0.f, v = 0.f, rf = 0.f;
    unsigned char* op = f1 + b * 512 + o;
    for (int t = 0; t < 128; ++t) {
        float acc = 0.f;
        if (t > 0) {
            const uchar4* sp = (const uchar4*)(p3 + (t - 1) * 13824 + b * 288 + kq * 72);
#pragma unroll
            for (int i = 0; i < 18; ++i) {
                uchar4 c4 = sp[i];
                acc += wr[i * 4 + 0] * (float)c4.x;
                acc += wr[i * 4 + 1] * (float)c4.y;
                acc += wr[i * 4 + 2] * (float)c4.z;
                acc += wr[i * 4 + 3] * (float)c4.w;
            }
        }
        acc += __shfl_xor(acc, 1, 64);
        acc += __shfl_xor(acc, 2, 64);
        float s = dyn_step(acc, u, v, rf);
        if (kq == 0) op[t * 24576] = (unsigned char)s;
    }
}

// fc2: 512->2 + final delay-shift into out [B,2,T]. One wave per (b,o).
__global__ __launch_bounds__(64) void k_fc2(const unsigned char* __restrict__ f1,
                                            const float* __restrict__ wfc2,
                                            float* __restrict__ out) {
    int o = blockIdx.x & 1;
    int b = blockIdx.x >> 1;
    int lane = threadIdx.x;
    float wr[8];
#pragma unroll
    for (int k = 0; k < 8; ++k) wr[k] = wfc2[o * 512 + k * 64 + lane];
    float u = 0.f, v = 0.f, rf = 0.f;
    float* obase = out + (b * 2 + o) * 128;
    if (lane == 0) obase[0] = 0.0f;   // delay_shift zero at t=0
    for (int t = 0; t < 128; ++t) {
        float acc = 0.f;
        if (t > 0) {
            const unsigned char* sp = f1 + (t - 1) * 24576 + b * 512;
#pragma unroll
            for (int k = 0; k < 8; ++k)
                acc += wr[k] * (float)sp[k * 64 + lane];
        }
#pragma unroll
        for (int m = 1; m < 64; m <<= 1) acc += __shfl_xor(acc, m, 64);
        float s = dyn_step(acc, u, v, rf);
        if (lane == 0 && t < 127) obase[t + 1] = s;
    }
}

// ---------------------------------------------------------------------------
extern "C" void kernel_launch(void* const* d_in, const int* in_sizes, int n_in,
                              void* d_out, int out_size, void* d_ws, size_t ws_size,
                              hipStream_t stream) {
    const float* in   = (const float*)d_in[0];
    const float* w1   = (const float*)d_in[1];
    const float* w2   = (const float*)d_in[2];
    const float* w3   = (const float*)d_in[3];
    const float* wfc1 = (const float*)d_in[4];
    const float* wfc2 = (const float*)d_in[5];
    float* out = (float*)d_out;
    char* ws = (char*)d_ws;

    unsigned char* xin = (unsigned char*)(ws);              // 19,267,584
    unsigned char* s1  = (unsigned char*)(ws + 19267584);   // 28,311,552
    unsigned char* p1  = (unsigned char*)(ws + 47579136);   //  9,633,792
    unsigned char* s2  = (unsigned char*)(ws + 57212928);   // 14,155,776
    unsigned char* p2  = (unsigned char*)(ws + 71368704);   //  6,291,456
    unsigned char* s3  = (unsigned char*)(ws + 77660160);   //  7,077,888
    unsigned char* p3  = (unsigned char*)(ws + 84738048);   //  1,769,472
    unsigned char* f1  = (unsigned char*)(ws + 86507520);   //  3,145,728
    // total 89,653,248 bytes

    // zero the padded conv-input buffers (borders must be 0 every launch)
    hipMemsetAsync(xin, 0, 19267584, stream);
    hipMemsetAsync(p1, 0, 9633792, stream);
    hipMemsetAsync(p2, 0, 6291456, stream);

    k_pack <<<2028, 256, 0, stream>>>(in, xin);
    k_conv1<<<864, 256, 0, stream>>>(xin, w1, s1);
    k_pool1<<<216, 256, 0, stream>>>(s1, p1);
    k_conv2<<<432, 256, 0, stream>>>(p1, w2, s2);
    k_pool2<<<108, 256, 0, stream>>>(s2, p2);
    k_conv3<<<432, 256, 0, stream>>>(p2, w3, s3);
    k_pool3<<<54, 256, 0, stream>>>(s3, p3);
    k_fc1  <<<384, 256, 0, stream>>>(p3, wfc1, f1);
    k_fc2  <<<96, 64, 0, stream>>>(f1, wfc2, out);
}

// Round 2
// 965.591 us; speedup vs baseline: 2.6620x; 2.6620x over previous
//
#include <hip/hip_runtime.h>

// ---------------------------------------------------------------------------
// SNN (SLAYER/Loihi CUBA LIF) forward, bitmask edition.
// Spike planes are stored two ways:
//   - bytes  (0/1) for pool consumption + final fc stages
//   - 32-bit row masks (bit x = pixel x in the PADDED image) for conv taps
// Conv tap = bfe + cvt + fmac, weights k-split across lanes so they stay in
// VGPRs (<=36 floats/lane). Each stage loops t internally; producer spikes
// read at t-1 (delay_shift), conv1 reads input at t.
// ---------------------------------------------------------------------------

#define THETA 5120.0f

__device__ __forceinline__ float dyn_step(float x, float& u, float& v, float& r) {
#pragma clang fp contract(off)
    u = 0.75f * u + 64.0f * x;          // current decay (1024/4096), W_SCALE=64
    float vn = 0.96875f * v + u;        // voltage decay (128/4096)
    vn = (r > 0.0f) ? 0.0f : vn;        // refractory clamp
    float s;
    if (vn >= THETA) { s = 1.0f; v = 0.0f; r = 1.0f; }
    else             { s = 0.0f; v = vn; r = fmaxf(r - 1.0f, 0.0f); }
    return s;
}

// ---------------------------------------------------------------------------
// Pack + transpose: in [B=48,C=4,26,26,T=128] f32 -> xin bytes [t][b][c][28][28]
// (interior at +1; borders pre-zeroed by memset). LDS transpose for coalescing.
// ---------------------------------------------------------------------------
__global__ __launch_bounds__(256) void k_pack(const float* __restrict__ in,
                                              unsigned char* __restrict__ xin) {
    __shared__ unsigned char lds[64][132];
    const int tid = threadIdx.x;
    const int lane = tid & 63, w = tid >> 6;
    const int site0 = blockIdx.x * 64;              // 129792 sites total
    for (int rep = 0; rep < 16; ++rep) {
        int sl = w * 16 + rep;
        const float2* p = (const float2*)(in + (site0 + sl) * 128) + lane;
        float2 f = *p;
        lds[sl][lane * 2]     = (f.x != 0.0f) ? 1 : 0;
        lds[sl][lane * 2 + 1] = (f.y != 0.0f) ? 1 : 0;
    }
    __syncthreads();
    int site = site0 + lane;
    int x = site % 26; int r = site / 26;
    int y = r % 26; r /= 26;
    int c = r & 3; int b = r >> 2;
    int obase = (b * 4 + c) * 784 + (y + 1) * 28 + (x + 1);
    for (int rep = 0; rep < 32; ++rep) {
        int t = w * 32 + rep;
        xin[t * 150528 + obase] = lds[lane][t];
    }
}

// ---------------------------------------------------------------------------
// Bytes -> row bitmasks. Input: n images of W*H bytes (each 0/1), contiguous.
// Output: n*H uint32, bit x of row y = byte[y*W+x]. W*H must be mult of 4.
// ---------------------------------------------------------------------------
template<int W, int H>
__global__ __launch_bounds__(256) void k_bits(const unsigned char* __restrict__ in,
                                              unsigned int* __restrict__ out, int n) {
    int g = blockIdx.x * 256 + threadIdx.x;
    if (g >= n) return;
    const unsigned int* p = (const unsigned int*)(in + (size_t)g * (W * H));
    unsigned int m[H];
#pragma unroll
    for (int y = 0; y < H; ++y) m[y] = 0u;
#pragma unroll
    for (int j = 0; j < W * H / 4; ++j) {
        unsigned int cw = p[j];
#pragma unroll
        for (int k = 0; k < 4; ++k) {
            int idx = j * 4 + k;
            m[idx / W] |= ((cw >> (8 * k)) & 1u) << (idx % W);
        }
    }
#pragma unroll
    for (int y = 0; y < H; ++y) out[(size_t)g * H + y] = m[y];
}

// ---------------------------------------------------------------------------
// conv1: 4->8 ch, 5x5 pad1, 26->24. K-split x4: lane kq handles channel kq
// (25 weights in VGPRs). threads = 4 * 48*8*24*24 = 884736.
// Input: xin_bits [t][b*4+c][28] u32 (stride 5376/t).
// ---------------------------------------------------------------------------
__global__ __launch_bounds__(256) void k_conv1(const unsigned int* __restrict__ xb,
                                               const float* __restrict__ w1,
                                               unsigned char* __restrict__ s1) {
    int gid = blockIdx.x * 256 + threadIdx.x;
    int kq = gid & 3; int r = gid >> 2;
    int ox = r % 24; r /= 24;
    int oy = r % 24; r /= 24;
    int oc = r & 7; int b = r >> 3;
    float wr[25];
    const float* wp = w1 + oc * 100 + kq * 25;
#pragma unroll
    for (int i = 0; i < 25; ++i) wr[i] = wp[i];
    float u = 0.f, v = 0.f, rf = 0.f;
    const unsigned int* base = xb + (b * 4 + kq) * 28 + oy;
    unsigned char* op = s1 + (b * 8 + oc) * 576 + oy * 24 + ox;
    for (int t = 0; t < 128; ++t) {
        const unsigned int* pt = base + t * 5376;
        float acc = 0.f;
#pragma unroll
        for (int ky = 0; ky < 5; ++ky) {
            unsigned int m = pt[ky] >> ox;
#pragma unroll
            for (int kx = 0; kx < 5; ++kx)
                acc += wr[ky * 5 + kx] * (float)((m >> kx) & 1u);
        }
        acc += __shfl_xor(acc, 1, 64);
        acc += __shfl_xor(acc, 2, 64);
        float s = dyn_step(acc, u, v, rf);
        if (kq == 0) op[t * 221184] = (unsigned char)s;
    }
}

// pool1: 2x2 sum * 88, 24->12, LIF. threads = 48*8*12*12 = 55296.
__global__ __launch_bounds__(256) void k_pool1(const unsigned char* __restrict__ s1,
                                               unsigned char* __restrict__ p1) {
    int gid = blockIdx.x * 256 + threadIdx.x;
    int px = gid % 12; int r = gid / 12;
    int py = r % 12; r /= 12;
    int c = r & 7; int b = r >> 3;
    const unsigned char* base = s1 + (b * 8 + c) * 576 + py * 48 + px * 2;
    unsigned char* op = p1 + (b * 8 + c) * 196 + (py + 1) * 14 + (px + 1);
    float u = 0.f, v = 0.f, rf = 0.f;
    for (int t = 0; t < 128; ++t) {
        float x = 0.f;
        if (t > 0) {
            const unsigned char* p = base + (t - 1) * 221184;
            int cnt = (int)p[0] + (int)p[1] + (int)p[24] + (int)p[25];
            x = 88.0f * (float)cnt;
        }
        float s = dyn_step(x, u, v, rf);
        op[t * 75264] = (unsigned char)s;
    }
}

// conv2: 8->16 ch, 3x3 pad1, 12->12. K-split x4: lane kq handles input
// channels 2kq,2kq+1 (18 weights). threads = 4 * 48*16*12*12 = 442368.
// Input: p1_bits [t][b*8+c][14] u32 (stride 5376/t).
__global__ __launch_bounds__(256) void k_conv2(const unsigned int* __restrict__ p1b,
                                               const float* __restrict__ w2,
                                               unsigned char* __restrict__ s2) {
    int gid = blockIdx.x * 256 + threadIdx.x;
    int kq = gid & 3; int r = gid >> 2;
    int ox = r % 12; r /= 12;
    int oy = r % 12; r /= 12;
    int oc = r & 15; int b = r >> 4;
    float wr[18];
    const float* wp = w2 + oc * 72 + kq * 18;
#pragma unroll
    for (int i = 0; i < 18; ++i) wr[i] = wp[i];
    float u = 0.f, v = 0.f, rf = 0.f;
    const unsigned int* base = p1b + (b * 8 + kq * 2) * 14 + oy;
    unsigned char* op = s2 + (b * 16 + oc) * 144 + oy * 12 + ox;
    for (int t = 0; t < 128; ++t) {
        float acc = 0.f;
        if (t > 0) {
            const unsigned int* pt = base + (t - 1) * 5376;
#pragma unroll
            for (int c2 = 0; c2 < 2; ++c2)
#pragma unroll
                for (int ky = 0; ky < 3; ++ky) {
                    unsigned int m = pt[c2 * 14 + ky] >> ox;
#pragma unroll
                    for (int kx = 0; kx < 3; ++kx)
                        acc += wr[c2 * 9 + ky * 3 + kx] * (float)((m >> kx) & 1u);
                }
        }
        acc += __shfl_xor(acc, 1, 64);
        acc += __shfl_xor(acc, 2, 64);
        float s = dyn_step(acc, u, v, rf);
        if (kq == 0) op[t * 110592] = (unsigned char)s;
    }
}

// pool2: 12->6. threads = 48*16*6*6 = 27648.
__global__ __launch_bounds__(256) void k_pool2(const unsigned char* __restrict__ s2,
                                               unsigned char* __restrict__ p2) {
    int gid = blockIdx.x * 256 + threadIdx.x;
    int px = gid % 6; int r = gid / 6;
    int py = r % 6; r /= 6;
    int c = r & 15; int b = r >> 4;
    const unsigned char* base = s2 + (b * 16 + c) * 144 + py * 24 + px * 2;
    unsigned char* op = p2 + (b * 16 + c) * 64 + (py + 1) * 8 + (px + 1);
    float u = 0.f, v = 0.f, rf = 0.f;
    for (int t = 0; t < 128; ++t) {
        float x = 0.f;
        if (t > 0) {
            const unsigned char* p = base + (t - 1) * 110592;
            int cnt = (int)p[0] + (int)p[1] + (int)p[12] + (int)p[13];
            x = 88.0f * (float)cnt;
        }
        float s = dyn_step(x, u, v, rf);
        op[t * 49152] = (unsigned char)s;
    }
}

// conv3: 16->32 ch, 3x3 pad1, 6->6. K-split x8: lane kh handles input
// channels 2kh,2kh+1 (18 weights). threads = 8 * 48*32*6*6 = 442368.
// Input: p2_bits [t][b*16+c][8] u32 (stride 6144/t).
__global__ __launch_bounds__(256) void k_conv3(const unsigned int* __restrict__ p2b,
                                               const float* __restrict__ w3,
                                               unsigned char* __restrict__ s3) {
    int gid = blockIdx.x * 256 + threadIdx.x;
    int kh = gid & 7; int r = gid >> 3;
    int ox = r % 6; r /= 6;
    int oy = r % 6; r /= 6;
    int oc = r & 31; int b = r >> 5;
    float wr[18];
    const float* wp = w3 + oc * 144 + kh * 18;
#pragma unroll
    for (int i = 0; i < 18; ++i) wr[i] = wp[i];
    float u = 0.f, v = 0.f, rf = 0.f;
    const unsigned int* base = p2b + (b * 16 + kh * 2) * 8 + oy;
    unsigned char* op = s3 + (b * 32 + oc) * 36 + oy * 6 + ox;
    for (int t = 0; t < 128; ++t) {
        float acc = 0.f;
        if (t > 0) {
            const unsigned int* pt = base + (t - 1) * 6144;
#pragma unroll
            for (int c2 = 0; c2 < 2; ++c2)
#pragma unroll
                for (int ky = 0; ky < 3; ++ky) {
                    unsigned int m = pt[c2 * 8 + ky] >> ox;
#pragma unroll
                    for (int kx = 0; kx < 3; ++kx)
                        acc += wr[c2 * 9 + ky * 3 + kx] * (float)((m >> kx) & 1u);
                }
        }
        acc += __shfl_xor(acc, 1, 64);
        acc += __shfl_xor(acc, 2, 64);
        acc += __shfl_xor(acc, 4, 64);
        float s = dyn_step(acc, u, v, rf);
        if (kh == 0) op[t * 55296] = (unsigned char)s;
    }
}

// pool3: 6->3. threads = 48*32*3*3 = 13824. Output flat [t][b][288] bytes.
__global__ __launch_bounds__(256) void k_pool3(const unsigned char* __restrict__ s3,
                                               unsigned char* __restrict__ p3) {
    int gid = blockIdx.x * 256 + threadIdx.x;
    int px = gid % 3; int r = gid / 3;
    int py = r % 3; r /= 3;
    int c = r & 31; int b = r >> 5;
    const unsigned char* base = s3 + (b * 32 + c) * 36 + py * 12 + px * 2;
    unsigned char* op = p3 + b * 288 + c * 9 + py * 3 + px;
    float u = 0.f, v = 0.f, rf = 0.f;
    for (int t = 0; t < 128; ++t) {
        float x = 0.f;
        if (t > 0) {
            const unsigned char* p = base + (t - 1) * 55296;
            int cnt = (int)p[0] + (int)p[1] + (int)p[6] + (int)p[7];
            x = 88.0f * (float)cnt;
        }
        float s = dyn_step(x, u, v, rf);
        op[t * 13824] = (unsigned char)s;
    }
}

// fc1: 288->512. K-split x8: 36 weights/lane stay in VGPRs for all 128 steps.
// threads = 8 * 48*512 = 196608.
__global__ __launch_bounds__(256) void k_fc1(const unsigned char* __restrict__ p3,
                                             const float* __restrict__ wfc1,
                                             unsigned char* __restrict__ f1) {
    int gid = blockIdx.x * 256 + threadIdx.x;
    int kq = gid & 7; int r = gid >> 3;
    int o = r & 511; int b = r >> 9;
    float wr[36];
    const float* wp = wfc1 + o * 288 + kq * 36;
#pragma unroll
    for (int i = 0; i < 36; ++i) wr[i] = wp[i];
    float u = 0.f, v = 0.f, rf = 0.f;
    unsigned char* op = f1 + b * 512 + o;
    for (int t = 0; t < 128; ++t) {
        float acc = 0.f;
        if (t > 0) {
            const uchar4* sp = (const uchar4*)(p3 + (t - 1) * 13824 + b * 288 + kq * 36);
#pragma unroll
            for (int i = 0; i < 9; ++i) {
                uchar4 c4 = sp[i];
                acc += wr[i * 4 + 0] * (float)c4.x;
                acc += wr[i * 4 + 1] * (float)c4.y;
                acc += wr[i * 4 + 2] * (float)c4.z;
                acc += wr[i * 4 + 3] * (float)c4.w;
            }
        }
        acc += __shfl_xor(acc, 1, 64);
        acc += __shfl_xor(acc, 2, 64);
        acc += __shfl_xor(acc, 4, 64);
        float s = dyn_step(acc, u, v, rf);
        if (kq == 0) op[t * 24576] = (unsigned char)s;
    }
}

// fc2: 512->2 + final delay-shift into out [B,2,T]. One wave per (b,o).
__global__ __launch_bounds__(64) void k_fc2(const unsigned char* __restrict__ f1,
                                            const float* __restrict__ wfc2,
                                            float* __restrict__ out) {
    int o = blockIdx.x & 1;
    int b = blockIdx.x >> 1;
    int lane = threadIdx.x;
    float wr[8];
#pragma unroll
    for (int k = 0; k < 8; ++k) wr[k] = wfc2[o * 512 + k * 64 + lane];
    float u = 0.f, v = 0.f, rf = 0.f;
    float* obase = out + (b * 2 + o) * 128;
    if (lane == 0) obase[0] = 0.0f;   // delay_shift zero at t=0
    for (int t = 0; t < 128; ++t) {
        float acc = 0.f;
        if (t > 0) {
            const unsigned char* sp = f1 + (t - 1) * 24576 + b * 512;
#pragma unroll
            for (int k = 0; k < 8; ++k)
                acc += wr[k] * (float)sp[k * 64 + lane];
        }
#pragma unroll
        for (int m = 1; m < 64; m <<= 1) acc += __shfl_xor(acc, m, 64);
        float s = dyn_step(acc, u, v, rf);
        if (lane == 0 && t < 127) obase[t + 1] = s;
    }
}

// ---------------------------------------------------------------------------
extern "C" void kernel_launch(void* const* d_in, const int* in_sizes, int n_in,
                              void* d_out, int out_size, void* d_ws, size_t ws_size,
                              hipStream_t stream) {
    const float* in   = (const float*)d_in[0];
    const float* w1   = (const float*)d_in[1];
    const float* w2   = (const float*)d_in[2];
    const float* w3   = (const float*)d_in[3];
    const float* wfc1 = (const float*)d_in[4];
    const float* wfc2 = (const float*)d_in[5];
    float* out = (float*)d_out;
    char* ws = (char*)d_ws;

    // Byte buffers (same map as round 1, total 89,653,248 bytes):
    unsigned char* xin = (unsigned char*)(ws);              // 19,267,584 [t][192][28][28]
    unsigned char* s1  = (unsigned char*)(ws + 19267584);   // 28,311,552
    unsigned char* p1  = (unsigned char*)(ws + 47579136);   //  9,633,792 [t][384][14][14]
    unsigned char* s2  = (unsigned char*)(ws + 57212928);   // 14,155,776
    unsigned char* p2  = (unsigned char*)(ws + 71368704);   //  6,291,456 [t][768][8][8]
    unsigned char* s3  = (unsigned char*)(ws + 77660160);   //  7,077,888
    unsigned char* p3  = (unsigned char*)(ws + 84738048);   //  1,769,472 [t][48][288]
    unsigned char* f1  = (unsigned char*)(ws + 86507520);   //  3,145,728 [t][48][512]
    // Bitmask buffers alias dead byte regions (stream-ordered safe):
    unsigned int* xin_b = (unsigned int*)(ws + 86507520);   // 2,752,512 in f1 slot (f1 written later)
    unsigned int* p1_b  = (unsigned int*)(ws);              // 2,752,512 in xin slot (xin dead after k_bits0)
    unsigned int* p2_b  = (unsigned int*)(ws + 2752512);    // 3,145,728 in xin slot

    // zero the padded conv-input byte buffers (borders must be 0 every launch)
    hipMemsetAsync(xin, 0, 19267584, stream);
    hipMemsetAsync(p1, 0, 9633792, stream);
    hipMemsetAsync(p2, 0, 6291456, stream);

    k_pack <<<2028, 256, 0, stream>>>(in, xin);
    k_bits<28,28><<<96, 256, 0, stream>>>(xin, xin_b, 24576);    // 128*192 images
    k_conv1<<<3456, 256, 0, stream>>>(xin_b, w1, s1);
    k_pool1<<<216, 256, 0, stream>>>(s1, p1);
    k_bits<14,14><<<192, 256, 0, stream>>>(p1, p1_b, 49152);     // 128*384 images
    k_conv2<<<1728, 256, 0, stream>>>(p1_b, w2, s2);
    k_pool2<<<108, 256, 0, stream>>>(s2, p2);
    k_bits<8,8><<<384, 256, 0, stream>>>(p2, p2_b, 98304);       // 128*768 images
    k_conv3<<<1728, 256, 0, stream>>>(p2_b, w3, s3);
    k_pool3<<<54, 256, 0, stream>>>(s3, p3);
    k_fc1  <<<768, 256, 0, stream>>>(p3, wfc1, f1);
    k_fc2  <<<96, 64, 0, stream>>>(f1, wfc2, out);
}

// Round 3
// 771.368 us; speedup vs baseline: 3.3323x; 1.2518x over previous
//
#include <hip/hip_runtime.h>

// ---------------------------------------------------------------------------
// SNN (SLAYER/Loihi CUBA LIF) forward, LUT edition.
// Conv stages use per-block LDS lookup tables: a 2-channel row window of
// binary spikes (6 or 10 bits) indexes a precomputed table of weight sums.
// One ds_read replaces ~6-10 tap FMAs. Cross-lane K-split reduction via DPP
// quad_perm adds (VALU pipe, not LDS). Each stage loops t internally;
// producers read at t-1 (delay_shift); conv1 reads input at t.
// ---------------------------------------------------------------------------

#define THETA 5120.0f

__device__ __forceinline__ float dyn_step(float x, float& u, float& v, float& r) {
#pragma clang fp contract(off)
    u = 0.75f * u + 64.0f * x;          // current decay (1024/4096), W_SCALE=64
    float vn = 0.96875f * v + u;        // voltage decay (128/4096)
    vn = (r > 0.0f) ? 0.0f : vn;        // refractory clamp
    float s;
    if (vn >= THETA) { s = 1.0f; v = 0.0f; r = 1.0f; }
    else             { s = 0.0f; v = vn; r = fmaxf(r - 1.0f, 0.0f); }
    return s;
}

// DPP butterfly adds (quad_perm): xor1 = [1,0,3,2] = 0xB1, xor2 = [2,3,0,1] = 0x4E
__device__ __forceinline__ float dpp_add_xor1(float x) {
    int y = __builtin_amdgcn_update_dpp(0, __float_as_int(x), 0xB1, 0xF, 0xF, true);
    return x + __int_as_float(y);
}
__device__ __forceinline__ float dpp_add_xor2(float x) {
    int y = __builtin_amdgcn_update_dpp(0, __float_as_int(x), 0x4E, 0xF, 0xF, true);
    return x + __int_as_float(y);
}

// pack 4 {0,1}-bytes (one u32) into 4 bits (bit k = byte k)
__device__ __forceinline__ unsigned int nib4(unsigned int w) {
    return ((w & 0x01010101u) * 0x01020408u) >> 24;
}

// ---------------------------------------------------------------------------
// Pack + transpose: in [B=48,C=4,26,26,T=128] f32 -> xin bytes [t][b*4+c][28*28]
// (interior at +1; borders pre-zeroed by memset). LDS transpose for coalescing.
// ---------------------------------------------------------------------------
__global__ __launch_bounds__(256) void k_pack(const float* __restrict__ in,
                                              unsigned char* __restrict__ xin) {
    __shared__ unsigned char lds[64][132];
    const int tid = threadIdx.x;
    const int lane = tid & 63, w = tid >> 6;
    const int site0 = blockIdx.x * 64;              // 129792 sites total
    for (int rep = 0; rep < 16; ++rep) {
        int sl = w * 16 + rep;
        const float2* p = (const float2*)(in + (site0 + sl) * 128) + lane;
        float2 f = *p;
        lds[sl][lane * 2]     = (f.x != 0.0f) ? 1 : 0;
        lds[sl][lane * 2 + 1] = (f.y != 0.0f) ? 1 : 0;
    }
    __syncthreads();
    int site = site0 + lane;
    int x = site % 26; int r = site / 26;
    int y = r % 26; r /= 26;
    int c = r & 3; int b = r >> 2;
    int obase = (b * 4 + c) * 784 + (y + 1) * 28 + (x + 1);
    for (int rep = 0; rep < 32; ++rep) {
        int t = w * 32 + rep;
        xin[t * 150528 + obase] = lds[lane][t];
    }
}

// ---------------------------------------------------------------------------
// bits1: xin bytes -> channel-pair row masks. xb[((t*48+b)*2+pr)*28+y] =
// {mask(c=2pr,row y), mask(c=2pr+1,row y)} (28-bit masks). 344064 threads.
// ---------------------------------------------------------------------------
__global__ __launch_bounds__(256) void k_bits1(const unsigned char* __restrict__ xin,
                                               uint2* __restrict__ xb) {
    int g = blockIdx.x * 256 + threadIdx.x;
    int y = g % 28; int r = g / 28;
    int pr = r & 1; r >>= 1;
    int b = r % 48; int t = r / 48;
    const unsigned int* ra = (const unsigned int*)(xin + t * 150528 + (b * 4 + pr * 2) * 784 + y * 28);
    const unsigned int* rb = (const unsigned int*)((const unsigned char*)ra + 784);
    unsigned int ma = 0, mb = 0;
#pragma unroll
    for (int j = 0; j < 7; ++j) {
        ma |= nib4(ra[j]) << (4 * j);
        mb |= nib4(rb[j]) << (4 * j);
    }
    xb[((t * 48 + b) * 2 + pr) * 28 + y] = make_uint2(ma, mb);
}

// ---------------------------------------------------------------------------
// conv1: 4->8 ch, 5x5 pad1, 26->24. LUT: 10-bit (2ch x 5 bits) windows.
// Block 384 = 1/3 of one (b,oc) image; tables 2pr x 5ky x 1025 = 41 KB LDS.
// kq2 split: lane kq handles pair kq. Grid 1152 x 384.
// ---------------------------------------------------------------------------
__global__ __launch_bounds__(384) void k_conv1(const uint2* __restrict__ xb,
                                               const float* __restrict__ w1,
                                               unsigned char* __restrict__ s1) {
    __shared__ float wsh[100];
    __shared__ float tbl[10250];
    int tid = threadIdx.x;
    int img = blockIdx.x / 3;                  // b*8+oc
    int local = (blockIdx.x % 3) * 384 + tid;  // 0..1151
    int b = img >> 3, oc = img & 7;
    if (tid < 100) wsh[tid] = w1[oc * 100 + tid];
    __syncthreads();
    for (int e = tid; e < 10240; e += 384) {
        int pr = e / 5120;
        int ky = (e / 1024) % 5;
        int i = e & 1023;
        float val = 0.f;
#pragma unroll
        for (int k = 0; k < 5; ++k)
            val += ((i >> k) & 1) ? wsh[pr * 50 + ky * 5 + k] : 0.f;
#pragma unroll
        for (int k = 0; k < 5; ++k)
            val += ((i >> (5 + k)) & 1) ? wsh[pr * 50 + 25 + ky * 5 + k] : 0.f;
        tbl[(pr * 5 + ky) * 1025 + i] = val;
    }
    __syncthreads();
    int kq = local & 1;
    int pix = local >> 1;
    int ox = pix % 24, oy = pix / 24;
    const uint2* base = xb + (b * 2 + kq) * 28 + oy;
    int tb = kq * 5 * 1025;
    unsigned char* op = s1 + img * 576 + oy * 24 + ox;
    float u = 0.f, v = 0.f, rf = 0.f;
    for (int t = 0; t < 128; ++t) {
        const uint2* pt = base + t * 2688;
        float acc = 0.f;
#pragma unroll
        for (int ky = 0; ky < 5; ++ky) {
            uint2 rw = pt[ky];
            unsigned int lo = (rw.x >> ox) & 31u;
            unsigned int hi = (rw.y >> ox) & 31u;
            acc += tbl[tb + ky * 1025 + (int)(lo | (hi << 5))];
        }
        acc = dpp_add_xor1(acc);
        float s = dyn_step(acc, u, v, rf);
        if (kq == 0) op[t * 221184] = (unsigned char)s;
    }
}

// pool1: 2x2 sum * 88, 24->12, LIF. Output p1 bytes, padded WIDTH-16 rows:
// [t][b*8+c][14 rows x 16]; interior at (py+1)*16+(px+1). 55296 threads.
__global__ __launch_bounds__(256) void k_pool1(const unsigned char* __restrict__ s1,
                                               unsigned char* __restrict__ p1) {
    int gid = blockIdx.x * 256 + threadIdx.x;
    int px = gid % 12; int r = gid / 12;
    int py = r % 12; r /= 12;
    int c = r & 7; int b = r >> 3;
    const unsigned char* base = s1 + (b * 8 + c) * 576 + py * 48 + px * 2;
    unsigned char* op = p1 + (b * 8 + c) * 224 + (py + 1) * 16 + (px + 1);
    float u = 0.f, v = 0.f, rf = 0.f;
    for (int t = 0; t < 128; ++t) {
        float x = 0.f;
        if (t > 0) {
            const unsigned char* p = base + (t - 1) * 221184;
            int cnt = (int)p[0] + (int)p[1] + (int)p[24] + (int)p[25];
            x = 88.0f * (float)cnt;
        }
        float s = dyn_step(x, u, v, rf);
        op[t * 86016] = (unsigned char)s;
    }
}

// bits2: p1 (width-16 rows) -> pair masks u32 (lo row bits 0..15, hi row
// bits 16..31). pb[((t*48+b)*4+pr)*14+y]. 344064 threads.
__global__ __launch_bounds__(256) void k_bits2(const unsigned char* __restrict__ p1,
                                               unsigned int* __restrict__ pb) {
    int g = blockIdx.x * 256 + threadIdx.x;
    int y = g % 14; int r = g / 14;
    int pr = r & 3; r >>= 2;
    int b = r % 48; int t = r / 48;
    const unsigned int* ra = (const unsigned int*)(p1 + t * 86016 + (b * 8 + pr * 2) * 224 + y * 16);
    const unsigned int* rb = (const unsigned int*)((const unsigned char*)ra + 224);
    unsigned int lo = 0, hi = 0;
#pragma unroll
    for (int j = 0; j < 4; ++j) {
        lo |= nib4(ra[j]) << (4 * j);
        hi |= nib4(rb[j]) << (4 * j);
    }
    pb[((t * 48 + b) * 4 + pr) * 14 + y] = lo | (hi << 16);
}

// conv2: 8->16 ch, 3x3 pad1, 12->12. LUT: 6-bit pair windows; tables
// [2 img][4 pr][3 ky][65]. Block 576 = 2 images. kq2: lane kq = pairs 2kq,2kq+1.
__global__ __launch_bounds__(576) void k_conv2(const unsigned int* __restrict__ pb,
                                               const float* __restrict__ w2,
                                               unsigned char* __restrict__ s2) {
    __shared__ float wsh[144];
    __shared__ float tbl[1560];
    int tid = threadIdx.x;
    int img0 = blockIdx.x * 2;
    if (tid < 144) {
        int oc = (img0 + tid / 72) & 15;
        wsh[tid] = w2[oc * 72 + (tid % 72)];
    }
    __syncthreads();
    for (int e = tid; e < 1536; e += 576) {
        int isel = e / 768;
        int pr = (e / 192) % 4;
        int ky = (e / 64) % 3;
        int i = e & 63;
        float val = 0.f;
#pragma unroll
        for (int k = 0; k < 3; ++k)
            val += ((i >> k) & 1) ? wsh[isel * 72 + (2 * pr) * 9 + ky * 3 + k] : 0.f;
#pragma unroll
        for (int k = 0; k < 3; ++k)
            val += ((i >> (3 + k)) & 1) ? wsh[isel * 72 + (2 * pr + 1) * 9 + ky * 3 + k] : 0.f;
        tbl[((isel * 4 + pr) * 3 + ky) * 65 + i] = val;
    }
    __syncthreads();
    int isel = tid / 288;
    int local = tid % 288;
    int img = img0 + isel;                 // b*16+oc
    int b = img >> 4;
    int kq = local & 1;
    int pix = local >> 1;
    int ox = pix % 12, oy = pix / 12;
    const unsigned int* base = pb + (b * 4 + kq * 2) * 14 + oy;
    int tb = (isel * 4 + kq * 2) * 3 * 65;
    unsigned char* op = s2 + img * 144 + oy * 12 + ox;
    float u = 0.f, v = 0.f, rf = 0.f;
    for (int t = 0; t < 128; ++t) {
        float acc = 0.f;
        if (t > 0) {
            const unsigned int* pt = base + (t - 1) * 2688;
#pragma unroll
            for (int pi = 0; pi < 2; ++pi)
#pragma unroll
                for (int ky = 0; ky < 3; ++ky) {
                    unsigned int m = pt[pi * 14 + ky];
                    unsigned int lo = (m >> ox) & 7u;
                    unsigned int hi = (m >> (16 + ox)) & 7u;
                    acc += tbl[tb + (pi * 3 + ky) * 65 + (int)(lo | (hi << 3))];
                }
        }
        acc = dpp_add_xor1(acc);
        float s = dyn_step(acc, u, v, rf);
        if (kq == 0) op[t * 110592] = (unsigned char)s;
    }
}

// pool2: 12->6. Output p2 bytes [t][b*16+c][8x8] padded (unchanged layout).
__global__ __launch_bounds__(256) void k_pool2(const unsigned char* __restrict__ s2,
                                               unsigned char* __restrict__ p2) {
    int gid = blockIdx.x * 256 + threadIdx.x;
    int px = gid % 6; int r = gid / 6;
    int py = r % 6; r /= 6;
    int c = r & 15; int b = r >> 4;
    const unsigned char* base = s2 + (b * 16 + c) * 144 + py * 24 + px * 2;
    unsigned char* op = p2 + (b * 16 + c) * 64 + (py + 1) * 8 + (px + 1);
    float u = 0.f, v = 0.f, rf = 0.f;
    for (int t = 0; t < 128; ++t) {
        float x = 0.f;
        if (t > 0) {
            const unsigned char* p = base + (t - 1) * 110592;
            int cnt = (int)p[0] + (int)p[1] + (int)p[12] + (int)p[13];
            x = 88.0f * (float)cnt;
        }
        float s = dyn_step(x, u, v, rf);
        op[t * 49152] = (unsigned char)s;
    }
}

// bits3: p2 -> quad masks: u32 = 4 channels' 8-bit rows (ch j at bits 8j).
// pb[((t*48+b)*4+q)*8+y]. 196608 threads.
__global__ __launch_bounds__(256) void k_bits3(const unsigned char* __restrict__ p2,
                                               unsigned int* __restrict__ pb) {
    int g = blockIdx.x * 256 + threadIdx.x;
    int y = g % 8; int r = g / 8;
    int q = r & 3; r >>= 2;
    int b = r % 48; int t = r / 48;
    const unsigned int* rp = (const unsigned int*)(p2 + t * 49152 + (b * 16 + q * 4) * 64 + y * 8);
    unsigned int m = 0;
#pragma unroll
    for (int c = 0; c < 4; ++c) {
        unsigned int byte = nib4(rp[c * 16]) | (nib4(rp[c * 16 + 1]) << 4);
        m |= byte << (8 * c);
    }
    pb[((t * 48 + b) * 4 + q) * 8 + y] = m;
}

// conv3: 16->32 ch, 3x3 pad1, 6->6. LUT 6-bit pair windows; tables
// [4 img][8 pr][3 ky][65] = 25 KB. Block 576 = 4 images. kh4 split: lane kh
// handles quad kh (4 ic, one u32 load -> 2 table reads per ky).
__global__ __launch_bounds__(576) void k_conv3(const unsigned int* __restrict__ pb,
                                               const float* __restrict__ w3,
                                               unsigned char* __restrict__ s3) {
    __shared__ float wsh[576];
    __shared__ float tbl[6240];
    int tid = threadIdx.x;
    int img0 = blockIdx.x * 4;
    {
        int oc = (img0 + tid / 144) & 31;
        wsh[tid] = w3[oc * 144 + (tid % 144)];
    }
    __syncthreads();
    for (int e = tid; e < 6144; e += 576) {
        int il = e / 1536;
        int pr = (e / 192) % 8;
        int ky = (e / 64) % 3;
        int i = e & 63;
        float val = 0.f;
#pragma unroll
        for (int k = 0; k < 3; ++k)
            val += ((i >> k) & 1) ? wsh[il * 144 + (2 * pr) * 9 + ky * 3 + k] : 0.f;
#pragma unroll
        for (int k = 0; k < 3; ++k)
            val += ((i >> (3 + k)) & 1) ? wsh[il * 144 + (2 * pr + 1) * 9 + ky * 3 + k] : 0.f;
        tbl[((il * 8 + pr) * 3 + ky) * 65 + i] = val;
    }
    __syncthreads();
    int isel = tid / 144;
    int local = tid % 144;
    int img = img0 + isel;                 // b*32+oc
    int b = img >> 5;
    int kh = local & 3;
    int pix = local >> 2;
    int ox = pix % 6, oy = pix / 6;
    const unsigned int* base = pb + (b * 4 + kh) * 8 + oy;
    int tb = (isel * 8 + kh * 2) * 3 * 65;
    unsigned char* op = s3 + img * 36 + oy * 6 + ox;
    float u = 0.f, v = 0.f, rf = 0.f;
    for (int t = 0; t < 128; ++t) {
        float acc = 0.f;
        if (t > 0) {
            const unsigned int* pt = base + (t - 1) * 1536;
#pragma unroll
            for (int ky = 0; ky < 3; ++ky) {
                unsigned int m = pt[ky];
                unsigned int a0 = (m >> ox) & 7u;
                unsigned int a1 = (m >> (8 + ox)) & 7u;
                unsigned int b0 = (m >> (16 + ox)) & 7u;
                unsigned int b1 = (m >> (24 + ox)) & 7u;
                acc += tbl[tb + ky * 65 + (int)(a0 | (a1 << 3))];
                acc += tbl[tb + (3 + ky) * 65 + (int)(b0 | (b1 << 3))];
            }
        }
        acc = dpp_add_xor1(acc);
        acc = dpp_add_xor2(acc);
        float s = dyn_step(acc, u, v, rf);
        if (kh == 0) op[t * 55296] = (unsigned char)s;
    }
}

// pool3: 6->3. Output flat [t][b][288] bytes. 13824 threads.
__global__ __launch_bounds__(256) void k_pool3(const unsigned char* __restrict__ s3,
                                               unsigned char* __restrict__ p3) {
    int gid = blockIdx.x * 256 + threadIdx.x;
    int px = gid % 3; int r = gid / 3;
    int py = r % 3; r /= 3;
    int c = r & 31; int b = r >> 5;
    const unsigned char* base = s3 + (b * 32 + c) * 36 + py * 12 + px * 2;
    unsigned char* op = p3 + b * 288 + c * 9 + py * 3 + px;
    float u = 0.f, v = 0.f, rf = 0.f;
    for (int t = 0; t < 128; ++t) {
        float x = 0.f;
        if (t > 0) {
            const unsigned char* p = base + (t - 1) * 55296;
            int cnt = (int)p[0] + (int)p[1] + (int)p[6] + (int)p[7];
            x = 88.0f * (float)cnt;
        }
        float s = dyn_step(x, u, v, rf);
        op[t * 13824] = (unsigned char)s;
    }
}

// fc1: 288->512. K-split x8: 36 weights/lane in VGPRs for all 128 steps.
__global__ __launch_bounds__(256) void k_fc1(const unsigned char* __restrict__ p3,
                                             const float* __restrict__ wfc1,
                                             unsigned char* __restrict__ f1) {
    int gid = blockIdx.x * 256 + threadIdx.x;
    int kq = gid & 7; int r = gid >> 3;
    int o = r & 511; int b = r >> 9;
    float wr[36];
    const float* wp = wfc1 + o * 288 + kq * 36;
#pragma unroll
    for (int i = 0; i < 36; ++i) wr[i] = wp[i];
    float u = 0.f, v = 0.f, rf = 0.f;
    unsigned char* op = f1 + b * 512 + o;
    for (int t = 0; t < 128; ++t) {
        float acc = 0.f;
        if (t > 0) {
            const uchar4* sp = (const uchar4*)(p3 + (t - 1) * 13824 + b * 288 + kq * 36);
#pragma unroll
            for (int i = 0; i < 9; ++i) {
                uchar4 c4 = sp[i];
                acc += wr[i * 4 + 0] * (float)c4.x;
                acc += wr[i * 4 + 1] * (float)c4.y;
                acc += wr[i * 4 + 2] * (float)c4.z;
                acc += wr[i * 4 + 3] * (float)c4.w;
            }
        }
        acc = dpp_add_xor1(acc);
        acc = dpp_add_xor2(acc);
        acc += __shfl_xor(acc, 4, 64);
        float s = dyn_step(acc, u, v, rf);
        if (kq == 0) op[t * 24576] = (unsigned char)s;
    }
}

// fc2: 512->2 + final delay-shift into out [B,2,T]. One wave per (b,o).
__global__ __launch_bounds__(64) void k_fc2(const unsigned char* __restrict__ f1,
                                            const float* __restrict__ wfc2,
                                            float* __restrict__ out) {
    int o = blockIdx.x & 1;
    int b = blockIdx.x >> 1;
    int lane = threadIdx.x;
    float wr[8];
#pragma unroll
    for (int k = 0; k < 8; ++k) wr[k] = wfc2[o * 512 + k * 64 + lane];
    float u = 0.f, v = 0.f, rf = 0.f;
    float* obase = out + (b * 2 + o) * 128;
    if (lane == 0) obase[0] = 0.0f;   // delay_shift zero at t=0
    for (int t = 0; t < 128; ++t) {
        float acc = 0.f;
        if (t > 0) {
            const unsigned char* sp = f1 + (t - 1) * 24576 + b * 512;
#pragma unroll
            for (int k = 0; k < 8; ++k)
                acc += wr[k] * (float)sp[k * 64 + lane];
        }
#pragma unroll
        for (int m = 1; m < 64; m <<= 1) acc += __shfl_xor(acc, m, 64);
        float s = dyn_step(acc, u, v, rf);
        if (lane == 0 && t < 127) obase[t + 1] = s;
    }
}

// ---------------------------------------------------------------------------
extern "C" void kernel_launch(void* const* d_in, const int* in_sizes, int n_in,
                              void* d_out, int out_size, void* d_ws, size_t ws_size,
                              hipStream_t stream) {
    const float* in   = (const float*)d_in[0];
    const float* w1   = (const float*)d_in[1];
    const float* w2   = (const float*)d_in[2];
    const float* w3   = (const float*)d_in[3];
    const float* wfc1 = (const float*)d_in[4];
    const float* wfc2 = (const float*)d_in[5];
    float* out = (float*)d_out;
    char* ws = (char*)d_ws;

    // Byte buffers (round-2 offsets; old p1 slot retired):
    unsigned char* xin = (unsigned char*)(ws);              // 19,267,584 [t][192][784]
    unsigned char* s1  = (unsigned char*)(ws + 19267584);   // 28,311,552
    unsigned char* s2  = (unsigned char*)(ws + 57212928);   // 14,155,776
    unsigned char* p2  = (unsigned char*)(ws + 71368704);   //  6,291,456
    unsigned char* s3  = (unsigned char*)(ws + 77660160);   //  7,077,888
    unsigned char* p3  = (unsigned char*)(ws + 84738048);   //  1,769,472
    unsigned char* f1  = (unsigned char*)(ws + 86507520);   //  3,145,728
    // Aliased regions (stream-ordered lifetime-safe):
    uint2*        xb1 = (uint2*)(ws + 86507520);            // 2,752,512 in f1 slot (fc1 runs later)
    unsigned char* p1  = (unsigned char*)(ws);              // 11,010,048 in xin slot (xin dead after bits1)
    unsigned int* p1b = (unsigned int*)(ws + 11010048);     // 1,376,256 in xin slot
    unsigned int* p2b = (unsigned int*)(ws + 12386304);     //   786,432 in xin slot

    hipMemsetAsync(xin, 0, 19267584, stream);   // conv1 input borders
    hipMemsetAsync(p2, 0, 6291456, stream);     // conv3 input borders

    k_pack <<<2028, 256, 0, stream>>>(in, xin);
    k_bits1<<<1344, 256, 0, stream>>>(xin, xb1);
    hipMemsetAsync(ws, 0, 11010048, stream);    // p1 zero (xin bytes dead now)
    k_conv1<<<1152, 384, 0, stream>>>(xb1, w1, s1);
    k_pool1<<<216, 256, 0, stream>>>(s1, p1);
    k_bits2<<<1344, 256, 0, stream>>>(p1, p1b);
    k_conv2<<<384, 576, 0, stream>>>(p1b, w2, s2);
    k_pool2<<<108, 256, 0, stream>>>(s2, p2);
    k_bits3<<<768, 256, 0, stream>>>(p2, p2b);
    k_conv3<<<384, 576, 0, stream>>>(p2b, w3, s3);
    k_pool3<<<54, 256, 0, stream>>>(s3, p3);
    k_fc1  <<<768, 256, 0, stream>>>(p3, wfc1, f1);
    k_fc2  <<<96, 64, 0, stream>>>(f1, wfc2, out);
}

// Round 4
// 761.639 us; speedup vs baseline: 3.3749x; 1.0128x over previous
//
#include <hip/hip_runtime.h>

// ---------------------------------------------------------------------------
// SNN (SLAYER/Loihi CUBA LIF) forward, LUT edition v2.
// Conv stages use per-block LDS lookup tables indexed by binary spike windows.
// Bank-conflict fix: entry (hi,lo) stored at lo + S*hi with S=33 (conv1) or
// S=9 (conv2/3) so bank = lo+hi mod 32 -> common single-spike windows spread.
// Pool kernels emit row bitmasks directly via __ballot (bits2/bits3 removed).
// Each stage loops t internally; producers read at t-1 (delay_shift).
// ---------------------------------------------------------------------------

#define THETA 5120.0f

__device__ __forceinline__ float dyn_step(float x, float& u, float& v, float& r) {
#pragma clang fp contract(off)
    u = 0.75f * u + 64.0f * x;          // current decay (1024/4096), W_SCALE=64
    float vn = 0.96875f * v + u;        // voltage decay (128/4096)
    vn = (r > 0.0f) ? 0.0f : vn;        // refractory clamp
    float s;
    if (vn >= THETA) { s = 1.0f; v = 0.0f; r = 1.0f; }
    else             { s = 0.0f; v = vn; r = fmaxf(r - 1.0f, 0.0f); }
    return s;
}

// DPP butterfly adds (quad_perm): xor1 = 0xB1, xor2 = 0x4E
__device__ __forceinline__ float dpp_add_xor1(float x) {
    int y = __builtin_amdgcn_update_dpp(0, __float_as_int(x), 0xB1, 0xF, 0xF, true);
    return x + __int_as_float(y);
}
__device__ __forceinline__ float dpp_add_xor2(float x) {
    int y = __builtin_amdgcn_update_dpp(0, __float_as_int(x), 0x4E, 0xF, 0xF, true);
    return x + __int_as_float(y);
}

// pack 4 {0,1}-bytes (one u32) into 4 bits (bit k = byte k)
__device__ __forceinline__ unsigned int nib4(unsigned int w) {
    return ((w & 0x01010101u) * 0x01020408u) >> 24;
}

// ---------------------------------------------------------------------------
// Pack + transpose: in [B=48,C=4,26,26,T=128] f32 -> xin bytes [t][b*4+c][784]
// (interior at +1; borders pre-zeroed by memset). LDS transpose for coalescing.
// ---------------------------------------------------------------------------
__global__ __launch_bounds__(256) void k_pack(const float* __restrict__ in,
                                              unsigned char* __restrict__ xin) {
    __shared__ unsigned char lds[64][132];
    const int tid = threadIdx.x;
    const int lane = tid & 63, w = tid >> 6;
    const int site0 = blockIdx.x * 64;              // 129792 sites total
    for (int rep = 0; rep < 16; ++rep) {
        int sl = w * 16 + rep;
        const float2* p = (const float2*)(in + (site0 + sl) * 128) + lane;
        float2 f = *p;
        lds[sl][lane * 2]     = (f.x != 0.0f) ? 1 : 0;
        lds[sl][lane * 2 + 1] = (f.y != 0.0f) ? 1 : 0;
    }
    __syncthreads();
    int site = site0 + lane;
    int x = site % 26; int r = site / 26;
    int y = r % 26; r /= 26;
    int c = r & 3; int b = r >> 2;
    int obase = (b * 4 + c) * 784 + (y + 1) * 28 + (x + 1);
    for (int rep = 0; rep < 32; ++rep) {
        int t = w * 32 + rep;
        xin[t * 150528 + obase] = lds[lane][t];
    }
}

// bits1: xin bytes -> channel-pair row masks. xb[((t*48+b)*2+pr)*28+y] =
// {mask(c=2pr,row y), mask(c=2pr+1,row y)} (28-bit masks). 344064 threads.
__global__ __launch_bounds__(256) void k_bits1(const unsigned char* __restrict__ xin,
                                               uint2* __restrict__ xb) {
    int g = blockIdx.x * 256 + threadIdx.x;
    int y = g % 28; int r = g / 28;
    int pr = r & 1; r >>= 1;
    int b = r % 48; int t = r / 48;
    const unsigned int* ra = (const unsigned int*)(xin + t * 150528 + (b * 4 + pr * 2) * 784 + y * 28);
    const unsigned int* rb = (const unsigned int*)((const unsigned char*)ra + 784);
    unsigned int ma = 0, mb = 0;
#pragma unroll
    for (int j = 0; j < 7; ++j) {
        ma |= nib4(ra[j]) << (4 * j);
        mb |= nib4(rb[j]) << (4 * j);
    }
    xb[((t * 48 + b) * 2 + pr) * 28 + y] = make_uint2(ma, mb);
}

// ---------------------------------------------------------------------------
// conv1: 4->8 ch, 5x5 pad1, 26->24. LUT: 10-bit (2ch x 5 bits) windows stored
// bank-spread at lo + 33*hi (stride 1055/ky). Block 384 = 1/3 of one (b,oc)
// image; tables 2pr x 5ky x 1055 = 42.2 KB LDS. kq2: lane kq handles pair kq.
// ---------------------------------------------------------------------------
__global__ __launch_bounds__(384) void k_conv1(const uint2* __restrict__ xb,
                                               const float* __restrict__ w1,
                                               unsigned char* __restrict__ s1) {
    __shared__ float wsh[100];
    __shared__ float tbl[10550];
    int tid = threadIdx.x;
    int img = blockIdx.x / 3;                  // b*8+oc
    int local = (blockIdx.x % 3) * 384 + tid;  // 0..1151
    int b = img >> 3, oc = img & 7;
    if (tid < 100) wsh[tid] = w1[oc * 100 + tid];
    __syncthreads();
    for (int e = tid; e < 10240; e += 384) {
        int pr = e / 5120;
        int ky = (e / 1024) % 5;
        int i = e & 1023;
        int lo = i & 31, hi = i >> 5;
        float val = 0.f;
#pragma unroll
        for (int k = 0; k < 5; ++k)
            val += ((lo >> k) & 1) ? wsh[pr * 50 + ky * 5 + k] : 0.f;
#pragma unroll
        for (int k = 0; k < 5; ++k)
            val += ((hi >> k) & 1) ? wsh[pr * 50 + 25 + ky * 5 + k] : 0.f;
        tbl[(pr * 5 + ky) * 1055 + lo + 33 * hi] = val;
    }
    __syncthreads();
    int kq = local & 1;
    int pix = local >> 1;
    int ox = pix % 24, oy = pix / 24;
    const uint2* base = xb + (b * 2 + kq) * 28 + oy;
    int tb = kq * 5275;
    unsigned char* op = s1 + img * 576 + oy * 24 + ox;
    float u = 0.f, v = 0.f, rf = 0.f;
    for (int t = 0; t < 128; ++t) {
        const uint2* pt = base + t * 2688;
        float acc = 0.f;
#pragma unroll
        for (int ky = 0; ky < 5; ++ky) {
            uint2 rw = pt[ky];
            unsigned int lo = (rw.x >> ox) & 31u;
            unsigned int hi = (rw.y >> ox) & 31u;
            acc += tbl[tb + ky * 1055 + (int)(lo + 33u * hi)];
        }
        acc = dpp_add_xor1(acc);
        float s = dyn_step(acc, u, v, rf);
        if (kq == 0) op[t * 221184] = (unsigned char)s;
    }
}

// ---------------------------------------------------------------------------
// pool1 + mask emit: 2x2 sum * 88, 24->12, LIF, then __ballot -> u16 row masks.
// Wave = 4 rows x 16 lanes (px 12..15 idle). pb16[t][b][14 y][8 c] u16,
// interior rows at y+1 (pad rows pre-zeroed by memset). 1152 waves.
// ---------------------------------------------------------------------------
__global__ __launch_bounds__(256) void k_pool1(const unsigned char* __restrict__ s1,
                                               unsigned short* __restrict__ pb16) {
    int wv = blockIdx.x * 4 + (threadIdx.x >> 6);
    int lane = threadIdx.x & 63;
    int rg = wv % 3; int r = wv / 3;
    int c = r & 7; int b = r >> 3;
    int px = lane & 15;
    int py = rg * 4 + (lane >> 4);
    int pxc = (px < 12) ? px : 11;
    const unsigned char* base = s1 + (b * 8 + c) * 576 + py * 48 + pxc * 2;
    float u = 0.f, v = 0.f, rf = 0.f;
    int g = lane >> 4;
    unsigned short* wp = pb16 + ((0 * 48 + b) * 14 + py + 1) * 8 + c;
    for (int t = 0; t < 128; ++t) {
        float x = 0.f;
        if (t > 0) {
            const unsigned char* p = base + (t - 1) * 221184;
            int cnt = (int)p[0] + (int)p[1] + (int)p[24] + (int)p[25];
            x = (px < 12) ? 88.0f * (float)cnt : 0.0f;
        }
        float s = dyn_step(x, u, v, rf);
        unsigned long long bal = __ballot(s > 0.5f);
        if ((lane & 15) == 0)
            wp[t * 5376] = (unsigned short)((bal >> (16 * g)) & 0xFFFu);
    }
}

// ---------------------------------------------------------------------------
// conv2: 8->16 ch, 3x3 pad1, 12->12. LUT 6-bit pair windows at lo + 9*hi
// (stride 71). Tables [2 img][4 pr][3 ky][71]. Block 576 = 2 images.
// kq2: lane kq handles pairs 2kq, 2kq+1. Input: pb16 u16 rows.
// ---------------------------------------------------------------------------
__global__ __launch_bounds__(576) void k_conv2(const unsigned int* __restrict__ pbu,
                                               const float* __restrict__ w2,
                                               unsigned char* __restrict__ s2) {
    __shared__ float wsh[144];
    __shared__ float tbl[1704];
    int tid = threadIdx.x;
    int img0 = blockIdx.x * 2;
    if (tid < 144) {
        int oc = (img0 + tid / 72) & 15;
        wsh[tid] = w2[oc * 72 + (tid % 72)];
    }
    __syncthreads();
    for (int e = tid; e < 1536; e += 576) {
        int isel = e / 768;
        int pr = (e / 192) % 4;
        int ky = (e / 64) % 3;
        int i = e & 63;
        int lo = i & 7, hi = i >> 3;
        float val = 0.f;
#pragma unroll
        for (int k = 0; k < 3; ++k)
            val += ((lo >> k) & 1) ? wsh[isel * 72 + (2 * pr) * 9 + ky * 3 + k] : 0.f;
#pragma unroll
        for (int k = 0; k < 3; ++k)
            val += ((hi >> k) & 1) ? wsh[isel * 72 + (2 * pr + 1) * 9 + ky * 3 + k] : 0.f;
        tbl[((isel * 4 + pr) * 3 + ky) * 71 + lo + 9 * hi] = val;
    }
    __syncthreads();
    int isel = tid / 288;
    int local = tid % 288;
    int img = img0 + isel;                 // b*16+oc
    int b = img >> 4;
    int kq = local & 1;
    int pix = local >> 1;
    int ox = pix % 12, oy = pix / 12;
    // pbu: u32 view of pb16: [t][b][14 y][4 u32]; pair pr at word pr.
    const unsigned int* base = pbu + (b * 14 + oy) * 4;
    int tb = (isel * 4 + kq * 2) * 213;    // 3*71
    unsigned char* op = s2 + img * 144 + oy * 12 + ox;
    float u = 0.f, v = 0.f, rf = 0.f;
    for (int t = 0; t < 128; ++t) {
        float acc = 0.f;
        if (t > 0) {
            const unsigned int* pt = base + (t - 1) * 2688;   // 48*14*4
#pragma unroll
            for (int pi = 0; pi < 2; ++pi) {
                int pr = kq * 2 + pi;
#pragma unroll
                for (int ky = 0; ky < 3; ++ky) {
                    unsigned int m = pt[ky * 4 + pr];
                    unsigned int ml = (m & 0xFFFFu) << 1;
                    unsigned int mh = (m >> 16) << 1;
                    unsigned int lo = (ml >> ox) & 7u;
                    unsigned int hi = (mh >> ox) & 7u;
                    acc += tbl[tb + (pi * 3 + ky) * 71 + (int)(lo + 9u * hi)];
                }
            }
        }
        acc = dpp_add_xor1(acc);
        float s = dyn_step(acc, u, v, rf);
        if (kq == 0) op[t * 110592] = (unsigned char)s;
    }
}

// ---------------------------------------------------------------------------
// pool2 + mask emit: 12->6, LIF, ballot -> u16 row masks.
// Wave = one (b,c) image: lane = px + 8*py (px>=6 or py>=6 idle).
// pb2[t][b][8 y][16 c] u16, interior rows at y+1. 768 waves.
// ---------------------------------------------------------------------------
__global__ __launch_bounds__(256) void k_pool2(const unsigned char* __restrict__ s2,
                                               unsigned short* __restrict__ pb2) {
    int wv = blockIdx.x * 4 + (threadIdx.x >> 6);
    int lane = threadIdx.x & 63;
    int c = wv & 15; int b = wv >> 4;
    int px = lane & 7, py = lane >> 3;
    int active = (px < 6) && (py < 6);
    int pxc = (px < 6) ? px : 5;
    int pyc = (py < 6) ? py : 5;
    const unsigned char* base = s2 + (b * 16 + c) * 144 + pyc * 24 + pxc * 2;
    float u = 0.f, v = 0.f, rf = 0.f;
    unsigned short* wp = pb2 + ((0 * 48 + b) * 8 + py + 1) * 16 + c;
    for (int t = 0; t < 128; ++t) {
        float x = 0.f;
        if (t > 0) {
            const unsigned char* p = base + (t - 1) * 110592;
            int cnt = (int)p[0] + (int)p[1] + (int)p[12] + (int)p[13];
            x = active ? 88.0f * (float)cnt : 0.0f;
        }
        float s = dyn_step(x, u, v, rf);
        unsigned long long bal = __ballot(s > 0.5f);
        if ((lane & 7) == 0 && py < 6)
            wp[t * 6144] = (unsigned short)((bal >> (8 * py)) & 0x3Fu);
    }
}

// ---------------------------------------------------------------------------
// conv3: 16->32 ch, 3x3 pad1, 6->6. LUT 6-bit pair windows at lo + 9*hi
// (stride 71). Tables [4 img][8 pr][3 ky][71] = 27.3 KB. Block 576 = 4 images.
// kh4: lane kh handles ic quad 4kh..4kh+3 (one uint2 load per ky).
// ---------------------------------------------------------------------------
__global__ __launch_bounds__(576) void k_conv3(const uint2* __restrict__ pbu,
                                               const float* __restrict__ w3,
                                               unsigned char* __restrict__ s3) {
    __shared__ float wsh[576];
    __shared__ float tbl[6816];
    int tid = threadIdx.x;
    int img0 = blockIdx.x * 4;
    {
        int oc = (img0 + tid / 144) & 31;
        wsh[tid] = w3[oc * 144 + (tid % 144)];
    }
    __syncthreads();
    for (int e = tid; e < 6144; e += 576) {
        int il = e / 1536;
        int pr = (e / 192) % 8;
        int ky = (e / 64) % 3;
        int i = e & 63;
        int lo = i & 7, hi = i >> 3;
        float val = 0.f;
#pragma unroll
        for (int k = 0; k < 3; ++k)
            val += ((lo >> k) & 1) ? wsh[il * 144 + (2 * pr) * 9 + ky * 3 + k] : 0.f;
#pragma unroll
        for (int k = 0; k < 3; ++k)
            val += ((hi >> k) & 1) ? wsh[il * 144 + (2 * pr + 1) * 9 + ky * 3 + k] : 0.f;
        tbl[((il * 8 + pr) * 3 + ky) * 71 + lo + 9 * hi] = val;
    }
    __syncthreads();
    int isel = tid / 144;
    int local = tid % 144;
    int img = img0 + isel;                 // b*32+oc
    int b = img >> 5;
    int kh = local & 3;
    int pix = local >> 2;
    int ox = pix % 6, oy = pix / 6;
    // pbu: uint2 view of pb2: [t][b][8 y][8 u32]; quad kh at uint2 index kh.
    const uint2* base = pbu + (b * 8 + oy) * 4;
    int tb = (isel * 8 + kh * 2) * 213;    // 3*71
    unsigned char* op = s3 + img * 36 + oy * 6 + ox;
    float u = 0.f, v = 0.f, rf = 0.f;
    for (int t = 0; t < 128; ++t) {
        float acc = 0.f;
        if (t > 0) {
            const uint2* pt = base + (t - 1) * 1536;   // 48*8*4
#pragma unroll
            for (int ky = 0; ky < 3; ++ky) {
                uint2 d = pt[ky * 4 + kh];
                unsigned int a0 = ((d.x & 0xFFFFu) << 1) >> ox;
                unsigned int a1 = ((d.x >> 16) << 1) >> ox;
                unsigned int b0 = ((d.y & 0xFFFFu) << 1) >> ox;
                unsigned int b1 = ((d.y >> 16) << 1) >> ox;
                acc += tbl[tb + ky * 71 + (int)((a0 & 7u) + 9u * (a1 & 7u))];
                acc += tbl[tb + 213 + ky * 71 + (int)((b0 & 7u) + 9u * (b1 & 7u))];
            }
        }
        acc = dpp_add_xor1(acc);
        acc = dpp_add_xor2(acc);
        float s = dyn_step(acc, u, v, rf);
        if (kh == 0) op[t * 55296] = (unsigned char)s;
    }
}

// pool3: 6->3. Output flat [t][b][288] bytes. 13824 threads.
__global__ __launch_bounds__(256) void k_pool3(const unsigned char* __restrict__ s3,
                                               unsigned char* __restrict__ p3) {
    int gid = blockIdx.x * 256 + threadIdx.x;
    int px = gid % 3; int r = gid / 3;
    int py = r % 3; r /= 3;
    int c = r & 31; int b = r >> 5;
    const unsigned char* base = s3 + (b * 32 + c) * 36 + py * 12 + px * 2;
    unsigned char* op = p3 + b * 288 + c * 9 + py * 3 + px;
    float u = 0.f, v = 0.f, rf = 0.f;
    for (int t = 0; t < 128; ++t) {
        float x = 0.f;
        if (t > 0) {
            const unsigned char* p = base + (t - 1) * 55296;
            int cnt = (int)p[0] + (int)p[1] + (int)p[6] + (int)p[7];
            x = 88.0f * (float)cnt;
        }
        float s = dyn_step(x, u, v, rf);
        op[t * 13824] = (unsigned char)s;
    }
}

// fc1: 288->512. K-split x8: 36 weights/lane in VGPRs for all 128 steps.
__global__ __launch_bounds__(256) void k_fc1(const unsigned char* __restrict__ p3,
                                             const float* __restrict__ wfc1,
                                             unsigned char* __restrict__ f1) {
    int gid = blockIdx.x * 256 + threadIdx.x;
    int kq = gid & 7; int r = gid >> 3;
    int o = r & 511; int b = r >> 9;
    float wr[36];
    const float* wp = wfc1 + o * 288 + kq * 36;
#pragma unroll
    for (int i = 0; i < 36; ++i) wr[i] = wp[i];
    float u = 0.f, v = 0.f, rf = 0.f;
    unsigned char* op = f1 + b * 512 + o;
    for (int t = 0; t < 128; ++t) {
        float acc = 0.f;
        if (t > 0) {
            const uchar4* sp = (const uchar4*)(p3 + (t - 1) * 13824 + b * 288 + kq * 36);
#pragma unroll
            for (int i = 0; i < 9; ++i) {
                uchar4 c4 = sp[i];
                acc += wr[i * 4 + 0] * (float)c4.x;
                acc += wr[i * 4 + 1] * (float)c4.y;
                acc += wr[i * 4 + 2] * (float)c4.z;
                acc += wr[i * 4 + 3] * (float)c4.w;
            }
        }
        acc = dpp_add_xor1(acc);
        acc = dpp_add_xor2(acc);
        acc += __shfl_xor(acc, 4, 64);
        float s = dyn_step(acc, u, v, rf);
        if (kq == 0) op[t * 24576] = (unsigned char)s;
    }
}

// fc2: 512->2 + final delay-shift into out [B,2,T]. One wave per (b,o).
__global__ __launch_bounds__(64) void k_fc2(const unsigned char* __restrict__ f1,
                                            const float* __restrict__ wfc2,
                                            float* __restrict__ out) {
    int o = blockIdx.x & 1;
    int b = blockIdx.x >> 1;
    int lane = threadIdx.x;
    float wr[8];
#pragma unroll
    for (int k = 0; k < 8; ++k) wr[k] = wfc2[o * 512 + k * 64 + lane];
    float u = 0.f, v = 0.f, rf = 0.f;
    float* obase = out + (b * 2 + o) * 128;
    if (lane == 0) obase[0] = 0.0f;   // delay_shift zero at t=0
    for (int t = 0; t < 128; ++t) {
        float acc = 0.f;
        if (t > 0) {
            const unsigned char* sp = f1 + (t - 1) * 24576 + b * 512;
#pragma unroll
            for (int k = 0; k < 8; ++k)
                acc += wr[k] * (float)sp[k * 64 + lane];
        }
#pragma unroll
        for (int m = 1; m < 64; m <<= 1) acc += __shfl_xor(acc, m, 64);
        float s = dyn_step(acc, u, v, rf);
        if (lane == 0 && t < 127) obase[t + 1] = s;
    }
}

// ---------------------------------------------------------------------------
extern "C" void kernel_launch(void* const* d_in, const int* in_sizes, int n_in,
                              void* d_out, int out_size, void* d_ws, size_t ws_size,
                              hipStream_t stream) {
    const float* in   = (const float*)d_in[0];
    const float* w1   = (const float*)d_in[1];
    const float* w2   = (const float*)d_in[2];
    const float* w3   = (const float*)d_in[3];
    const float* wfc1 = (const float*)d_in[4];
    const float* wfc2 = (const float*)d_in[5];
    float* out = (float*)d_out;
    char* ws = (char*)d_ws;

    unsigned char* xin   = (unsigned char*)(ws);             // 19,267,584 [t][192][784]
    unsigned char* s1    = (unsigned char*)(ws + 19267584);  // 28,311,552
    unsigned short* pb16 = (unsigned short*)(ws + 47579136); //  1,376,256 [t][48][14][8] u16
    unsigned char* s2    = (unsigned char*)(ws + 57212928);  // 14,155,776
    unsigned short* pb2  = (unsigned short*)(ws + 71368704); //  1,572,864 [t][48][8][16] u16
    unsigned char* s3    = (unsigned char*)(ws + 77660160);  //  7,077,888
    unsigned char* p3    = (unsigned char*)(ws + 84738048);  //  1,769,472 [t][48][288]
    unsigned char* f1    = (unsigned char*)(ws + 86507520);  //  3,145,728 [t][48][512]
    uint2*         xb1   = (uint2*)(ws + 86507520);          //  2,752,512 in f1 slot (fc1 later)

    hipMemsetAsync(xin, 0, 19267584, stream);   // conv1 input borders
    hipMemsetAsync(pb16, 0, 1376256, stream);   // conv2 mask pad rows
    hipMemsetAsync(pb2, 0, 1572864, stream);    // conv3 mask pad rows

    k_pack <<<2028, 256, 0, stream>>>(in, xin);
    k_bits1<<<1344, 256, 0, stream>>>(xin, xb1);
    k_conv1<<<1152, 384, 0, stream>>>(xb1, w1, s1);
    k_pool1<<<288, 256, 0, stream>>>(s1, pb16);
    k_conv2<<<384, 576, 0, stream>>>((const unsigned int*)pb16, w2, s2);
    k_pool2<<<192, 256, 0, stream>>>(s2, pb2);
    k_conv3<<<384, 576, 0, stream>>>((const uint2*)pb2, w3, s3);
    k_pool3<<<54, 256, 0, stream>>>(s3, p3);
    k_fc1  <<<768, 256, 0, stream>>>(p3, wfc1, f1);
    k_fc2  <<<96, 64, 0, stream>>>(f1, wfc2, out);
}

// Round 5
// 711.112 us; speedup vs baseline: 3.6146x; 1.0711x over previous
//
#include <hip/hip_runtime.h>

// ---------------------------------------------------------------------------
// SNN forward, split-phase edition.
// Each conv stage = k_wsum (LUT conv, PARALLEL over t; no serial dep) +
// k_scan (LIF recurrence over precomputed wsum stream; pool LIF + ballot mask
// emit fused in-register). Pool kernels and byte spike planes eliminated.
// One 56.6 MB f32 slab holds wsum (conv1 runs as two oc-halves to fit).
// ---------------------------------------------------------------------------

#define THETA 5120.0f

__device__ __forceinline__ float dyn_step(float x, float& u, float& v, float& r) {
#pragma clang fp contract(off)
    u = 0.75f * u + 64.0f * x;          // current decay (1024/4096), W_SCALE=64
    float vn = 0.96875f * v + u;        // voltage decay (128/4096)
    vn = (r > 0.0f) ? 0.0f : vn;        // refractory clamp
    float s;
    if (vn >= THETA) { s = 1.0f; v = 0.0f; r = 1.0f; }
    else             { s = 0.0f; v = vn; r = fmaxf(r - 1.0f, 0.0f); }
    return s;
}

__device__ __forceinline__ float dpp_add_xor1(float x) {
    int y = __builtin_amdgcn_update_dpp(0, __float_as_int(x), 0xB1, 0xF, 0xF, true);
    return x + __int_as_float(y);
}

// compress even bits (0,2,4,...) of a 24-bit value into 12 bits
__device__ __forceinline__ unsigned int compress_even(unsigned int m) {
    m &= 0x00555555u;
    m = (m | (m >> 1)) & 0x00333333u;
    m = (m | (m >> 2)) & 0x000F0F0Fu;
    m = (m | (m >> 4)) & 0x00FF00FFu;
    m = (m | (m >> 8)) & 0x0000FFFFu;
    return m;
}

// ---------------------------------------------------------------------------
// k_masks: in [B=48,C=4,26,26,T=128] f32 -> xb uint2[t][b][pr][28 rows]
// (channel-pair padded row masks, interior bit x+1, rows 1..26).
// Wave = (b,pr,y): ch = lane>>5, x = lane&31 (26 active). Ballot = both
// channels' row bits in one op. 2496 waves.
// ---------------------------------------------------------------------------
__global__ __launch_bounds__(256) void k_masks(const float* __restrict__ in,
                                               uint2* __restrict__ xb) {
    int wv = blockIdx.x * 4 + (threadIdx.x >> 6);
    int lane = threadIdx.x & 63;
    int y = wv % 26; int r = wv / 26;
    int pr = r & 1; int b = r >> 1;
    int ch = lane >> 5;
    int x = lane & 31;
    int act = x < 26;
    int xc = act ? x : 25;
    const float4* src = (const float4*)(in + (size_t)(((b * 4 + pr * 2 + ch) * 26 + y) * 26 + xc) * 128);
    uint2* dst = xb + ((size_t)b * 2 + pr) * 28 + (y + 1);
    for (int t4 = 0; t4 < 32; ++t4) {
        float4 f = src[t4];
#pragma unroll
        for (int k = 0; k < 4; ++k) {
            float fv = (k == 0) ? f.x : (k == 1) ? f.y : (k == 2) ? f.z : f.w;
            unsigned long long bal = __ballot(act && (fv != 0.0f));
            if (lane == 0) {
                unsigned int lo = ((unsigned int)bal & 0x03FFFFFFu) << 1;
                unsigned int hi = ((unsigned int)(bal >> 32) & 0x03FFFFFFu) << 1;
                dst[(size_t)(t4 * 4 + k) * 2688] = make_uint2(lo, hi);  // 48*2*28
            }
        }
    }
}

// ---------------------------------------------------------------------------
// k_wsum1: conv1 wsum (4->8ch, 5x5, 26->24) for oc half H (oc = H*4+oc4).
// Block 576 = one (b,oc) image, all 576 pixels; t-chunk 64. LUT 10-bit
// windows at lo + 33*hi (stride 1055), 2 pairs x 5 ky. 384 blocks/half.
// Output slab [t][ (b*4+oc4)*576 + pix ] f32 (110592 per t).
// ---------------------------------------------------------------------------
template<int H>
__global__ __launch_bounds__(576) void k_wsum1(const uint2* __restrict__ xb,
                                               const float* __restrict__ w1,
                                               float* __restrict__ ws) {
    __shared__ float wsh[100];
    __shared__ float tbl[10550];
    int tid = threadIdx.x;
    int tch = blockIdx.x & 1;
    int img = blockIdx.x >> 1;            // 0..191
    int b = img >> 2, oc4 = img & 3;
    int oc = H * 4 + oc4;
    if (tid < 100) wsh[tid] = w1[oc * 100 + tid];
    __syncthreads();
    for (int e = tid; e < 10240; e += 576) {
        int pr = e / 5120;
        int ky = (e / 1024) % 5;
        int i = e & 1023;
        int lo = i & 31, hi = i >> 5;
        float val = 0.f;
#pragma unroll
        for (int k = 0; k < 5; ++k)
            val += ((lo >> k) & 1) ? wsh[pr * 50 + ky * 5 + k] : 0.f;
#pragma unroll
        for (int k = 0; k < 5; ++k)
            val += ((hi >> k) & 1) ? wsh[pr * 50 + 25 + ky * 5 + k] : 0.f;
        tbl[(pr * 5 + ky) * 1055 + lo + 33 * hi] = val;
    }
    __syncthreads();
    int ox = tid % 24, oy = tid / 24;
    float* op = ws + (b * 4 + oc4) * 576 + tid;
    for (int t = tch * 64; t < tch * 64 + 64; ++t) {
        const uint2* rp = xb + ((size_t)t * 48 + b) * 56 + oy;   // pair 0 rows
        float acc = 0.f;
#pragma unroll
        for (int ky = 0; ky < 5; ++ky) {
            uint2 r0 = rp[ky];
            uint2 r1 = rp[28 + ky];
            acc += tbl[ky * 1055 + (int)(((r0.x >> ox) & 31u) + 33u * ((r0.y >> ox) & 31u))];
            acc += tbl[5275 + ky * 1055 + (int)(((r1.x >> ox) & 31u) + 33u * ((r1.y >> ox) & 31u))];
        }
        op[(size_t)t * 110592] = acc;
    }
}

// ---------------------------------------------------------------------------
// k_scan1: conv1 LIF + pool1 LIF + mask emit, oc half H.
// Wave = (b,oc4,ypair): lanes 0..47 = 2 conv rows x 24 px. Pool quad =
// lanes {2px,2px+1,2px+24,2px+25}; pool spikes ballot -> 12-bit row mask
// stored <<1 at pb16[t][b][py+1][c]. 2304 waves/half.
// ---------------------------------------------------------------------------
template<int H>
__global__ __launch_bounds__(256) void k_scan1(const float* __restrict__ ws,
                                               unsigned short* __restrict__ pb16) {
    int wv = blockIdx.x * 4 + (threadIdx.x >> 6);
    int lane = threadIdx.x & 63;
    int yp = wv % 12; int r = wv / 12;
    int oc4 = r & 3; int b = r >> 2;
    int act = lane < 48;
    int li = act ? lane : 0;
    int dy = li / 24, x = li % 24;
    const float* wp = ws + (b * 4 + oc4) * 576 + (yp * 2 + dy) * 24 + x;
    int pool_act = act && (lane < 24) && ((lane & 1) == 0);
    unsigned short* op = pb16 + ((size_t)b * 14 + yp + 1) * 8 + (H * 4 + oc4);
    float u = 0.f, v = 0.f, rf = 0.f;
    float pu = 0.f, pv = 0.f, prf = 0.f;
    float sp = 0.f;
    for (int t = 0; t < 128; ++t) {
        float w = wp[(size_t)t * 110592];
        // pool consumes conv spikes at t-1 (sp)
        float a = dpp_add_xor1(sp);
        float cnt = a + __shfl(a, (lane & 31) + 24 >= 64 ? 63 : lane + 24 > 63 ? 63 : lane + 24, 64);
        float ps = dyn_step(88.0f * cnt, pu, pv, prf);
        unsigned long long bal = __ballot(pool_act && (ps > 0.5f));
        if (lane == 0) {
            unsigned int m = compress_even((unsigned int)bal & 0x00FFFFFFu);
            op[(size_t)t * 5376] = (unsigned short)(m << 1);   // 48*14*8
        }
        sp = dyn_step(w, u, v, rf);
    }
}

// ---------------------------------------------------------------------------
// k_wsum2: conv2 wsum (8->16ch, 3x3, 12->12). Block 576 = 4 images x 144 pix;
// t-chunk 32 (grid 768). LUT 6-bit windows at lo + 9*hi (stride 71);
// tables [4 img][4 pr][3 ky][71]. Reads pb16 rows (uint4 = 8 ch) at t-1.
// Output slab [t][ img*144 + pix ] (110592 per t).
// ---------------------------------------------------------------------------
__global__ __launch_bounds__(576) void k_wsum2(const unsigned short* __restrict__ pb16,
                                               const float* __restrict__ w2,
                                               float* __restrict__ ws) {
    __shared__ float wsh[288];
    __shared__ float tbl[3408];
    int tid = threadIdx.x;
    int tch = blockIdx.x & 3;
    int g = blockIdx.x >> 2;              // 0..191
    if (tid < 288) {
        int oc = (g * 4 + tid / 72) & 15;
        wsh[tid] = w2[oc * 72 + (tid % 72)];
    }
    __syncthreads();
    for (int e = tid; e < 3072; e += 576) {
        int isel = e / 768;
        int pr = (e / 192) % 4;
        int ky = (e / 64) % 3;
        int i = e & 63;
        int lo = i & 7, hi = i >> 3;
        float val = 0.f;
#pragma unroll
        for (int k = 0; k < 3; ++k)
            val += ((lo >> k) & 1) ? wsh[isel * 72 + (2 * pr) * 9 + ky * 3 + k] : 0.f;
#pragma unroll
        for (int k = 0; k < 3; ++k)
            val += ((hi >> k) & 1) ? wsh[isel * 72 + (2 * pr + 1) * 9 + ky * 3 + k] : 0.f;
        tbl[isel * 852 + (pr * 3 + ky) * 71 + lo + 9 * hi] = val;
    }
    __syncthreads();
    int isel = tid / 144;
    int pix = tid % 144;
    int ox = pix % 12, oy = pix / 12;
    int img = g * 4 + isel;
    int b = img >> 4;
    const float* tb = tbl + isel * 852;
    float* op = ws + img * 144 + pix;
    for (int t = tch * 32; t < tch * 32 + 32; ++t) {
        float acc = 0.f;
        if (t > 0) {
            const uint4* rp = (const uint4*)(pb16 + (((size_t)(t - 1) * 48 + b) * 14 + oy) * 8);
#pragma unroll
            for (int ky = 0; ky < 3; ++ky) {
                uint4 row = rp[ky];
                unsigned int wd[4] = {row.x, row.y, row.z, row.w};
#pragma unroll
                for (int pr = 0; pr < 4; ++pr) {
                    unsigned int lo = (wd[pr] >> ox) & 7u;
                    unsigned int hi = (wd[pr] >> (16 + ox)) & 7u;
                    acc += tb[(pr * 3 + ky) * 71 + (int)(lo + 9u * hi)];
                }
            }
        }
        op[(size_t)t * 110592] = acc;
    }
}

// ---------------------------------------------------------------------------
// k_scan2: conv2 LIF + pool2 LIF + mask emit.
// Wave = (b,oc,yq): lanes 0..47 = 4 conv rows x 12 px (2 pool rows).
// Pool quad = {2px,2px+1,+12,+13} within row pair. 2304 waves.
// ---------------------------------------------------------------------------
__global__ __launch_bounds__(256) void k_scan2(const float* __restrict__ ws,
                                               unsigned short* __restrict__ pb2) {
    int wv = blockIdx.x * 4 + (threadIdx.x >> 6);
    int lane = threadIdx.x & 63;
    int yq = wv % 3; int r = wv / 3;
    int oc = r & 15; int b = r >> 4;
    int act = lane < 48;
    int li = act ? lane : 0;
    int dy = li / 12, x = li % 12;
    const float* wp = ws + (b * 16 + oc) * 144 + (yq * 4 + dy) * 12 + x;
    int pool_act = act && ((dy & 1) == 0) && ((x & 1) == 0);
    unsigned short* op = pb2 + ((size_t)b * 8 + yq * 2 + 1) * 16 + oc;
    float u = 0.f, v = 0.f, rf = 0.f;
    float pu = 0.f, pv = 0.f, prf = 0.f;
    float sp = 0.f;
    for (int t = 0; t < 128; ++t) {
        float w = wp[(size_t)t * 110592];
        float a = dpp_add_xor1(sp);
        int src = lane + 12 > 63 ? 63 : lane + 12;
        float cnt = a + __shfl(a, src, 64);
        float ps = dyn_step(88.0f * cnt, pu, pv, prf);
        unsigned long long bal = __ballot(pool_act && (ps > 0.5f));
        if (lane == 0) {
            unsigned int m0 = compress_even((unsigned int)bal & 0xFFFu);
            unsigned int m1 = compress_even(((unsigned int)(bal >> 24)) & 0xFFFu);
            op[(size_t)t * 6144] = (unsigned short)(m0 << 1);          // 48*8*16
            op[(size_t)t * 6144 + 16] = (unsigned short)(m1 << 1);
        }
        sp = dyn_step(w, u, v, rf);
    }
}

// ---------------------------------------------------------------------------
// k_wsum3: conv3 wsum (16->32ch, 3x3, 6->6). Block 576 = 4 oc x 4 b x 36 pix;
// t-chunk 32 (grid 384). Tables [4 osel][8 pr][3 ky][71] = 27.3 KB.
// Reads pb2 rows (2x uint4 = 16 ch) at t-1. Output [t][(b*32+oc)*36+pix].
// ---------------------------------------------------------------------------
__global__ __launch_bounds__(576) void k_wsum3(const unsigned short* __restrict__ pb2,
                                               const float* __restrict__ w3,
                                               float* __restrict__ ws) {
    __shared__ float wsh[576];
    __shared__ float tbl[6816];
    int tid = threadIdx.x;
    int tch = blockIdx.x & 3;
    int gb = blockIdx.x >> 2;             // 0..95 = ocg*12 + bg
    int ocg = gb / 12, bg = gb % 12;
    {
        int oc_t = ocg * 4 + tid / 144;
        wsh[tid] = w3[oc_t * 144 + (tid % 144)];
    }
    __syncthreads();
    for (int e = tid; e < 6144; e += 576) {
        int osel = e / 1536;
        int pr = (e / 192) % 8;
        int ky = (e / 64) % 3;
        int i = e & 63;
        int lo = i & 7, hi = i >> 3;
        float val = 0.f;
#pragma unroll
        for (int k = 0; k < 3; ++k)
            val += ((lo >> k) & 1) ? wsh[osel * 144 + (2 * pr) * 9 + ky * 3 + k] : 0.f;
#pragma unroll
        for (int k = 0; k < 3; ++k)
            val += ((hi >> k) & 1) ? wsh[osel * 144 + (2 * pr + 1) * 9 + ky * 3 + k] : 0.f;
        tbl[osel * 1704 + (pr * 3 + ky) * 71 + lo + 9 * hi] = val;
    }
    __syncthreads();
    int osel = tid / 144;
    int rem = tid % 144;
    int bsel = rem / 36;
    int pix = rem % 36;
    int ox = pix % 6, oy = pix / 6;
    int oc = ocg * 4 + osel;
    int b = bg * 4 + bsel;
    const float* tb = tbl + osel * 1704;
    float* op = ws + (b * 32 + oc) * 36 + pix;
    for (int t = tch * 32; t < tch * 32 + 32; ++t) {
        float acc = 0.f;
        if (t > 0) {
            const uint4* rp = (const uint4*)(pb2 + (((size_t)(t - 1) * 48 + b) * 8 + oy) * 16);
#pragma unroll
            for (int ky = 0; ky < 3; ++ky) {
                uint4 rA = rp[ky * 2];
                uint4 rB = rp[ky * 2 + 1];
                unsigned int wd[8] = {rA.x, rA.y, rA.z, rA.w, rB.x, rB.y, rB.z, rB.w};
#pragma unroll
                for (int pr = 0; pr < 8; ++pr) {
                    unsigned int lo = (wd[pr] >> ox) & 7u;
                    unsigned int hi = (wd[pr] >> (16 + ox)) & 7u;
                    acc += tb[(pr * 3 + ky) * 71 + (int)(lo + 9u * hi)];
                }
            }
        }
        op[(size_t)t * 55296] = acc;
    }
}

// ---------------------------------------------------------------------------
// k_scan3: conv3 LIF + pool3 LIF + byte emit into p3 [t][b][c*9+py*3+px].
// Wave = (b,oc): lanes 0..35 = 6 rows x 6 px. Pool quad = {2px,2px+1,+6,+7}.
// 1536 waves.
// ---------------------------------------------------------------------------
__global__ __launch_bounds__(256) void k_scan3(const float* __restrict__ ws,
                                               unsigned char* __restrict__ p3) {
    int wv = blockIdx.x * 4 + (threadIdx.x >> 6);
    int lane = threadIdx.x & 63;
    int oc = wv & 31; int b = wv >> 5;
    int act = lane < 36;
    int li = act ? lane : 0;
    int dy = li / 6, x = li % 6;
    const float* wp = ws + (b * 32 + oc) * 36 + li;
    int pool_act = act && ((dy & 1) == 0) && ((x & 1) == 0);
    unsigned char* op = p3 + b * 288 + oc * 9 + (dy >> 1) * 3 + (x >> 1);
    float u = 0.f, v = 0.f, rf = 0.f;
    float pu = 0.f, pv = 0.f, prf = 0.f;
    float sp = 0.f;
    for (int t = 0; t < 128; ++t) {
        float w = wp[(size_t)t * 55296];
        float a = dpp_add_xor1(sp);
        int src = lane + 6 > 63 ? 63 : lane + 6;
        float cnt = a + __shfl(a, src, 64);
        float ps = dyn_step(88.0f * cnt, pu, pv, prf);
        if (pool_act) op[(size_t)t * 13824] = (unsigned char)ps;
        sp = dyn_step(w, u, v, rf);
    }
}

// fc1: 288->512. K-split x8: 36 weights/lane in VGPRs for all 128 steps.
__global__ __launch_bounds__(256) void k_fc1(const unsigned char* __restrict__ p3,
                                             const float* __restrict__ wfc1,
                                             unsigned char* __restrict__ f1) {
    int gid = blockIdx.x * 256 + threadIdx.x;
    int kq = gid & 7; int r = gid >> 3;
    int o = r & 511; int b = r >> 9;
    float wr[36];
    const float* wp = wfc1 + o * 288 + kq * 36;
#pragma unroll
    for (int i = 0; i < 36; ++i) wr[i] = wp[i];
    float u = 0.f, v = 0.f, rf = 0.f;
    unsigned char* op = f1 + b * 512 + o;
    for (int t = 0; t < 128; ++t) {
        float acc = 0.f;
        if (t > 0) {
            const uchar4* sp = (const uchar4*)(p3 + (t - 1) * 13824 + b * 288 + kq * 36);
#pragma unroll
            for (int i = 0; i < 9; ++i) {
                uchar4 c4 = sp[i];
                acc += wr[i * 4 + 0] * (float)c4.x;
                acc += wr[i * 4 + 1] * (float)c4.y;
                acc += wr[i * 4 + 2] * (float)c4.z;
                acc += wr[i * 4 + 3] * (float)c4.w;
            }
        }
        acc = dpp_add_xor1(acc);
        int y2 = __builtin_amdgcn_update_dpp(0, __float_as_int(acc), 0x4E, 0xF, 0xF, true);
        acc = acc + __int_as_float(y2);
        acc += __shfl_xor(acc, 4, 64);
        float s = dyn_step(acc, u, v, rf);
        if (kq == 0) op[t * 24576] = (unsigned char)s;
    }
}

// fc2: 512->2 + final delay-shift into out [B,2,T]. One wave per (b,o).
__global__ __launch_bounds__(64) void k_fc2(const unsigned char* __restrict__ f1,
                                            const float* __restrict__ wfc2,
                                            float* __restrict__ out) {
    int o = blockIdx.x & 1;
    int b = blockIdx.x >> 1;
    int lane = threadIdx.x;
    float wr[8];
#pragma unroll
    for (int k = 0; k < 8; ++k) wr[k] = wfc2[o * 512 + k * 64 + lane];
    float u = 0.f, v = 0.f, rf = 0.f;
    float* obase = out + (b * 2 + o) * 128;
    if (lane == 0) obase[0] = 0.0f;
    for (int t = 0; t < 128; ++t) {
        float acc = 0.f;
        if (t > 0) {
            const unsigned char* sp = f1 + (t - 1) * 24576 + b * 512;
#pragma unroll
            for (int k = 0; k < 8; ++k)
                acc += wr[k] * (float)sp[k * 64 + lane];
        }
#pragma unroll
        for (int m = 1; m < 64; m <<= 1) acc += __shfl_xor(acc, m, 64);
        float s = dyn_step(acc, u, v, rf);
        if (lane == 0 && t < 127) obase[t + 1] = s;
    }
}

// ---------------------------------------------------------------------------
extern "C" void kernel_launch(void* const* d_in, const int* in_sizes, int n_in,
                              void* d_out, int out_size, void* d_ws, size_t ws_size,
                              hipStream_t stream) {
    const float* in   = (const float*)d_in[0];
    const float* w1   = (const float*)d_in[1];
    const float* w2   = (const float*)d_in[2];
    const float* w3   = (const float*)d_in[3];
    const float* wfc1 = (const float*)d_in[4];
    const float* wfc2 = (const float*)d_in[5];
    float* out = (float*)d_out;
    char* ws = (char*)d_ws;

    float*          slab = (float*)(ws);                       // 56,623,104 B (wsum, reused)
    uint2*          xb   = (uint2*)(ws + 56623104);            //  2,752,512
    unsigned short* pb16 = (unsigned short*)(ws + 59375616);   //  1,376,256
    unsigned short* pb2  = (unsigned short*)(ws + 60751872);   //  1,572,864
    unsigned char*  p3   = (unsigned char*)(ws + 62324736);    //  1,769,472
    unsigned char*  f1   = (unsigned char*)(ws + 64094208);    //  3,145,728
    // total 67,239,936 bytes

    hipMemsetAsync(xb, 0, 2752512, stream);     // pad rows 0/27
    hipMemsetAsync(pb16, 0, 1376256, stream);   // pad rows 0/13
    hipMemsetAsync(pb2, 0, 1572864, stream);    // pad rows 0/7

    k_masks   <<<624, 256, 0, stream>>>(in, xb);
    k_wsum1<0><<<384, 576, 0, stream>>>(xb, w1, slab);
    k_scan1<0><<<576, 256, 0, stream>>>(slab, pb16);
    k_wsum1<1><<<384, 576, 0, stream>>>(xb, w1, slab);
    k_scan1<1><<<576, 256, 0, stream>>>(slab, pb16);
    k_wsum2   <<<768, 576, 0, stream>>>(pb16, w2, slab);
    k_scan2   <<<576, 256, 0, stream>>>(slab, pb2);
    k_wsum3   <<<384, 576, 0, stream>>>(pb2, w3, slab);
    k_scan3   <<<384, 256, 0, stream>>>(slab, p3);
    k_fc1     <<<768, 256, 0, stream>>>(p3, wfc1, f1);
    k_fc2     <<<96, 64, 0, stream>>>(f1, wfc2, out);
}

// Round 7
// 674.684 us; speedup vs baseline: 3.8098x; 1.0540x over previous
//
#include <hip/hip_runtime.h>

// ---------------------------------------------------------------------------
// SNN forward, split-phase v2.
// Every stage = wsum (parallel over t) + scan (serial LIF, 8-deep register
// prefetch so global loads leave the dependency chain). Conv wsum via LDS
// LUTs (bank-spread); fc wsum dense VALU with weights in VGPRs.
// ---------------------------------------------------------------------------

#define THETA 5120.0f

__device__ __forceinline__ float dyn_step(float x, float& u, float& v, float& r) {
#pragma clang fp contract(off)
    u = 0.75f * u + 64.0f * x;          // current decay (1024/4096), W_SCALE=64
    float vn = 0.96875f * v + u;        // voltage decay (128/4096)
    vn = (r > 0.0f) ? 0.0f : vn;        // refractory clamp
    float s;
    if (vn >= THETA) { s = 1.0f; v = 0.0f; r = 1.0f; }
    else             { s = 0.0f; v = vn; r = fmaxf(r - 1.0f, 0.0f); }
    return s;
}

__device__ __forceinline__ float dpp_add_xor1(float x) {
    int y = __builtin_amdgcn_update_dpp(0, __float_as_int(x), 0xB1, 0xF, 0xF, true);
    return x + __int_as_float(y);
}
__device__ __forceinline__ float dpp_add_xor2(float x) {
    int y = __builtin_amdgcn_update_dpp(0, __float_as_int(x), 0x4E, 0xF, 0xF, true);
    return x + __int_as_float(y);
}

// compress even bits (0,2,4,...) of a 24-bit value into 12 bits
__device__ __forceinline__ unsigned int compress_even(unsigned int m) {
    m &= 0x00555555u;
    m = (m | (m >> 1)) & 0x00333333u;
    m = (m | (m >> 2)) & 0x000F0F0Fu;
    m = (m | (m >> 4)) & 0x00FF00FFu;
    m = (m | (m >> 8)) & 0x0000FFFFu;
    return m;
}

// ---------------------------------------------------------------------------
// k_masks: in [B=48,C=4,26,26,T=128] f32 -> xb uint2[t][b][pr][28 rows]
// ---------------------------------------------------------------------------
__global__ __launch_bounds__(256) void k_masks(const float* __restrict__ in,
                                               uint2* __restrict__ xb) {
    int wv = blockIdx.x * 4 + (threadIdx.x >> 6);
    int lane = threadIdx.x & 63;
    int y = wv % 26; int r = wv / 26;
    int pr = r & 1; int b = r >> 1;
    int ch = lane >> 5;
    int x = lane & 31;
    int act = x < 26;
    int xc = act ? x : 25;
    const float4* src = (const float4*)(in + (size_t)(((b * 4 + pr * 2 + ch) * 26 + y) * 26 + xc) * 128);
    uint2* dst = xb + ((size_t)b * 2 + pr) * 28 + (y + 1);
    for (int t4 = 0; t4 < 32; ++t4) {
        float4 f = src[t4];
#pragma unroll
        for (int k = 0; k < 4; ++k) {
            float fv = (k == 0) ? f.x : (k == 1) ? f.y : (k == 2) ? f.z : f.w;
            unsigned long long bal = __ballot(act && (fv != 0.0f));
            if (lane == 0) {
                unsigned int lo = ((unsigned int)bal & 0x03FFFFFFu) << 1;
                unsigned int hi = ((unsigned int)(bal >> 32) & 0x03FFFFFFu) << 1;
                dst[(size_t)(t4 * 4 + k) * 2688] = make_uint2(lo, hi);
            }
        }
    }
}

// ---------------------------------------------------------------------------
// k_wsum1: conv1 wsum (4->8ch, 5x5, 26->24), oc half H. LUT 10-bit windows
// at lo + 33*hi. Block 576 = one (b,oc) image; t-chunk 64.
// ---------------------------------------------------------------------------
template<int H>
__global__ __launch_bounds__(576) void k_wsum1(const uint2* __restrict__ xb,
                                               const float* __restrict__ w1,
                                               float* __restrict__ ws) {
    __shared__ float wsh[100];
    __shared__ float tbl[10550];
    int tid = threadIdx.x;
    int tch = blockIdx.x & 1;
    int img = blockIdx.x >> 1;            // 0..191
    int b = img >> 2, oc4 = img & 3;
    int oc = H * 4 + oc4;
    if (tid < 100) wsh[tid] = w1[oc * 100 + tid];
    __syncthreads();
    for (int e = tid; e < 10240; e += 576) {
        int pr = e / 5120;
        int ky = (e / 1024) % 5;
        int i = e & 1023;
        int lo = i & 31, hi = i >> 5;
        float val = 0.f;
#pragma unroll
        for (int k = 0; k < 5; ++k)
            val += ((lo >> k) & 1) ? wsh[pr * 50 + ky * 5 + k] : 0.f;
#pragma unroll
        for (int k = 0; k < 5; ++k)
            val += ((hi >> k) & 1) ? wsh[pr * 50 + 25 + ky * 5 + k] : 0.f;
        tbl[(pr * 5 + ky) * 1055 + lo + 33 * hi] = val;
    }
    __syncthreads();
    int ox = tid % 24, oy = tid / 24;
    float* op = ws + (b * 4 + oc4) * 576 + tid;
    for (int t = tch * 64; t < tch * 64 + 64; ++t) {
        const uint2* rp = xb + ((size_t)t * 48 + b) * 56 + oy;
        float acc = 0.f;
#pragma unroll
        for (int ky = 0; ky < 5; ++ky) {
            uint2 r0 = rp[ky];
            uint2 r1 = rp[28 + ky];
            acc += tbl[ky * 1055 + (int)(((r0.x >> ox) & 31u) + 33u * ((r0.y >> ox) & 31u))];
            acc += tbl[5275 + ky * 1055 + (int)(((r1.x >> ox) & 31u) + 33u * ((r1.y >> ox) & 31u))];
        }
        op[(size_t)t * 110592] = acc;
    }
}

// ---------------------------------------------------------------------------
// k_scan1: conv1 LIF + pool1 LIF + mask emit, oc half H. 8-deep prefetch.
// ---------------------------------------------------------------------------
template<int H>
__global__ __launch_bounds__(256) void k_scan1(const float* __restrict__ ws,
                                               unsigned short* __restrict__ pb16) {
    int wv = blockIdx.x * 4 + (threadIdx.x >> 6);
    int lane = threadIdx.x & 63;
    int yp = wv % 12; int r = wv / 12;
    int oc4 = r & 3; int b = r >> 2;
    int act = lane < 48;
    int li = act ? lane : 0;
    int dy = li / 24, x = li % 24;
    const float* wp = ws + (b * 4 + oc4) * 576 + (yp * 2 + dy) * 24 + x;
    int pool_act = act && (lane < 24) && ((lane & 1) == 0);
    unsigned short* op = pb16 + ((size_t)b * 14 + yp + 1) * 8 + (H * 4 + oc4);
    float u = 0.f, v = 0.f, rf = 0.f;
    float pu = 0.f, pv = 0.f, prf = 0.f;
    float sp = 0.f;
    float wbuf[8];
#pragma unroll
    for (int i = 0; i < 8; ++i) wbuf[i] = wp[(size_t)i * 110592];
    for (int tb = 0; tb < 128; tb += 8) {
#pragma unroll
        for (int j = 0; j < 8; ++j) {
            int t = tb + j;
            float w = wbuf[j];
            if (t + 8 < 128) wbuf[j] = wp[(size_t)(t + 8) * 110592];
            float a = dpp_add_xor1(sp);
            float cnt = a + __shfl(a, (lane & 31) + 24 >= 64 ? 63 : lane + 24 > 63 ? 63 : lane + 24, 64);
            float ps = dyn_step(88.0f * cnt, pu, pv, prf);
            unsigned long long bal = __ballot(pool_act && (ps > 0.5f));
            if (lane == 0) {
                unsigned int m = compress_even((unsigned int)bal & 0x00FFFFFFu);
                op[(size_t)t * 5376] = (unsigned short)(m << 1);
            }
            sp = dyn_step(w, u, v, rf);
        }
    }
}

// ---------------------------------------------------------------------------
// k_wsum2: conv2 wsum (8->16ch, 3x3, 12->12). LUT 6-bit windows at lo+9*hi.
// ---------------------------------------------------------------------------
__global__ __launch_bounds__(576) void k_wsum2(const unsigned short* __restrict__ pb16,
                                               const float* __restrict__ w2,
                                               float* __restrict__ ws) {
    __shared__ float wsh[288];
    __shared__ float tbl[3408];
    int tid = threadIdx.x;
    int tch = blockIdx.x & 3;
    int g = blockIdx.x >> 2;              // 0..191
    if (tid < 288) {
        int oc = (g * 4 + tid / 72) & 15;
        wsh[tid] = w2[oc * 72 + (tid % 72)];
    }
    __syncthreads();
    for (int e = tid; e < 3072; e += 576) {
        int isel = e / 768;
        int pr = (e / 192) % 4;
        int ky = (e / 64) % 3;
        int i = e & 63;
        int lo = i & 7, hi = i >> 3;
        float val = 0.f;
#pragma unroll
        for (int k = 0; k < 3; ++k)
            val += ((lo >> k) & 1) ? wsh[isel * 72 + (2 * pr) * 9 + ky * 3 + k] : 0.f;
#pragma unroll
        for (int k = 0; k < 3; ++k)
            val += ((hi >> k) & 1) ? wsh[isel * 72 + (2 * pr + 1) * 9 + ky * 3 + k] : 0.f;
        tbl[isel * 852 + (pr * 3 + ky) * 71 + lo + 9 * hi] = val;
    }
    __syncthreads();
    int isel = tid / 144;
    int pix = tid % 144;
    int ox = pix % 12, oy = pix / 12;
    int img = g * 4 + isel;
    int b = img >> 4;
    const float* tb = tbl + isel * 852;
    float* op = ws + img * 144 + pix;
    for (int t = tch * 32; t < tch * 32 + 32; ++t) {
        float acc = 0.f;
        if (t > 0) {
            const uint4* rp = (const uint4*)(pb16 + (((size_t)(t - 1) * 48 + b) * 14 + oy) * 8);
#pragma unroll
            for (int ky = 0; ky < 3; ++ky) {
                uint4 row = rp[ky];
                unsigned int wd[4] = {row.x, row.y, row.z, row.w};
#pragma unroll
                for (int pr = 0; pr < 4; ++pr) {
                    unsigned int lo = (wd[pr] >> ox) & 7u;
                    unsigned int hi = (wd[pr] >> (16 + ox)) & 7u;
                    acc += tb[(pr * 3 + ky) * 71 + (int)(lo + 9u * hi)];
                }
            }
        }
        op[(size_t)t * 110592] = acc;
    }
}

// ---------------------------------------------------------------------------
// k_scan2: conv2 LIF + pool2 LIF + mask emit. 8-deep prefetch.
// ---------------------------------------------------------------------------
__global__ __launch_bounds__(256) void k_scan2(const float* __restrict__ ws,
                                               unsigned short* __restrict__ pb2) {
    int wv = blockIdx.x * 4 + (threadIdx.x >> 6);
    int lane = threadIdx.x & 63;
    int yq = wv % 3; int r = wv / 3;
    int oc = r & 15; int b = r >> 4;
    int act = lane < 48;
    int li = act ? lane : 0;
    int dy = li / 12, x = li % 12;
    const float* wp = ws + (b * 16 + oc) * 144 + (yq * 4 + dy) * 12 + x;
    int pool_act = act && ((dy & 1) == 0) && ((x & 1) == 0);
    unsigned short* op = pb2 + ((size_t)b * 8 + yq * 2 + 1) * 16 + oc;
    float u = 0.f, v = 0.f, rf = 0.f;
    float pu = 0.f, pv = 0.f, prf = 0.f;
    float sp = 0.f;
    float wbuf[8];
#pragma unroll
    for (int i = 0; i < 8; ++i) wbuf[i] = wp[(size_t)i * 110592];
    for (int tb = 0; tb < 128; tb += 8) {
#pragma unroll
        for (int j = 0; j < 8; ++j) {
            int t = tb + j;
            float w = wbuf[j];
            if (t + 8 < 128) wbuf[j] = wp[(size_t)(t + 8) * 110592];
            float a = dpp_add_xor1(sp);
            int src = lane + 12 > 63 ? 63 : lane + 12;
            float cnt = a + __shfl(a, src, 64);
            float ps = dyn_step(88.0f * cnt, pu, pv, prf);
            unsigned long long bal = __ballot(pool_act && (ps > 0.5f));
            if (lane == 0) {
                unsigned int m0 = compress_even((unsigned int)bal & 0xFFFu);
                unsigned int m1 = compress_even(((unsigned int)(bal >> 24)) & 0xFFFu);
                op[(size_t)t * 6144] = (unsigned short)(m0 << 1);
                op[(size_t)t * 6144 + 16] = (unsigned short)(m1 << 1);
            }
            sp = dyn_step(w, u, v, rf);
        }
    }
}

// ---------------------------------------------------------------------------
// k_wsum3: conv3 wsum (16->32ch, 3x3, 6->6).
// ---------------------------------------------------------------------------
__global__ __launch_bounds__(576) void k_wsum3(const unsigned short* __restrict__ pb2,
                                               const float* __restrict__ w3,
                                               float* __restrict__ ws) {
    __shared__ float wsh[576];
    __shared__ float tbl[6816];
    int tid = threadIdx.x;
    int tch = blockIdx.x & 3;
    int gb = blockIdx.x >> 2;             // 0..95 = ocg*12 + bg
    int ocg = gb / 12, bg = gb % 12;
    {
        int oc_t = ocg * 4 + tid / 144;
        wsh[tid] = w3[oc_t * 144 + (tid % 144)];
    }
    __syncthreads();
    for (int e = tid; e < 6144; e += 576) {
        int osel = e / 1536;
        int pr = (e / 192) % 8;
        int ky = (e / 64) % 3;
        int i = e & 63;
        int lo = i & 7, hi = i >> 3;
        float val = 0.f;
#pragma unroll
        for (int k = 0; k < 3; ++k)
            val += ((lo >> k) & 1) ? wsh[osel * 144 + (2 * pr) * 9 + ky * 3 + k] : 0.f;
#pragma unroll
        for (int k = 0; k < 3; ++k)
            val += ((hi >> k) & 1) ? wsh[osel * 144 + (2 * pr + 1) * 9 + ky * 3 + k] : 0.f;
        tbl[osel * 1704 + (pr * 3 + ky) * 71 + lo + 9 * hi] = val;
    }
    __syncthreads();
    int osel = tid / 144;
    int rem = tid % 144;
    int bsel = rem / 36;
    int pix = rem % 36;
    int ox = pix % 6, oy = pix / 6;
    int oc = ocg * 4 + osel;
    int b = bg * 4 + bsel;
    const float* tb = tbl + osel * 1704;
    float* op = ws + (b * 32 + oc) * 36 + pix;
    for (int t = tch * 32; t < tch * 32 + 32; ++t) {
        float acc = 0.f;
        if (t > 0) {
            const uint4* rp = (const uint4*)(pb2 + (((size_t)(t - 1) * 48 + b) * 8 + oy) * 16);
#pragma unroll
            for (int ky = 0; ky < 3; ++ky) {
                uint4 rA = rp[ky * 2];
                uint4 rB = rp[ky * 2 + 1];
                unsigned int wd[8] = {rA.x, rA.y, rA.z, rA.w, rB.x, rB.y, rB.z, rB.w};
#pragma unroll
                for (int pr = 0; pr < 8; ++pr) {
                    unsigned int lo = (wd[pr] >> ox) & 7u;
                    unsigned int hi = (wd[pr] >> (16 + ox)) & 7u;
                    acc += tb[(pr * 3 + ky) * 71 + (int)(lo + 9u * hi)];
                }
            }
        }
        op[(size_t)t * 55296] = acc;
    }
}

// ---------------------------------------------------------------------------
// k_scan3: conv3 LIF + pool3 LIF + byte emit into p3 [t][b][288]. Prefetch.
// ---------------------------------------------------------------------------
__global__ __launch_bounds__(256) void k_scan3(const float* __restrict__ ws,
                                               unsigned char* __restrict__ p3) {
    int wv = blockIdx.x * 4 + (threadIdx.x >> 6);
    int lane = threadIdx.x & 63;
    int oc = wv & 31; int b = wv >> 5;
    int act = lane < 36;
    int li = act ? lane : 0;
    int dy = li / 6, x = li % 6;
    const float* wp = ws + (b * 32 + oc) * 36 + li;
    int pool_act = act && ((dy & 1) == 0) && ((x & 1) == 0);
    unsigned char* op = p3 + b * 288 + oc * 9 + (dy >> 1) * 3 + (x >> 1);
    float u = 0.f, v = 0.f, rf = 0.f;
    float pu = 0.f, pv = 0.f, prf = 0.f;
    float sp = 0.f;
    float wbuf[8];
#pragma unroll
    for (int i = 0; i < 8; ++i) wbuf[i] = wp[(size_t)i * 55296];
    for (int tb = 0; tb < 128; tb += 8) {
#pragma unroll
        for (int j = 0; j < 8; ++j) {
            int t = tb + j;
            float w = wbuf[j];
            if (t + 8 < 128) wbuf[j] = wp[(size_t)(t + 8) * 55296];
            float a = dpp_add_xor1(sp);
            int src = lane + 6 > 63 ? 63 : lane + 6;
            float cnt = a + __shfl(a, src, 64);
            float ps = dyn_step(88.0f * cnt, pu, pv, prf);
            if (pool_act) op[(size_t)t * 13824] = (unsigned char)ps;
            sp = dyn_step(w, u, v, rf);
        }
    }
}

// ---------------------------------------------------------------------------
// k_fc1w: fc1 wsum, parallel over t. Thread = (kq8, o512, b48, tc16); 36
// weights/lane in VGPRs, 8 t-steps/thread. wsf1[t][b*512+o] f32.
// ---------------------------------------------------------------------------
__global__ __launch_bounds__(256) void k_fc1w(const unsigned char* __restrict__ p3,
                                              const float* __restrict__ wfc1,
                                              float* __restrict__ wsf1) {
    int gid = blockIdx.x * 256 + threadIdx.x;
    int kq = gid & 7;
    int o = (gid >> 3) & 511;
    int r = gid >> 12;                 // 0..767
    int b = r % 48; int tc = r / 48;   // tc 0..15
    float wr[36];
    const float* wp = wfc1 + o * 288 + kq * 36;
#pragma unroll
    for (int i = 0; i < 36; ++i) wr[i] = wp[i];
    float* op = wsf1 + (size_t)b * 512 + o;
#pragma unroll
    for (int j = 0; j < 8; ++j) {
        int t = tc * 8 + j;
        float acc = 0.f;
        if (t > 0) {
            const uchar4* sp = (const uchar4*)(p3 + (size_t)(t - 1) * 13824 + b * 288 + kq * 36);
#pragma unroll
            for (int i = 0; i < 9; ++i) {
                uchar4 c4 = sp[i];
                acc += wr[i * 4 + 0] * (float)c4.x;
                acc += wr[i * 4 + 1] * (float)c4.y;
                acc += wr[i * 4 + 2] * (float)c4.z;
                acc += wr[i * 4 + 3] * (float)c4.w;
            }
        }
        acc = dpp_add_xor1(acc);
        acc = dpp_add_xor2(acc);
        acc += __shfl_xor(acc, 4, 64);
        if (kq == 0) op[(size_t)t * 24576] = acc;
    }
}

// k_fc1s: fc1 LIF scan. Thread per (b,o); emits f32 spikes f1f[t][b*512+o].
__global__ __launch_bounds__(256) void k_fc1s(const float* __restrict__ wsf1,
                                              float* __restrict__ f1f) {
    int tid = blockIdx.x * 256 + threadIdx.x;   // 0..24575
    float u = 0.f, v = 0.f, rf = 0.f;
    float wbuf[8];
#pragma unroll
    for (int i = 0; i < 8; ++i) wbuf[i] = wsf1[(size_t)i * 24576 + tid];
    for (int tb = 0; tb < 128; tb += 8) {
#pragma unroll
        for (int j = 0; j < 8; ++j) {
            int t = tb + j;
            float w = wbuf[j];
            if (t + 8 < 128) wbuf[j] = wsf1[(size_t)(t + 8) * 24576 + tid];
            float s = dyn_step(w, u, v, rf);
            f1f[(size_t)t * 24576 + tid] = s;
        }
    }
}

// k_fc2w: fc2 wsum, parallel over t. Wave per (t,b); lane: o=lane&1,
// kq=lane>>1 (16 f32 slice). wsf2[t][b*2+o].
__global__ __launch_bounds__(256) void k_fc2w(const float* __restrict__ f1f,
                                              const float* __restrict__ wfc2,
                                              float* __restrict__ wsf2) {
    int wv = blockIdx.x * 4 + (threadIdx.x >> 6);   // 0..6143
    int lane = threadIdx.x & 63;
    int b = wv % 48, t = wv / 48;
    int o = lane & 1, kq = lane >> 1;
    float acc = 0.f;
    if (t > 0) {
        const float* wp = wfc2 + o * 512 + kq * 16;
        const float* sp = f1f + (size_t)(t - 1) * 24576 + b * 512 + kq * 16;
#pragma unroll
        for (int i = 0; i < 16; ++i) acc += wp[i] * sp[i];
    }
#pragma unroll
    for (int m = 2; m < 64; m <<= 1) acc += __shfl_xor(acc, m, 64);
    if (lane < 2) wsf2[(size_t)t * 96 + b * 2 + o] = acc;
}

// k_fc2s: fc2 LIF scan + delay-shift into out [B,2,T]. 96 active threads.
__global__ __launch_bounds__(128) void k_fc2s(const float* __restrict__ wsf2,
                                              float* __restrict__ out) {
    int tid = threadIdx.x;
    if (tid >= 96) return;
    float* ob = out + tid * 128;       // tid = b*2+o
    ob[0] = 0.0f;
    float u = 0.f, v = 0.f, rf = 0.f;
    float wbuf[8];
#pragma unroll
    for (int i = 0; i < 8; ++i) wbuf[i] = wsf2[(size_t)i * 96 + tid];
    for (int tb = 0; tb < 128; tb += 8) {
#pragma unroll
        for (int j = 0; j < 8; ++j) {
            int t = tb + j;
            float w = wbuf[j];
            if (t + 8 < 128) wbuf[j] = wsf2[(size_t)(t + 8) * 96 + tid];
            float s = dyn_step(w, u, v, rf);
            if (t < 127) ob[t + 1] = s;
        }
    }
}

// ---------------------------------------------------------------------------
extern "C" void kernel_launch(void* const* d_in, const int* in_sizes, int n_in,
                              void* d_out, int out_size, void* d_ws, size_t ws_size,
                              hipStream_t stream) {
    const float* in   = (const float*)d_in[0];
    const float* w1   = (const float*)d_in[1];
    const float* w2   = (const float*)d_in[2];
    const float* w3   = (const float*)d_in[3];
    const float* wfc1 = (const float*)d_in[4];
    const float* wfc2 = (const float*)d_in[5];
    float* out = (float*)d_out;
    char* ws = (char*)d_ws;

    float*          slab = (float*)(ws);                       // 56,623,104 (conv wsums; fc wsums reuse)
    uint2*          xb   = (uint2*)(ws + 56623104);            //  2,752,512
    unsigned short* pb16 = (unsigned short*)(ws + 59375616);   //  1,376,256
    unsigned short* pb2  = (unsigned short*)(ws + 60751872);   //  1,572,864
    unsigned char*  p3   = (unsigned char*)(ws + 62324736);    //  1,769,472
    float*          f1f  = (float*)(ws + 64094208);            // 12,582,912
    float*          wsf1 = (float*)(ws);                       // 12,582,912 (slab reuse, post-scan3)
    float*          wsf2 = (float*)(ws + 16777216);            //     49,152 (slab reuse, disjoint)
    // total 76,677,120 bytes

    hipMemsetAsync(xb, 0, 2752512, stream);     // pad rows 0/27
    hipMemsetAsync(pb16, 0, 1376256, stream);   // pad rows 0/13
    hipMemsetAsync(pb2, 0, 1572864, stream);    // pad rows 0/7

    k_masks   <<<624, 256, 0, stream>>>(in, xb);
    k_wsum1<0><<<384, 576, 0, stream>>>(xb, w1, slab);
    k_scan1<0><<<576, 256, 0, stream>>>(slab, pb16);
    k_wsum1<1><<<384, 576, 0, stream>>>(xb, w1, slab);
    k_scan1<1><<<576, 256, 0, stream>>>(slab, pb16);
    k_wsum2   <<<768, 576, 0, stream>>>(pb16, w2, slab);
    k_scan2   <<<576, 256, 0, stream>>>(slab, pb2);
    k_wsum3   <<<384, 576, 0, stream>>>(pb2, w3, slab);
    k_scan3   <<<384, 256, 0, stream>>>(slab, p3);
    k_fc1w    <<<12288, 256, 0, stream>>>(p3, wfc1, wsf1);
    k_fc1s    <<<96, 256, 0, stream>>>(wsf1, f1f);
    k_fc2w    <<<1536, 256, 0, stream>>>(f1f, wfc2, wsf2);
    k_fc2s    <<<1, 128, 0, stream>>>(wsf2, out);
}

// Round 8
// 634.682 us; speedup vs baseline: 4.0499x; 1.0630x over previous
//
#include <hip/hip_runtime.h>

// ---------------------------------------------------------------------------
// SNN forward, split-phase v3: fc1 on MFMA.
// Conv stages: wsum (LDS-LUT, parallel over t) + scan (serial LIF, prefetch).
// fc1: spikes emitted as bf16 A-matrix rows by scan3; weights split bf16x3
// (exact f32 coverage); 16x16x32 bf16 MFMA GEMM -> wsf1; tiny LIF scan.
// ---------------------------------------------------------------------------

#define THETA 5120.0f

typedef __attribute__((ext_vector_type(8))) short bfrag;   // 8 bf16 (4 VGPRs)
typedef __attribute__((ext_vector_type(4))) float ffrag;   // 4 f32 acc

__device__ __forceinline__ float dyn_step(float x, float& u, float& v, float& r) {
#pragma clang fp contract(off)
    u = 0.75f * u + 64.0f * x;          // current decay (1024/4096), W_SCALE=64
    float vn = 0.96875f * v + u;        // voltage decay (128/4096)
    vn = (r > 0.0f) ? 0.0f : vn;        // refractory clamp
    float s;
    if (vn >= THETA) { s = 1.0f; v = 0.0f; r = 1.0f; }
    else             { s = 0.0f; v = vn; r = fmaxf(r - 1.0f, 0.0f); }
    return s;
}

__device__ __forceinline__ float dpp_add_xor1(float x) {
    int y = __builtin_amdgcn_update_dpp(0, __float_as_int(x), 0xB1, 0xF, 0xF, true);
    return x + __int_as_float(y);
}
__device__ __forceinline__ float dpp_add_xor2(float x) {
    int y = __builtin_amdgcn_update_dpp(0, __float_as_int(x), 0x4E, 0xF, 0xF, true);
    return x + __int_as_float(y);
}

// compress even bits (0,2,4,...) of a 24-bit value into 12 bits
__device__ __forceinline__ unsigned int compress_even(unsigned int m) {
    m &= 0x00555555u;
    m = (m | (m >> 1)) & 0x00333333u;
    m = (m | (m >> 2)) & 0x000F0F0Fu;
    m = (m | (m >> 4)) & 0x00FF00FFu;
    m = (m | (m >> 8)) & 0x0000FFFFu;
    return m;
}

__device__ __forceinline__ unsigned short f2bf(float f) {
    unsigned int u = __float_as_uint(f);
    unsigned int r = (u + 0x7FFFu + ((u >> 16) & 1u)) >> 16;   // RNE
    return (unsigned short)r;
}
__device__ __forceinline__ float bf2f(unsigned short b) {
    return __uint_as_float(((unsigned int)b) << 16);
}

// ---------------------------------------------------------------------------
// k_masks: in [B=48,C=4,26,26,T=128] f32 -> xb uint2[t][b][pr][28 rows]
// ---------------------------------------------------------------------------
__global__ __launch_bounds__(256) void k_masks(const float* __restrict__ in,
                                               uint2* __restrict__ xb) {
    int wv = blockIdx.x * 4 + (threadIdx.x >> 6);
    int lane = threadIdx.x & 63;
    int y = wv % 26; int r = wv / 26;
    int pr = r & 1; int b = r >> 1;
    int ch = lane >> 5;
    int x = lane & 31;
    int act = x < 26;
    int xc = act ? x : 25;
    const float4* src = (const float4*)(in + (size_t)(((b * 4 + pr * 2 + ch) * 26 + y) * 26 + xc) * 128);
    uint2* dst = xb + ((size_t)b * 2 + pr) * 28 + (y + 1);
    for (int t4 = 0; t4 < 32; ++t4) {
        float4 f = src[t4];
#pragma unroll
        for (int k = 0; k < 4; ++k) {
            float fv = (k == 0) ? f.x : (k == 1) ? f.y : (k == 2) ? f.z : f.w;
            unsigned long long bal = __ballot(act && (fv != 0.0f));
            if (lane == 0) {
                unsigned int lo = ((unsigned int)bal & 0x03FFFFFFu) << 1;
                unsigned int hi = ((unsigned int)(bal >> 32) & 0x03FFFFFFu) << 1;
                dst[(size_t)(t4 * 4 + k) * 2688] = make_uint2(lo, hi);
            }
        }
    }
}

// ---------------------------------------------------------------------------
// k_wsum1: conv1 wsum (4->8ch, 5x5, 26->24), oc half H. LUT 10-bit windows
// at lo + 33*hi. Block 576 = one (b,oc) image; t-chunk 64.
// ---------------------------------------------------------------------------
template<int H>
__global__ __launch_bounds__(576) void k_wsum1(const uint2* __restrict__ xb,
                                               const float* __restrict__ w1,
                                               float* __restrict__ ws) {
    __shared__ float wsh[100];
    __shared__ float tbl[10550];
    int tid = threadIdx.x;
    int tch = blockIdx.x & 1;
    int img = blockIdx.x >> 1;            // 0..191
    int b = img >> 2, oc4 = img & 3;
    int oc = H * 4 + oc4;
    if (tid < 100) wsh[tid] = w1[oc * 100 + tid];
    __syncthreads();
    for (int e = tid; e < 10240; e += 576) {
        int pr = e / 5120;
        int ky = (e / 1024) % 5;
        int i = e & 1023;
        int lo = i & 31, hi = i >> 5;
        float val = 0.f;
#pragma unroll
        for (int k = 0; k < 5; ++k)
            val += ((lo >> k) & 1) ? wsh[pr * 50 + ky * 5 + k] : 0.f;
#pragma unroll
        for (int k = 0; k < 5; ++k)
            val += ((hi >> k) & 1) ? wsh[pr * 50 + 25 + ky * 5 + k] : 0.f;
        tbl[(pr * 5 + ky) * 1055 + lo + 33 * hi] = val;
    }
    __syncthreads();
    int ox = tid % 24, oy = tid / 24;
    float* op = ws + (b * 4 + oc4) * 576 + tid;
    for (int t = tch * 64; t < tch * 64 + 64; ++t) {
        const uint2* rp = xb + ((size_t)t * 48 + b) * 56 + oy;
        float acc = 0.f;
#pragma unroll
        for (int ky = 0; ky < 5; ++ky) {
            uint2 r0 = rp[ky];
            uint2 r1 = rp[28 + ky];
            acc += tbl[ky * 1055 + (int)(((r0.x >> ox) & 31u) + 33u * ((r0.y >> ox) & 31u))];
            acc += tbl[5275 + ky * 1055 + (int)(((r1.x >> ox) & 31u) + 33u * ((r1.y >> ox) & 31u))];
        }
        op[(size_t)t * 110592] = acc;
    }
}

// ---------------------------------------------------------------------------
// k_scan1: conv1 LIF + pool1 LIF + mask emit, oc half H. 8-deep prefetch.
// ---------------------------------------------------------------------------
template<int H>
__global__ __launch_bounds__(256) void k_scan1(const float* __restrict__ ws,
                                               unsigned short* __restrict__ pb16) {
    int wv = blockIdx.x * 4 + (threadIdx.x >> 6);
    int lane = threadIdx.x & 63;
    int yp = wv % 12; int r = wv / 12;
    int oc4 = r & 3; int b = r >> 2;
    int act = lane < 48;
    int li = act ? lane : 0;
    int dy = li / 24, x = li % 24;
    const float* wp = ws + (b * 4 + oc4) * 576 + (yp * 2 + dy) * 24 + x;
    int pool_act = act && (lane < 24) && ((lane & 1) == 0);
    unsigned short* op = pb16 + ((size_t)b * 14 + yp + 1) * 8 + (H * 4 + oc4);
    float u = 0.f, v = 0.f, rf = 0.f;
    float pu = 0.f, pv = 0.f, prf = 0.f;
    float sp = 0.f;
    float wbuf[8];
#pragma unroll
    for (int i = 0; i < 8; ++i) wbuf[i] = wp[(size_t)i * 110592];
    for (int tb = 0; tb < 128; tb += 8) {
#pragma unroll
        for (int j = 0; j < 8; ++j) {
            int t = tb + j;
            float w = wbuf[j];
            if (t + 8 < 128) wbuf[j] = wp[(size_t)(t + 8) * 110592];
            float a = dpp_add_xor1(sp);
            float cnt = a + __shfl(a, (lane & 31) + 24 >= 64 ? 63 : lane + 24 > 63 ? 63 : lane + 24, 64);
            float ps = dyn_step(88.0f * cnt, pu, pv, prf);
            unsigned long long bal = __ballot(pool_act && (ps > 0.5f));
            if (lane == 0) {
                unsigned int m = compress_even((unsigned int)bal & 0x00FFFFFFu);
                op[(size_t)t * 5376] = (unsigned short)(m << 1);
            }
            sp = dyn_step(w, u, v, rf);
        }
    }
}

// ---------------------------------------------------------------------------
// k_wsum2: conv2 wsum (8->16ch, 3x3, 12->12). LUT 6-bit windows at lo+9*hi.
// ---------------------------------------------------------------------------
__global__ __launch_bounds__(576) void k_wsum2(const unsigned short* __restrict__ pb16,
                                               const float* __restrict__ w2,
                                               float* __restrict__ ws) {
    __shared__ float wsh[288];
    __shared__ float tbl[3408];
    int tid = threadIdx.x;
    int tch = blockIdx.x & 3;
    int g = blockIdx.x >> 2;              // 0..191
    if (tid < 288) {
        int oc = (g * 4 + tid / 72) & 15;
        wsh[tid] = w2[oc * 72 + (tid % 72)];
    }
    __syncthreads();
    for (int e = tid; e < 3072; e += 576) {
        int isel = e / 768;
        int pr = (e / 192) % 4;
        int ky = (e / 64) % 3;
        int i = e & 63;
        int lo = i & 7, hi = i >> 3;
        float val = 0.f;
#pragma unroll
        for (int k = 0; k < 3; ++k)
            val += ((lo >> k) & 1) ? wsh[isel * 72 + (2 * pr) * 9 + ky * 3 + k] : 0.f;
#pragma unroll
        for (int k = 0; k < 3; ++k)
            val += ((hi >> k) & 1) ? wsh[isel * 72 + (2 * pr + 1) * 9 + ky * 3 + k] : 0.f;
        tbl[isel * 852 + (pr * 3 + ky) * 71 + lo + 9 * hi] = val;
    }
    __syncthreads();
    int isel = tid / 144;
    int pix = tid % 144;
    int ox = pix % 12, oy = pix / 12;
    int img = g * 4 + isel;
    int b = img >> 4;
    const float* tb = tbl + isel * 852;
    float* op = ws + img * 144 + pix;
    for (int t = tch * 32; t < tch * 32 + 32; ++t) {
        float acc = 0.f;
        if (t > 0) {
            const uint4* rp = (const uint4*)(pb16 + (((size_t)(t - 1) * 48 + b) * 14 + oy) * 8);
#pragma unroll
            for (int ky = 0; ky < 3; ++ky) {
                uint4 row = rp[ky];
                unsigned int wd[4] = {row.x, row.y, row.z, row.w};
#pragma unroll
                for (int pr = 0; pr < 4; ++pr) {
                    unsigned int lo = (wd[pr] >> ox) & 7u;
                    unsigned int hi = (wd[pr] >> (16 + ox)) & 7u;
                    acc += tb[(pr * 3 + ky) * 71 + (int)(lo + 9u * hi)];
                }
            }
        }
        op[(size_t)t * 110592] = acc;
    }
}

// ---------------------------------------------------------------------------
// k_scan2: conv2 LIF + pool2 LIF + mask emit. 8-deep prefetch.
// ---------------------------------------------------------------------------
__global__ __launch_bounds__(256) void k_scan2(const float* __restrict__ ws,
                                               unsigned short* __restrict__ pb2) {
    int wv = blockIdx.x * 4 + (threadIdx.x >> 6);
    int lane = threadIdx.x & 63;
    int yq = wv % 3; int r = wv / 3;
    int oc = r & 15; int b = r >> 4;
    int act = lane < 48;
    int li = act ? lane : 0;
    int dy = li / 12, x = li % 12;
    const float* wp = ws + (b * 16 + oc) * 144 + (yq * 4 + dy) * 12 + x;
    int pool_act = act && ((dy & 1) == 0) && ((x & 1) == 0);
    unsigned short* op = pb2 + ((size_t)b * 8 + yq * 2 + 1) * 16 + oc;
    float u = 0.f, v = 0.f, rf = 0.f;
    float pu = 0.f, pv = 0.f, prf = 0.f;
    float sp = 0.f;
    float wbuf[8];
#pragma unroll
    for (int i = 0; i < 8; ++i) wbuf[i] = wp[(size_t)i * 110592];
    for (int tb = 0; tb < 128; tb += 8) {
#pragma unroll
        for (int j = 0; j < 8; ++j) {
            int t = tb + j;
            float w = wbuf[j];
            if (t + 8 < 128) wbuf[j] = wp[(size_t)(t + 8) * 110592];
            float a = dpp_add_xor1(sp);
            int src = lane + 12 > 63 ? 63 : lane + 12;
            float cnt = a + __shfl(a, src, 64);
            float ps = dyn_step(88.0f * cnt, pu, pv, prf);
            unsigned long long bal = __ballot(pool_act && (ps > 0.5f));
            if (lane == 0) {
                unsigned int m0 = compress_even((unsigned int)bal & 0xFFFu);
                unsigned int m1 = compress_even(((unsigned int)(bal >> 24)) & 0xFFFu);
                op[(size_t)t * 6144] = (unsigned short)(m0 << 1);
                op[(size_t)t * 6144 + 16] = (unsigned short)(m1 << 1);
            }
            sp = dyn_step(w, u, v, rf);
        }
    }
}

// ---------------------------------------------------------------------------
// k_wsum3: conv3 wsum (16->32ch, 3x3, 6->6).
// ---------------------------------------------------------------------------
__global__ __launch_bounds__(576) void k_wsum3(const unsigned short* __restrict__ pb2,
                                               const float* __restrict__ w3,
                                               float* __restrict__ ws) {
    __shared__ float wsh[576];
    __shared__ float tbl[6816];
    int tid = threadIdx.x;
    int tch = blockIdx.x & 3;
    int gb = blockIdx.x >> 2;             // 0..95 = ocg*12 + bg
    int ocg = gb / 12, bg = gb % 12;
    {
        int oc_t = ocg * 4 + tid / 144;
        wsh[tid] = w3[oc_t * 144 + (tid % 144)];
    }
    __syncthreads();
    for (int e = tid; e < 6144; e += 576) {
        int osel = e / 1536;
        int pr = (e / 192) % 8;
        int ky = (e / 64) % 3;
        int i = e & 63;
        int lo = i & 7, hi = i >> 3;
        float val = 0.f;
#pragma unroll
        for (int k = 0; k < 3; ++k)
            val += ((lo >> k) & 1) ? wsh[osel * 144 + (2 * pr) * 9 + ky * 3 + k] : 0.f;
#pragma unroll
        for (int k = 0; k < 3; ++k)
            val += ((hi >> k) & 1) ? wsh[osel * 144 + (2 * pr + 1) * 9 + ky * 3 + k] : 0.f;
        tbl[osel * 1704 + (pr * 3 + ky) * 71 + lo + 9 * hi] = val;
    }
    __syncthreads();
    int osel = tid / 144;
    int rem = tid % 144;
    int bsel = rem / 36;
    int pix = rem % 36;
    int ox = pix % 6, oy = pix / 6;
    int oc = ocg * 4 + osel;
    int b = bg * 4 + bsel;
    const float* tb = tbl + osel * 1704;
    float* op = ws + (b * 32 + oc) * 36 + pix;
    for (int t = tch * 32; t < tch * 32 + 32; ++t) {
        float acc = 0.f;
        if (t > 0) {
            const uint4* rp = (const uint4*)(pb2 + (((size_t)(t - 1) * 48 + b) * 8 + oy) * 16);
#pragma unroll
            for (int ky = 0; ky < 3; ++ky) {
                uint4 rA = rp[ky * 2];
                uint4 rB = rp[ky * 2 + 1];
                unsigned int wd[8] = {rA.x, rA.y, rA.z, rA.w, rB.x, rB.y, rB.z, rB.w};
#pragma unroll
                for (int pr = 0; pr < 8; ++pr) {
                    unsigned int lo = (wd[pr] >> ox) & 7u;
                    unsigned int hi = (wd[pr] >> (16 + ox)) & 7u;
                    acc += tb[(pr * 3 + ky) * 71 + (int)(lo + 9u * hi)];
                }
            }
        }
        op[(size_t)t * 55296] = acc;
    }
}

// ---------------------------------------------------------------------------
// k_scan3: conv3 LIF + pool3 LIF; emits bf16 spike rows of the fc1 A-matrix:
// a3[(t+1)*48 + b][oc*9 + py*3 + px] = spike(t) (delay-shift folded in).
// Row t=0 pre-zeroed by memset. 8-deep prefetch.
// ---------------------------------------------------------------------------
__global__ __launch_bounds__(256) void k_scan3(const float* __restrict__ ws,
                                               unsigned short* __restrict__ a3) {
    int wv = blockIdx.x * 4 + (threadIdx.x >> 6);
    int lane = threadIdx.x & 63;
    int oc = wv & 31; int b = wv >> 5;
    int act = lane < 36;
    int li = act ? lane : 0;
    int dy = li / 6, x = li % 6;
    const float* wp = ws + (b * 32 + oc) * 36 + li;
    int pool_act = act && ((dy & 1) == 0) && ((x & 1) == 0);
    unsigned short* op = a3 + (size_t)b * 288 + oc * 9 + (dy >> 1) * 3 + (x >> 1);
    float u = 0.f, v = 0.f, rf = 0.f;
    float pu = 0.f, pv = 0.f, prf = 0.f;
    float sp = 0.f;
    float wbuf[8];
#pragma unroll
    for (int i = 0; i < 8; ++i) wbuf[i] = wp[(size_t)i * 55296];
    for (int tb = 0; tb < 128; tb += 8) {
#pragma unroll
        for (int j = 0; j < 8; ++j) {
            int t = tb + j;
            float w = wbuf[j];
            if (t + 8 < 128) wbuf[j] = wp[(size_t)(t + 8) * 55296];
            float a = dpp_add_xor1(sp);
            int src = lane + 6 > 63 ? 63 : lane + 6;
            float cnt = a + __shfl(a, src, 64);
            float ps = dyn_step(88.0f * cnt, pu, pv, prf);
            if (pool_act && t < 127)
                op[(size_t)(t + 1) * 13824] = (ps > 0.5f) ? 0x3F80 : 0;   // bf16 1.0/0.0
            sp = dyn_step(w, u, v, rf);
        }
    }
}

// ---------------------------------------------------------------------------
// k_wsplit: wfc1[512][288] f32 -> wb[3][288][512] bf16 (bf16x3 split:
// b0+b1+b2 reconstructs f32 to below-ulp error). 147456 threads.
// ---------------------------------------------------------------------------
__global__ __launch_bounds__(256) void k_wsplit(const float* __restrict__ wfc1,
                                                unsigned short* __restrict__ wb) {
    int gid = blockIdx.x * 256 + threadIdx.x;
    int o = gid / 288, k = gid % 288;
    float w = wfc1[gid];
    unsigned short b0 = f2bf(w);
    float r1 = w - bf2f(b0);
    unsigned short b1 = f2bf(r1);
    float r2 = r1 - bf2f(b1);
    unsigned short b2 = f2bf(r2);
    wb[(size_t)k * 512 + o] = b0;
    wb[(size_t)147456 + k * 512 + o] = b1;
    wb[(size_t)294912 + k * 512 + o] = b2;
}

// ---------------------------------------------------------------------------
// k_fc1mm: wsf1[m][o] = A[m][k] x W[k][o] via mfma_f32_16x16x32_bf16.
// M=6144 (t*48+b), N=512, K'=864 (288 x 3 chunks). Block = 4 waves, one
// 16-wide n-tile; B tile (864x16) staged in LDS, padded stride 872 ushorts.
// Grid 768 = 32 n-tiles x 24 m-chunks; 4 m-tiles per wave.
// A-frag: A[m=lane&15][k=quad*8+j]; B-frag: B[k=quad*8+j][n=lane&15];
// D: row=quad*4+reg, col=lane&15 (m89-verified layouts).
// ---------------------------------------------------------------------------
__global__ __launch_bounds__(256) void k_fc1mm(const unsigned short* __restrict__ a3,
                                               const unsigned short* __restrict__ wb,
                                               float* __restrict__ wsf1) {
    __shared__ unsigned short Bs[16 * 872];
    int tid = threadIdx.x;
    int nt = blockIdx.x & 31;
    int mc = blockIdx.x >> 5;
    int n0 = nt * 16;
    for (int idx = tid; idx < 13824; idx += 256) {
        int kp = idx >> 4;
        int n = idx & 15;
        Bs[n * 872 + kp] = wb[(size_t)kp * 512 + n0 + n];
    }
    __syncthreads();
    int wave = tid >> 6;
    int lane = tid & 63;
    int ln = lane & 15, quad = lane >> 4;
#pragma unroll
    for (int i = 0; i < 4; ++i) {
        int m0 = (mc * 16 + wave * 4 + i) * 16;
        const unsigned short* arow = a3 + (size_t)(m0 + ln) * 288 + quad * 8;
        ffrag acc = {0.f, 0.f, 0.f, 0.f};
#pragma unroll
        for (int kb = 0; kb < 9; ++kb) {
            bfrag av = *(const bfrag*)(arow + kb * 32);
#pragma unroll
            for (int c = 0; c < 3; ++c) {
                bfrag bv = *(const bfrag*)(&Bs[ln * 872 + c * 288 + kb * 32 + quad * 8]);
                acc = __builtin_amdgcn_mfma_f32_16x16x32_bf16(av, bv, acc, 0, 0, 0);
            }
        }
        float* wout = wsf1 + (size_t)(m0 + quad * 4) * 512 + n0 + ln;
        wout[0] = acc[0];
        wout[512] = acc[1];
        wout[1024] = acc[2];
        wout[1536] = acc[3];
    }
}

// k_fc1s: fc1 LIF scan. Thread per (b,o); emits f32 spikes f1f[t][b*512+o].
__global__ __launch_bounds__(256) void k_fc1s(const float* __restrict__ wsf1,
                                              float* __restrict__ f1f) {
    int tid = blockIdx.x * 256 + threadIdx.x;   // 0..24575
    float u = 0.f, v = 0.f, rf = 0.f;
    float wbuf[8];
#pragma unroll
    for (int i = 0; i < 8; ++i) wbuf[i] = wsf1[(size_t)i * 24576 + tid];
    for (int tb = 0; tb < 128; tb += 8) {
#pragma unroll
        for (int j = 0; j < 8; ++j) {
            int t = tb + j;
            float w = wbuf[j];
            if (t + 8 < 128) wbuf[j] = wsf1[(size_t)(t + 8) * 24576 + tid];
            float s = dyn_step(w, u, v, rf);
            f1f[(size_t)t * 24576 + tid] = s;
        }
    }
}

// k_fc2w: fc2 wsum, parallel over t. Wave per (t,b); lane: o=lane&1,
// kq=lane>>1 (16 f32 slice). wsf2[t][b*2+o].
__global__ __launch_bounds__(256) void k_fc2w(const float* __restrict__ f1f,
                                              const float* __restrict__ wfc2,
                                              float* __restrict__ wsf2) {
    int wv = blockIdx.x * 4 + (threadIdx.x >> 6);   // 0..6143
    int lane = threadIdx.x & 63;
    int b = wv % 48, t = wv / 48;
    int o = lane & 1, kq = lane >> 1;
    float acc = 0.f;
    if (t > 0) {
        const float* wp = wfc2 + o * 512 + kq * 16;
        const float* sp = f1f + (size_t)(t - 1) * 24576 + b * 512 + kq * 16;
#pragma unroll
        for (int i = 0; i < 16; ++i) acc += wp[i] * sp[i];
    }
#pragma unroll
    for (int m = 2; m < 64; m <<= 1) acc += __shfl_xor(acc, m, 64);
    if (lane < 2) wsf2[(size_t)t * 96 + b * 2 + o] = acc;
}

// k_fc2s: fc2 LIF scan + delay-shift into out [B,2,T]. 96 active threads.
__global__ __launch_bounds__(128) void k_fc2s(const float* __restrict__ wsf2,
                                              float* __restrict__ out) {
    int tid = threadIdx.x;
    if (tid >= 96) return;
    float* ob = out + tid * 128;       // tid = b*2+o
    ob[0] = 0.0f;
    float u = 0.f, v = 0.f, rf = 0.f;
    float wbuf[8];
#pragma unroll
    for (int i = 0; i < 8; ++i) wbuf[i] = wsf2[(size_t)i * 96 + tid];
    for (int tb = 0; tb < 128; tb += 8) {
#pragma unroll
        for (int j = 0; j < 8; ++j) {
            int t = tb + j;
            float w = wbuf[j];
            if (t + 8 < 128) wbuf[j] = wsf2[(size_t)(t + 8) * 96 + tid];
            float s = dyn_step(w, u, v, rf);
            if (t < 127) ob[t + 1] = s;
        }
    }
}

// ---------------------------------------------------------------------------
extern "C" void kernel_launch(void* const* d_in, const int* in_sizes, int n_in,
                              void* d_out, int out_size, void* d_ws, size_t ws_size,
                              hipStream_t stream) {
    const float* in   = (const float*)d_in[0];
    const float* w1   = (const float*)d_in[1];
    const float* w2   = (const float*)d_in[2];
    const float* w3   = (const float*)d_in[3];
    const float* wfc1 = (const float*)d_in[4];
    const float* wfc2 = (const float*)d_in[5];
    float* out = (float*)d_out;
    char* ws = (char*)d_ws;

    float*          slab = (float*)(ws);                       // 56,623,104 (conv wsums; wsf1 reuse)
    uint2*          xb   = (uint2*)(ws + 56623104);            //  2,752,512
    unsigned short* pb16 = (unsigned short*)(ws + 59375616);   //  1,376,256
    unsigned short* pb2  = (unsigned short*)(ws + 60751872);   //  1,572,864
    float*          f1f  = (float*)(ws + 64094208);            // 12,582,912
    unsigned short* a3   = (unsigned short*)(ws + 76677120);   //  3,538,944 [6144][288] bf16
    unsigned short* wb   = (unsigned short*)(ws + 80216064);   //    884,736 [3][288][512] bf16
    float*          wsf1 = (float*)(ws);                       // 12,582,912 (slab reuse, post-scan3)
    float*          wsf2 = (float*)(ws + 16777216);            //     49,152 (slab reuse, disjoint)
    // total 81,100,800 bytes

    hipMemsetAsync(xb, 0, 2752512, stream);     // pad rows 0/27
    hipMemsetAsync(pb16, 0, 1376256, stream);   // pad rows 0/13
    hipMemsetAsync(pb2, 0, 1572864, stream);    // pad rows 0/7
    hipMemsetAsync(a3, 0, 27648, stream);       // A rows t=0 (48*288 bf16)

    k_wsplit  <<<576, 256, 0, stream>>>(wfc1, wb);
    k_masks   <<<624, 256, 0, stream>>>(in, xb);
    k_wsum1<0><<<384, 576, 0, stream>>>(xb, w1, slab);
    k_scan1<0><<<576, 256, 0, stream>>>(slab, pb16);
    k_wsum1<1><<<384, 576, 0, stream>>>(xb, w1, slab);
    k_scan1<1><<<576, 256, 0, stream>>>(slab, pb16);
    k_wsum2   <<<768, 576, 0, stream>>>(pb16, w2, slab);
    k_scan2   <<<576, 256, 0, stream>>>(slab, pb2);
    k_wsum3   <<<384, 576, 0, stream>>>(pb2, w3, slab);
    k_scan3   <<<384, 256, 0, stream>>>(slab, a3);
    k_fc1mm   <<<768, 256, 0, stream>>>(a3, wb, wsf1);
    k_fc1s    <<<96, 256, 0, stream>>>(wsf1, f1f);
    k_fc2w    <<<1536, 256, 0, stream>>>(f1f, wfc2, wsf2);
    k_fc2s    <<<1, 128, 0, stream>>>(wsf2, out);
}

// Round 9
// 602.651 us; speedup vs baseline: 4.2652x; 1.0532x over previous
//
#include <hip/hip_runtime.h>

// ---------------------------------------------------------------------------
// SNN forward, split-phase v4.
// wsum (parallel over t, LDS-LUT conv / MFMA fc) + scan (serial LIF).
// Scans: quad-major neuron order (pool = 2 DPP quad_perm adds), 64 active
// lanes (256B coalesced loads), 16-deep prefetch, NO per-step stores (ballot
// -> register burst every 8 t into per-wave staging; builder kernels expand
// to mask rows / bf16 A-matrix in parallel over t).
// ---------------------------------------------------------------------------

#define THETA 5120.0f

typedef __attribute__((ext_vector_type(8))) short bfrag;   // 8 bf16 (4 VGPRs)
typedef __attribute__((ext_vector_type(4))) float ffrag;   // 4 f32 acc

__device__ __forceinline__ float dyn_step(float x, float& u, float& v, float& r) {
#pragma clang fp contract(off)
    u = 0.75f * u + 64.0f * x;          // current decay (1024/4096), W_SCALE=64
    float vn = 0.96875f * v + u;        // voltage decay (128/4096)
    vn = (r > 0.0f) ? 0.0f : vn;        // refractory clamp
    float s;
    if (vn >= THETA) { s = 1.0f; v = 0.0f; r = 1.0f; }
    else             { s = 0.0f; v = vn; r = fmaxf(r - 1.0f, 0.0f); }
    return s;
}

__device__ __forceinline__ float dpp_add_xor1(float x) {
    int y = __builtin_amdgcn_update_dpp(0, __float_as_int(x), 0xB1, 0xF, 0xF, true);
    return x + __int_as_float(y);
}
__device__ __forceinline__ float dpp_add_xor2(float x) {
    int y = __builtin_amdgcn_update_dpp(0, __float_as_int(x), 0x4E, 0xF, 0xF, true);
    return x + __int_as_float(y);
}

// compress bits at positions 4k (k=0..15) of a 64-bit word into 16 bits
__device__ __forceinline__ unsigned int compress4(unsigned long long x) {
    x &= 0x1111111111111111ull;
    x = (x | (x >> 3))  & 0x0303030303030303ull;
    x = (x | (x >> 6))  & 0x000F000F000F000Full;
    x = (x | (x >> 12)) & 0x000000FF000000FFull;
    x = (x | (x >> 24)) & 0xFFFFull;
    return (unsigned int)x;
}

__device__ __forceinline__ unsigned short f2bf(float f) {
    unsigned int u = __float_as_uint(f);
    unsigned int r = (u + 0x7FFFu + ((u >> 16) & 1u)) >> 16;   // RNE
    return (unsigned short)r;
}
__device__ __forceinline__ float bf2f(unsigned short b) {
    return __uint_as_float(((unsigned int)b) << 16);
}

// ---------------------------------------------------------------------------
// k_masks: in [B=48,C=4,26,26,T=128] f32 -> xb uint2[t][b][pr][28 rows]
// ---------------------------------------------------------------------------
__global__ __launch_bounds__(256) void k_masks(const float* __restrict__ in,
                                               uint2* __restrict__ xb) {
    int wv = blockIdx.x * 4 + (threadIdx.x >> 6);
    int lane = threadIdx.x & 63;
    int y = wv % 26; int r = wv / 26;
    int pr = r & 1; int b = r >> 1;
    int ch = lane >> 5;
    int x = lane & 31;
    int act = x < 26;
    int xc = act ? x : 25;
    const float4* src = (const float4*)(in + (size_t)(((b * 4 + pr * 2 + ch) * 26 + y) * 26 + xc) * 128);
    uint2* dst = xb + ((size_t)b * 2 + pr) * 28 + (y + 1);
    for (int t4 = 0; t4 < 32; ++t4) {
        float4 f = src[t4];
#pragma unroll
        for (int k = 0; k < 4; ++k) {
            float fv = (k == 0) ? f.x : (k == 1) ? f.y : (k == 2) ? f.z : f.w;
            unsigned long long bal = __ballot(act && (fv != 0.0f));
            if (lane == 0) {
                unsigned int lo = ((unsigned int)bal & 0x03FFFFFFu) << 1;
                unsigned int hi = ((unsigned int)(bal >> 32) & 0x03FFFFFFu) << 1;
                dst[(size_t)(t4 * 4 + k) * 2688] = make_uint2(lo, hi);
            }
        }
    }
}

// ---------------------------------------------------------------------------
// k_wsum1: conv1 wsum (4->8ch, 5x5, 26->24), oc half H. LUT 10-bit windows
// at lo + 33*hi. Block 576 = one (b,oc) image; t-chunk 64. QUAD-MAJOR pixel
// order: pix = q*4+s, q = py*12+px (pool coords), s = dy*2+dx.
// ---------------------------------------------------------------------------
template<int H>
__global__ __launch_bounds__(576) void k_wsum1(const uint2* __restrict__ xb,
                                               const float* __restrict__ w1,
                                               float* __restrict__ ws) {
    __shared__ float wsh[100];
    __shared__ float tbl[10550];
    int tid = threadIdx.x;
    int tch = blockIdx.x & 1;
    int img = blockIdx.x >> 1;            // 0..191
    int b = img >> 2, oc4 = img & 3;
    int oc = H * 4 + oc4;
    if (tid < 100) wsh[tid] = w1[oc * 100 + tid];
    __syncthreads();
    for (int e = tid; e < 10240; e += 576) {
        int pr = e / 5120;
        int ky = (e / 1024) % 5;
        int i = e & 1023;
        int lo = i & 31, hi = i >> 5;
        float val = 0.f;
#pragma unroll
        for (int k = 0; k < 5; ++k)
            val += ((lo >> k) & 1) ? wsh[pr * 50 + ky * 5 + k] : 0.f;
#pragma unroll
        for (int k = 0; k < 5; ++k)
            val += ((hi >> k) & 1) ? wsh[pr * 50 + 25 + ky * 5 + k] : 0.f;
        tbl[(pr * 5 + ky) * 1055 + lo + 33 * hi] = val;
    }
    __syncthreads();
    int q = tid >> 2, s = tid & 3;
    int ox = (q % 12) * 2 + (s & 1);
    int oy = (q / 12) * 2 + (s >> 1);
    float* op = ws + (b * 4 + oc4) * 576 + tid;
    for (int t = tch * 64; t < tch * 64 + 64; ++t) {
        const uint2* rp = xb + ((size_t)t * 48 + b) * 56 + oy;
        float acc = 0.f;
#pragma unroll
        for (int ky = 0; ky < 5; ++ky) {
            uint2 r0 = rp[ky];
            uint2 r1 = rp[28 + ky];
            acc += tbl[ky * 1055 + (int)(((r0.x >> ox) & 31u) + 33u * ((r0.y >> ox) & 31u))];
            acc += tbl[5275 + ky * 1055 + (int)(((r1.x >> ox) & 31u) + 33u * ((r1.y >> ox) & 31u))];
        }
        op[(size_t)t * 110592] = acc;
    }
}

// ---------------------------------------------------------------------------
// k_scan1: conv1 LIF + pool1 LIF, oc half H. Wave = 64 neurons = 16 quads.
// Pool bits ballot-compressed to u16/t, burst-flushed (uint4 per 8 t) to
// st1[(H*1728 + wave)*128 + t]. 1728 waves/half.
// ---------------------------------------------------------------------------
template<int H>
__global__ __launch_bounds__(256) void k_scan1(const float* __restrict__ ws,
                                               unsigned short* __restrict__ st1) {
    int wv = blockIdx.x * 4 + (threadIdx.x >> 6);   // 0..1727
    int lane = threadIdx.x & 63;
    const float* wp = ws + wv * 64 + lane;
    unsigned short* so = st1 + ((size_t)(H * 1728 + wv)) * 128;
    float u = 0.f, v = 0.f, rf = 0.f;
    float pu = 0.f, pv = 0.f, prf = 0.f;
    float sp = 0.f;
    unsigned int mb[4];
    float wbuf[16];
#pragma unroll
    for (int i = 0; i < 16; ++i) wbuf[i] = wp[(size_t)i * 110592];
    for (int tb = 0; tb < 128; tb += 16) {
#pragma unroll
        for (int j = 0; j < 16; ++j) {
            int t = tb + j;
            float w = wbuf[j];
            if (t + 16 < 128) wbuf[j] = wp[(size_t)(t + 16) * 110592];
            float cnt = dpp_add_xor2(dpp_add_xor1(sp));
            float ps = dyn_step(88.0f * cnt, pu, pv, prf);
            unsigned long long bal = __ballot(((lane & 3) == 0) && (ps > 0.5f));
            unsigned int m = compress4(bal);
            int sl = (t >> 1) & 3;
            mb[sl] = (t & 1) ? (mb[sl] | (m << 16)) : m;
            if ((t & 7) == 7 && lane == 0)
                *(uint4*)(so + (t & ~7)) = make_uint4(mb[0], mb[1], mb[2], mb[3]);
            sp = dyn_step(w, u, v, rf);
        }
    }
}

// k_mb1: st1 -> pb16 row masks [t][b][y+1][oc] (12 bits << 1). 589824 thr.
__global__ __launch_bounds__(256) void k_mb1(const unsigned short* __restrict__ st1,
                                             unsigned short* __restrict__ pb16) {
    int gid = blockIdx.x * 256 + threadIdx.x;
    int oc = gid & 7; int r = gid >> 3;
    int y = r % 12; r /= 12;
    int b = r % 48; int t = r / 48;
    int base = (oc >> 2) * 1728 + (b * 4 + (oc & 3)) * 9;
    int Q0 = y * 12;
    int w0 = Q0 >> 4, off = Q0 & 15;
    unsigned int v0 = st1[(size_t)(base + w0) * 128 + t];
    unsigned int v1 = (off > 4) ? (unsigned int)st1[(size_t)(base + w0 + 1) * 128 + t] : 0u;
    unsigned int m = ((v0 >> off) | (v1 << (16 - off))) & 0xFFFu;
    pb16[((size_t)(t * 48 + b) * 14 + y + 1) * 8 + oc] = (unsigned short)(m << 1);
}

// ---------------------------------------------------------------------------
// k_wsum2: conv2 wsum (8->16ch, 3x3, 12->12). LUT 6-bit windows at lo+9*hi.
// QUAD-MAJOR pixel order: pix = q*4+s, q = py*6+px.
// ---------------------------------------------------------------------------
__global__ __launch_bounds__(576) void k_wsum2(const unsigned short* __restrict__ pb16,
                                               const float* __restrict__ w2,
                                               float* __restrict__ ws) {
    __shared__ float wsh[288];
    __shared__ float tbl[3408];
    int tid = threadIdx.x;
    int tch = blockIdx.x & 3;
    int g = blockIdx.x >> 2;              // 0..191
    if (tid < 288) {
        int oc = (g * 4 + tid / 72) & 15;
        wsh[tid] = w2[oc * 72 + (tid % 72)];
    }
    __syncthreads();
    for (int e = tid; e < 3072; e += 576) {
        int isel = e / 768;
        int pr = (e / 192) % 4;
        int ky = (e / 64) % 3;
        int i = e & 63;
        int lo = i & 7, hi = i >> 3;
        float val = 0.f;
#pragma unroll
        for (int k = 0; k < 3; ++k)
            val += ((lo >> k) & 1) ? wsh[isel * 72 + (2 * pr) * 9 + ky * 3 + k] : 0.f;
#pragma unroll
        for (int k = 0; k < 3; ++k)
            val += ((hi >> k) & 1) ? wsh[isel * 72 + (2 * pr + 1) * 9 + ky * 3 + k] : 0.f;
        tbl[isel * 852 + (pr * 3 + ky) * 71 + lo + 9 * hi] = val;
    }
    __syncthreads();
    int isel = tid / 144;
    int pix = tid % 144;
    int q = pix >> 2, s = pix & 3;
    int ox = (q % 6) * 2 + (s & 1);
    int oy = (q / 6) * 2 + (s >> 1);
    int img = g * 4 + isel;
    int b = img >> 4;
    const float* tb = tbl + isel * 852;
    float* op = ws + img * 144 + pix;
    for (int t = tch * 32; t < tch * 32 + 32; ++t) {
        float acc = 0.f;
        if (t > 0) {
            const uint4* rp = (const uint4*)(pb16 + (((size_t)(t - 1) * 48 + b) * 14 + oy) * 8);
#pragma unroll
            for (int ky = 0; ky < 3; ++ky) {
                uint4 row = rp[ky];
                unsigned int wd[4] = {row.x, row.y, row.z, row.w};
#pragma unroll
                for (int pr = 0; pr < 4; ++pr) {
                    unsigned int lo = (wd[pr] >> ox) & 7u;
                    unsigned int hi = (wd[pr] >> (16 + ox)) & 7u;
                    acc += tb[(pr * 3 + ky) * 71 + (int)(lo + 9u * hi)];
                }
            }
        }
        op[(size_t)t * 110592] = acc;
    }
}

// ---------------------------------------------------------------------------
// k_scan2: conv2 LIF + pool2 LIF. Block 576 = 4 images (9 waves); wave = 16
// quads. Staging st2[(g4*9 + wloc)*128 + t]. 1728 waves.
// ---------------------------------------------------------------------------
__global__ __launch_bounds__(576) void k_scan2(const float* __restrict__ ws,
                                               unsigned short* __restrict__ st2) {
    int tid = threadIdx.x;
    int wloc = tid >> 6, lane = tid & 63;
    int g4 = blockIdx.x;                  // 0..191
    const float* wp = ws + g4 * 576 + tid;
    unsigned short* so = st2 + ((size_t)(g4 * 9 + wloc)) * 128;
    float u = 0.f, v = 0.f, rf = 0.f;
    float pu = 0.f, pv = 0.f, prf = 0.f;
    float sp = 0.f;
    unsigned int mb[4];
    float wbuf[16];
#pragma unroll
    for (int i = 0; i < 16; ++i) wbuf[i] = wp[(size_t)i * 110592];
    for (int tb = 0; tb < 128; tb += 16) {
#pragma unroll
        for (int j = 0; j < 16; ++j) {
            int t = tb + j;
            float w = wbuf[j];
            if (t + 16 < 128) wbuf[j] = wp[(size_t)(t + 16) * 110592];
            float cnt = dpp_add_xor2(dpp_add_xor1(sp));
            float ps = dyn_step(88.0f * cnt, pu, pv, prf);
            unsigned long long bal = __ballot(((lane & 3) == 0) && (ps > 0.5f));
            unsigned int m = compress4(bal);
            int sl = (t >> 1) & 3;
            mb[sl] = (t & 1) ? (mb[sl] | (m << 16)) : m;
            if ((t & 7) == 7 && lane == 0)
                *(uint4*)(so + (t & ~7)) = make_uint4(mb[0], mb[1], mb[2], mb[3]);
            sp = dyn_step(w, u, v, rf);
        }
    }
}

// k_mb2: st2 -> pb2 row masks [t][b][y+1][oc] (6 bits << 1). 589824 thr.
__global__ __launch_bounds__(256) void k_mb2(const unsigned short* __restrict__ st2,
                                             unsigned short* __restrict__ pb2) {
    int gid = blockIdx.x * 256 + threadIdx.x;
    int oc = gid & 15; int r = gid >> 4;
    int y = r % 6; r /= 6;
    int b = r % 48; int t = r / 48;
    int img = b * 16 + oc;
    int g4 = img >> 2, lI = img & 3;
    int Q0 = lI * 36 + y * 6;
    int w0 = Q0 >> 4, off = Q0 & 15;
    unsigned int v0 = st2[(size_t)(g4 * 9 + w0) * 128 + t];
    unsigned int v1 = (off > 10) ? (unsigned int)st2[(size_t)(g4 * 9 + w0 + 1) * 128 + t] : 0u;
    unsigned int m = ((v0 >> off) | (v1 << (16 - off))) & 0x3Fu;
    pb2[((size_t)(t * 48 + b) * 8 + y + 1) * 16 + oc] = (unsigned short)(m << 1);
}

// ---------------------------------------------------------------------------
// k_wsum3: conv3 wsum (16->32ch, 3x3, 6->6). QUAD-MAJOR: pix = q*4+s,
// q = py*3+px.
// ---------------------------------------------------------------------------
__global__ __launch_bounds__(576) void k_wsum3(const unsigned short* __restrict__ pb2,
                                               const float* __restrict__ w3,
                                               float* __restrict__ ws) {
    __shared__ float wsh[576];
    __shared__ float tbl[6816];
    int tid = threadIdx.x;
    int tch = blockIdx.x & 3;
    int gb = blockIdx.x >> 2;             // 0..95 = ocg*12 + bg
    int ocg = gb / 12, bg = gb % 12;
    {
        int oc_t = ocg * 4 + tid / 144;
        wsh[tid] = w3[oc_t * 144 + (tid % 144)];
    }
    __syncthreads();
    for (int e = tid; e < 6144; e += 576) {
        int osel = e / 1536;
        int pr = (e / 192) % 8;
        int ky = (e / 64) % 3;
        int i = e & 63;
        int lo = i & 7, hi = i >> 3;
        float val = 0.f;
#pragma unroll
        for (int k = 0; k < 3; ++k)
            val += ((lo >> k) & 1) ? wsh[osel * 144 + (2 * pr) * 9 + ky * 3 + k] : 0.f;
#pragma unroll
        for (int k = 0; k < 3; ++k)
            val += ((hi >> k) & 1) ? wsh[osel * 144 + (2 * pr + 1) * 9 + ky * 3 + k] : 0.f;
        tbl[osel * 1704 + (pr * 3 + ky) * 71 + lo + 9 * hi] = val;
    }
    __syncthreads();
    int osel = tid / 144;
    int rem = tid % 144;
    int bsel = rem / 36;
    int pix = rem % 36;
    int q = pix >> 2, s = pix & 3;
    int ox = (q % 3) * 2 + (s & 1);
    int oy = (q / 3) * 2 + (s >> 1);
    int oc = ocg * 4 + osel;
    int b = bg * 4 + bsel;
    const float* tb = tbl + osel * 1704;
    float* op = ws + (b * 32 + oc) * 36 + pix;
    for (int t = tch * 32; t < tch * 32 + 32; ++t) {
        float acc = 0.f;
        if (t > 0) {
            const uint4* rp = (const uint4*)(pb2 + (((size_t)(t - 1) * 48 + b) * 8 + oy) * 16);
#pragma unroll
            for (int ky = 0; ky < 3; ++ky) {
                uint4 rA = rp[ky * 2];
                uint4 rB = rp[ky * 2 + 1];
                unsigned int wd[8] = {rA.x, rA.y, rA.z, rA.w, rB.x, rB.y, rB.z, rB.w};
#pragma unroll
                for (int pr = 0; pr < 8; ++pr) {
                    unsigned int lo = (wd[pr] >> ox) & 7u;
                    unsigned int hi = (wd[pr] >> (16 + ox)) & 7u;
                    acc += tb[(pr * 3 + ky) * 71 + (int)(lo + 9u * hi)];
                }
            }
        }
        op[(size_t)t * 55296] = acc;
    }
}

// ---------------------------------------------------------------------------
// k_scan3: conv3 LIF + pool3 LIF. 864 waves; staging st3[wave*128 + t].
// ---------------------------------------------------------------------------
__global__ __launch_bounds__(256) void k_scan3(const float* __restrict__ ws,
                                               unsigned short* __restrict__ st3) {
    int wv = blockIdx.x * 4 + (threadIdx.x >> 6);   // 0..863
    int lane = threadIdx.x & 63;
    const float* wp = ws + wv * 64 + lane;
    unsigned short* so = st3 + (size_t)wv * 128;
    float u = 0.f, v = 0.f, rf = 0.f;
    float pu = 0.f, pv = 0.f, prf = 0.f;
    float sp = 0.f;
    unsigned int mb[4];
    float wbuf[16];
#pragma unroll
    for (int i = 0; i < 16; ++i) wbuf[i] = wp[(size_t)i * 55296];
    for (int tb = 0; tb < 128; tb += 16) {
#pragma unroll
        for (int j = 0; j < 16; ++j) {
            int t = tb + j;
            float w = wbuf[j];
            if (t + 16 < 128) wbuf[j] = wp[(size_t)(t + 16) * 55296];
            float cnt = dpp_add_xor2(dpp_add_xor1(sp));
            float ps = dyn_step(88.0f * cnt, pu, pv, prf);
            unsigned long long bal = __ballot(((lane & 3) == 0) && (ps > 0.5f));
            unsigned int m = compress4(bal);
            int sl = (t >> 1) & 3;
            mb[sl] = (t & 1) ? (mb[sl] | (m << 16)) : m;
            if ((t & 7) == 7 && lane == 0)
                *(uint4*)(so + (t & ~7)) = make_uint4(mb[0], mb[1], mb[2], mb[3]);
            sp = dyn_step(w, u, v, rf);
        }
    }
}

// k_mb3: st3 -> bf16 A-matrix a3[(t+1)*13824 + G] (delay-shift folded).
// G = (b*32+oc)*9 + q -> column oc*9+q of row t*48+b. 1755648 threads.
__global__ __launch_bounds__(256) void k_mb3(const unsigned short* __restrict__ st3,
                                             unsigned short* __restrict__ a3) {
    int gid = blockIdx.x * 256 + threadIdx.x;
    if (gid >= 1755648) return;
    int G = gid % 13824, t = gid / 13824;
    unsigned int bit = ((unsigned int)st3[(size_t)(G >> 4) * 128 + t] >> (G & 15)) & 1u;
    a3[(size_t)(t + 1) * 13824 + G] = bit ? 0x3F80 : 0;
}

// ---------------------------------------------------------------------------
// k_wsplit: wfc1[512][288] f32 -> wb[3][288][512] bf16 (bf16x3 split).
// ---------------------------------------------------------------------------
__global__ __launch_bounds__(256) void k_wsplit(const float* __restrict__ wfc1,
                                                unsigned short* __restrict__ wb) {
    int gid = blockIdx.x * 256 + threadIdx.x;
    int o = gid / 288, k = gid % 288;
    float w = wfc1[gid];
    unsigned short b0 = f2bf(w);
    float r1 = w - bf2f(b0);
    unsigned short b1 = f2bf(r1);
    float r2 = r1 - bf2f(b1);
    unsigned short b2 = f2bf(r2);
    wb[(size_t)k * 512 + o] = b0;
    wb[(size_t)147456 + k * 512 + o] = b1;
    wb[(size_t)294912 + k * 512 + o] = b2;
}

// ---------------------------------------------------------------------------
// k_fc1mm: wsf1[m][o] = A[m][k] x W[k][o] via mfma_f32_16x16x32_bf16.
// ---------------------------------------------------------------------------
__global__ __launch_bounds__(256) void k_fc1mm(const unsigned short* __restrict__ a3,
                                               const unsigned short* __restrict__ wb,
                                               float* __restrict__ wsf1) {
    __shared__ unsigned short Bs[16 * 872];
    int tid = threadIdx.x;
    int nt = blockIdx.x & 31;
    int mc = blockIdx.x >> 5;
    int n0 = nt * 16;
    for (int idx = tid; idx < 13824; idx += 256) {
        int kp = idx >> 4;
        int n = idx & 15;
        Bs[n * 872 + kp] = wb[(size_t)kp * 512 + n0 + n];
    }
    __syncthreads();
    int wave = tid >> 6;
    int lane = tid & 63;
    int ln = lane & 15, quad = lane >> 4;
#pragma unroll
    for (int i = 0; i < 4; ++i) {
        int m0 = (mc * 16 + wave * 4 + i) * 16;
        const unsigned short* arow = a3 + (size_t)(m0 + ln) * 288 + quad * 8;
        ffrag acc = {0.f, 0.f, 0.f, 0.f};
#pragma unroll
        for (int kb = 0; kb < 9; ++kb) {
            bfrag av = *(const bfrag*)(arow + kb * 32);
#pragma unroll
            for (int c = 0; c < 3; ++c) {
                bfrag bv = *(const bfrag*)(&Bs[ln * 872 + c * 288 + kb * 32 + quad * 8]);
                acc = __builtin_amdgcn_mfma_f32_16x16x32_bf16(av, bv, acc, 0, 0, 0);
            }
        }
        float* wout = wsf1 + (size_t)(m0 + quad * 4) * 512 + n0 + ln;
        wout[0] = acc[0];
        wout[512] = acc[1];
        wout[1024] = acc[2];
        wout[1536] = acc[3];
    }
}

// k_fc1s: fc1 LIF scan. Thread per (b,o); emits f32 spikes f1f[t][b*512+o].
__global__ __launch_bounds__(256) void k_fc1s(const float* __restrict__ wsf1,
                                              float* __restrict__ f1f) {
    int tid = blockIdx.x * 256 + threadIdx.x;   // 0..24575
    float u = 0.f, v = 0.f, rf = 0.f;
    float wbuf[16];
#pragma unroll
    for (int i = 0; i < 16; ++i) wbuf[i] = wsf1[(size_t)i * 24576 + tid];
    for (int tb = 0; tb < 128; tb += 16) {
#pragma unroll
        for (int j = 0; j < 16; ++j) {
            int t = tb + j;
            float w = wbuf[j];
            if (t + 16 < 128) wbuf[j] = wsf1[(size_t)(t + 16) * 24576 + tid];
            float s = dyn_step(w, u, v, rf);
            f1f[(size_t)t * 24576 + tid] = s;
        }
    }
}

// k_fc2w: fc2 wsum, parallel over t. Wave per (t,b).
__global__ __launch_bounds__(256) void k_fc2w(const float* __restrict__ f1f,
                                              const float* __restrict__ wfc2,
                                              float* __restrict__ wsf2) {
    int wv = blockIdx.x * 4 + (threadIdx.x >> 6);   // 0..6143
    int lane = threadIdx.x & 63;
    int b = wv % 48, t = wv / 48;
    int o = lane & 1, kq = lane >> 1;
    float acc = 0.f;
    if (t > 0) {
        const float* wp = wfc2 + o * 512 + kq * 16;
        const float* sp = f1f + (size_t)(t - 1) * 24576 + b * 512 + kq * 16;
#pragma unroll
        for (int i = 0; i < 16; ++i) acc += wp[i] * sp[i];
    }
#pragma unroll
    for (int m = 2; m < 64; m <<= 1) acc += __shfl_xor(acc, m, 64);
    if (lane < 2) wsf2[(size_t)t * 96 + b * 2 + o] = acc;
}

// k_fc2s: fc2 LIF scan + delay-shift into out [B,2,T]. 96 active threads.
__global__ __launch_bounds__(128) void k_fc2s(const float* __restrict__ wsf2,
                                              float* __restrict__ out) {
    int tid = threadIdx.x;
    if (tid >= 96) return;
    float* ob = out + tid * 128;       // tid = b*2+o
    ob[0] = 0.0f;
    float u = 0.f, v = 0.f, rf = 0.f;
    float wbuf[8];
#pragma unroll
    for (int i = 0; i < 8; ++i) wbuf[i] = wsf2[(size_t)i * 96 + tid];
    for (int tb = 0; tb < 128; tb += 8) {
#pragma unroll
        for (int j = 0; j < 8; ++j) {
            int t = tb + j;
            float w = wbuf[j];
            if (t + 8 < 128) wbuf[j] = wsf2[(size_t)(t + 8) * 96 + tid];
            float s = dyn_step(w, u, v, rf);
            if (t < 127) ob[t + 1] = s;
        }
    }
}

// ---------------------------------------------------------------------------
extern "C" void kernel_launch(void* const* d_in, const int* in_sizes, int n_in,
                              void* d_out, int out_size, void* d_ws, size_t ws_size,
                              hipStream_t stream) {
    const float* in   = (const float*)d_in[0];
    const float* w1   = (const float*)d_in[1];
    const float* w2   = (const float*)d_in[2];
    const float* w3   = (const float*)d_in[3];
    const float* wfc1 = (const float*)d_in[4];
    const float* wfc2 = (const float*)d_in[5];
    float* out = (float*)d_out;
    char* ws = (char*)d_ws;

    float*          slab = (float*)(ws);                       // 56,623,104 (conv wsums; wsf1 reuse)
    uint2*          xb   = (uint2*)(ws + 56623104);            //  2,752,512
    unsigned short* pb16 = (unsigned short*)(ws + 59375616);   //  1,376,256
    unsigned short* pb2  = (unsigned short*)(ws + 60751872);   //  1,572,864
    float*          f1f  = (float*)(ws + 64094208);            // 12,582,912
    unsigned short* a3   = (unsigned short*)(ws + 76677120);   //  3,538,944 [6144][288] bf16
    unsigned short* wb   = (unsigned short*)(ws + 80216064);   //    884,736 [3][288][512] bf16
    unsigned short* st1  = (unsigned short*)(ws + 81100800);   //    884,736 [3456 waves][128] u16
    unsigned short* st2  = (unsigned short*)(ws + 81985536);   //    442,368 [1728 waves][128] u16
    unsigned short* st3  = (unsigned short*)(ws + 82427904);   //    221,184 [864 waves][128] u16
    float*          wsf1 = (float*)(ws);                       // 12,582,912 (slab reuse, post-scan3)
    float*          wsf2 = (float*)(ws + 16777216);            //     49,152 (slab reuse, disjoint)
    // total 82,649,088 bytes

    hipMemsetAsync(xb, 0, 2752512, stream);     // pad rows 0/27
    hipMemsetAsync(pb16, 0, 1376256, stream);   // pad rows 0/13
    hipMemsetAsync(pb2, 0, 1572864, stream);    // pad rows 0/7
    hipMemsetAsync(a3, 0, 27648, stream);       // A rows t=0 (48*288 bf16)

    k_wsplit  <<<576, 256, 0, stream>>>(wfc1, wb);
    k_masks   <<<624, 256, 0, stream>>>(in, xb);
    k_wsum1<0><<<384, 576, 0, stream>>>(xb, w1, slab);
    k_scan1<0><<<432, 256, 0, stream>>>(slab, st1);
    k_wsum1<1><<<384, 576, 0, stream>>>(xb, w1, slab);
    k_scan1<1><<<432, 256, 0, stream>>>(slab, st1);
    k_mb1     <<<2304, 256, 0, stream>>>(st1, pb16);
    k_wsum2   <<<768, 576, 0, stream>>>(pb16, w2, slab);
    k_scan2   <<<192, 576, 0, stream>>>(slab, st2);
    k_mb2     <<<2304, 256, 0, stream>>>(st2, pb2);
    k_wsum3   <<<384, 576, 0, stream>>>(pb2, w3, slab);
    k_scan3   <<<216, 256, 0, stream>>>(slab, st3);
    k_mb3     <<<6858, 256, 0, stream>>>(st3, a3);
    k_fc1mm   <<<768, 256, 0, stream>>>(a3, wb, wsf1);
    k_fc1s    <<<96, 256, 0, stream>>>(wsf1, f1f);
    k_fc2w    <<<1536, 256, 0, stream>>>(f1f, wfc2, wsf2);
    k_fc2s    <<<1, 128, 0, stream>>>(wsf2, out);
}

// Round 10
// 570.830 us; speedup vs baseline: 4.5030x; 1.0557x over previous
//
#include <hip/hip_runtime.h>

// ---------------------------------------------------------------------------
// SNN forward, split-phase v4.1.
// wsum (parallel over t, LDS-LUT conv / MFMA fc) + scan (serial LIF).
// v4.1: wsum1/wsum3 t-chunks halved (grid x2) -> ~27 waves/CU resident
// (was 13.5): occupancy was the wsum1 limiter (24% occ, 31% VALU, LDS 50%).
// ---------------------------------------------------------------------------

#define THETA 5120.0f

typedef __attribute__((ext_vector_type(8))) short bfrag;   // 8 bf16 (4 VGPRs)
typedef __attribute__((ext_vector_type(4))) float ffrag;   // 4 f32 acc

__device__ __forceinline__ float dyn_step(float x, float& u, float& v, float& r) {
#pragma clang fp contract(off)
    u = 0.75f * u + 64.0f * x;          // current decay (1024/4096), W_SCALE=64
    float vn = 0.96875f * v + u;        // voltage decay (128/4096)
    vn = (r > 0.0f) ? 0.0f : vn;        // refractory clamp
    float s;
    if (vn >= THETA) { s = 1.0f; v = 0.0f; r = 1.0f; }
    else             { s = 0.0f; v = vn; r = fmaxf(r - 1.0f, 0.0f); }
    return s;
}

__device__ __forceinline__ float dpp_add_xor1(float x) {
    int y = __builtin_amdgcn_update_dpp(0, __float_as_int(x), 0xB1, 0xF, 0xF, true);
    return x + __int_as_float(y);
}
__device__ __forceinline__ float dpp_add_xor2(float x) {
    int y = __builtin_amdgcn_update_dpp(0, __float_as_int(x), 0x4E, 0xF, 0xF, true);
    return x + __int_as_float(y);
}

// compress bits at positions 4k (k=0..15) of a 64-bit word into 16 bits
__device__ __forceinline__ unsigned int compress4(unsigned long long x) {
    x &= 0x1111111111111111ull;
    x = (x | (x >> 3))  & 0x0303030303030303ull;
    x = (x | (x >> 6))  & 0x000F000F000F000Full;
    x = (x | (x >> 12)) & 0x000000FF000000FFull;
    x = (x | (x >> 24)) & 0xFFFFull;
    return (unsigned int)x;
}

__device__ __forceinline__ unsigned short f2bf(float f) {
    unsigned int u = __float_as_uint(f);
    unsigned int r = (u + 0x7FFFu + ((u >> 16) & 1u)) >> 16;   // RNE
    return (unsigned short)r;
}
__device__ __forceinline__ float bf2f(unsigned short b) {
    return __uint_as_float(((unsigned int)b) << 16);
}

// ---------------------------------------------------------------------------
// k_masks: in [B=48,C=4,26,26,T=128] f32 -> xb uint2[t][b][pr][28 rows]
// ---------------------------------------------------------------------------
__global__ __launch_bounds__(256) void k_masks(const float* __restrict__ in,
                                               uint2* __restrict__ xb) {
    int wv = blockIdx.x * 4 + (threadIdx.x >> 6);
    int lane = threadIdx.x & 63;
    int y = wv % 26; int r = wv / 26;
    int pr = r & 1; int b = r >> 1;
    int ch = lane >> 5;
    int x = lane & 31;
    int act = x < 26;
    int xc = act ? x : 25;
    const float4* src = (const float4*)(in + (size_t)(((b * 4 + pr * 2 + ch) * 26 + y) * 26 + xc) * 128);
    uint2* dst = xb + ((size_t)b * 2 + pr) * 28 + (y + 1);
    for (int t4 = 0; t4 < 32; ++t4) {
        float4 f = src[t4];
#pragma unroll
        for (int k = 0; k < 4; ++k) {
            float fv = (k == 0) ? f.x : (k == 1) ? f.y : (k == 2) ? f.z : f.w;
            unsigned long long bal = __ballot(act && (fv != 0.0f));
            if (lane == 0) {
                unsigned int lo = ((unsigned int)bal & 0x03FFFFFFu) << 1;
                unsigned int hi = ((unsigned int)(bal >> 32) & 0x03FFFFFFu) << 1;
                dst[(size_t)(t4 * 4 + k) * 2688] = make_uint2(lo, hi);
            }
        }
    }
}

// ---------------------------------------------------------------------------
// k_wsum1: conv1 wsum (4->8ch, 5x5, 26->24), oc half H. LUT 10-bit windows
// at lo + 33*hi. Block 576 = one (b,oc) image; t-chunk 32 (grid 768/half).
// QUAD-MAJOR pixel order: pix = q*4+s, q = py*12+px, s = dy*2+dx.
// ---------------------------------------------------------------------------
template<int H>
__global__ __launch_bounds__(576) void k_wsum1(const uint2* __restrict__ xb,
                                               const float* __restrict__ w1,
                                               float* __restrict__ ws) {
    __shared__ float wsh[100];
    __shared__ float tbl[10550];
    int tid = threadIdx.x;
    int tch = blockIdx.x & 3;
    int img = blockIdx.x >> 2;            // 0..191
    int b = img >> 2, oc4 = img & 3;
    int oc = H * 4 + oc4;
    if (tid < 100) wsh[tid] = w1[oc * 100 + tid];
    __syncthreads();
    for (int e = tid; e < 10240; e += 576) {
        int pr = e / 5120;
        int ky = (e / 1024) % 5;
        int i = e & 1023;
        int lo = i & 31, hi = i >> 5;
        float val = 0.f;
#pragma unroll
        for (int k = 0; k < 5; ++k)
            val += ((lo >> k) & 1) ? wsh[pr * 50 + ky * 5 + k] : 0.f;
#pragma unroll
        for (int k = 0; k < 5; ++k)
            val += ((hi >> k) & 1) ? wsh[pr * 50 + 25 + ky * 5 + k] : 0.f;
        tbl[(pr * 5 + ky) * 1055 + lo + 33 * hi] = val;
    }
    __syncthreads();
    int q = tid >> 2, s = tid & 3;
    int ox = (q % 12) * 2 + (s & 1);
    int oy = (q / 12) * 2 + (s >> 1);
    float* op = ws + (b * 4 + oc4) * 576 + tid;
    for (int t = tch * 32; t < tch * 32 + 32; ++t) {
        const uint2* rp = xb + ((size_t)t * 48 + b) * 56 + oy;
        float acc = 0.f;
#pragma unroll
        for (int ky = 0; ky < 5; ++ky) {
            uint2 r0 = rp[ky];
            uint2 r1 = rp[28 + ky];
            acc += tbl[ky * 1055 + (int)(((r0.x >> ox) & 31u) + 33u * ((r0.y >> ox) & 31u))];
            acc += tbl[5275 + ky * 1055 + (int)(((r1.x >> ox) & 31u) + 33u * ((r1.y >> ox) & 31u))];
        }
        op[(size_t)t * 110592] = acc;
    }
}

// ---------------------------------------------------------------------------
// k_scan1: conv1 LIF + pool1 LIF, oc half H. Wave = 64 neurons = 16 quads.
// Pool bits ballot-compressed to u16/t, burst-flushed (uint4 per 8 t) to
// st1[(H*1728 + wave)*128 + t]. 1728 waves/half.
// ---------------------------------------------------------------------------
template<int H>
__global__ __launch_bounds__(256) void k_scan1(const float* __restrict__ ws,
                                               unsigned short* __restrict__ st1) {
    int wv = blockIdx.x * 4 + (threadIdx.x >> 6);   // 0..1727
    int lane = threadIdx.x & 63;
    const float* wp = ws + wv * 64 + lane;
    unsigned short* so = st1 + ((size_t)(H * 1728 + wv)) * 128;
    float u = 0.f, v = 0.f, rf = 0.f;
    float pu = 0.f, pv = 0.f, prf = 0.f;
    float sp = 0.f;
    unsigned int mb[4];
    float wbuf[16];
#pragma unroll
    for (int i = 0; i < 16; ++i) wbuf[i] = wp[(size_t)i * 110592];
    for (int tb = 0; tb < 128; tb += 16) {
#pragma unroll
        for (int j = 0; j < 16; ++j) {
            int t = tb + j;
            float w = wbuf[j];
            if (t + 16 < 128) wbuf[j] = wp[(size_t)(t + 16) * 110592];
            float cnt = dpp_add_xor2(dpp_add_xor1(sp));
            float ps = dyn_step(88.0f * cnt, pu, pv, prf);
            unsigned long long bal = __ballot(((lane & 3) == 0) && (ps > 0.5f));
            unsigned int m = compress4(bal);
            int sl = (t >> 1) & 3;
            mb[sl] = (t & 1) ? (mb[sl] | (m << 16)) : m;
            if ((t & 7) == 7 && lane == 0)
                *(uint4*)(so + (t & ~7)) = make_uint4(mb[0], mb[1], mb[2], mb[3]);
            sp = dyn_step(w, u, v, rf);
        }
    }
}

// k_mb1: st1 -> pb16 row masks [t][b][y+1][oc] (12 bits << 1). 589824 thr.
__global__ __launch_bounds__(256) void k_mb1(const unsigned short* __restrict__ st1,
                                             unsigned short* __restrict__ pb16) {
    int gid = blockIdx.x * 256 + threadIdx.x;
    int oc = gid & 7; int r = gid >> 3;
    int y = r % 12; r /= 12;
    int b = r % 48; int t = r / 48;
    int base = (oc >> 2) * 1728 + (b * 4 + (oc & 3)) * 9;
    int Q0 = y * 12;
    int w0 = Q0 >> 4, off = Q0 & 15;
    unsigned int v0 = st1[(size_t)(base + w0) * 128 + t];
    unsigned int v1 = (off > 4) ? (unsigned int)st1[(size_t)(base + w0 + 1) * 128 + t] : 0u;
    unsigned int m = ((v0 >> off) | (v1 << (16 - off))) & 0xFFFu;
    pb16[((size_t)(t * 48 + b) * 14 + y + 1) * 8 + oc] = (unsigned short)(m << 1);
}

// ---------------------------------------------------------------------------
// k_wsum2: conv2 wsum (8->16ch, 3x3, 12->12). LUT 6-bit windows at lo+9*hi.
// QUAD-MAJOR pixel order: pix = q*4+s, q = py*6+px.
// ---------------------------------------------------------------------------
__global__ __launch_bounds__(576) void k_wsum2(const unsigned short* __restrict__ pb16,
                                               const float* __restrict__ w2,
                                               float* __restrict__ ws) {
    __shared__ float wsh[288];
    __shared__ float tbl[3408];
    int tid = threadIdx.x;
    int tch = blockIdx.x & 3;
    int g = blockIdx.x >> 2;              // 0..191
    if (tid < 288) {
        int oc = (g * 4 + tid / 72) & 15;
        wsh[tid] = w2[oc * 72 + (tid % 72)];
    }
    __syncthreads();
    for (int e = tid; e < 3072; e += 576) {
        int isel = e / 768;
        int pr = (e / 192) % 4;
        int ky = (e / 64) % 3;
        int i = e & 63;
        int lo = i & 7, hi = i >> 3;
        float val = 0.f;
#pragma unroll
        for (int k = 0; k < 3; ++k)
            val += ((lo >> k) & 1) ? wsh[isel * 72 + (2 * pr) * 9 + ky * 3 + k] : 0.f;
#pragma unroll
        for (int k = 0; k < 3; ++k)
            val += ((hi >> k) & 1) ? wsh[isel * 72 + (2 * pr + 1) * 9 + ky * 3 + k] : 0.f;
        tbl[isel * 852 + (pr * 3 + ky) * 71 + lo + 9 * hi] = val;
    }
    __syncthreads();
    int isel = tid / 144;
    int pix = tid % 144;
    int q = pix >> 2, s = pix & 3;
    int ox = (q % 6) * 2 + (s & 1);
    int oy = (q / 6) * 2 + (s >> 1);
    int img = g * 4 + isel;
    int b = img >> 4;
    const float* tb = tbl + isel * 852;
    float* op = ws + img * 144 + pix;
    for (int t = tch * 32; t < tch * 32 + 32; ++t) {
        float acc = 0.f;
        if (t > 0) {
            const uint4* rp = (const uint4*)(pb16 + (((size_t)(t - 1) * 48 + b) * 14 + oy) * 8);
#pragma unroll
            for (int ky = 0; ky < 3; ++ky) {
                uint4 row = rp[ky];
                unsigned int wd[4] = {row.x, row.y, row.z, row.w};
#pragma unroll
                for (int pr = 0; pr < 4; ++pr) {
                    unsigned int lo = (wd[pr] >> ox) & 7u;
                    unsigned int hi = (wd[pr] >> (16 + ox)) & 7u;
                    acc += tb[(pr * 3 + ky) * 71 + (int)(lo + 9u * hi)];
                }
            }
        }
        op[(size_t)t * 110592] = acc;
    }
}

// ---------------------------------------------------------------------------
// k_scan2: conv2 LIF + pool2 LIF. Block 576 = 4 images (9 waves); wave = 16
// quads. Staging st2[(g4*9 + wloc)*128 + t]. 1728 waves.
// ---------------------------------------------------------------------------
__global__ __launch_bounds__(576) void k_scan2(const float* __restrict__ ws,
                                               unsigned short* __restrict__ st2) {
    int tid = threadIdx.x;
    int wloc = tid >> 6, lane = tid & 63;
    int g4 = blockIdx.x;                  // 0..191
    const float* wp = ws + g4 * 576 + tid;
    unsigned short* so = st2 + ((size_t)(g4 * 9 + wloc)) * 128;
    float u = 0.f, v = 0.f, rf = 0.f;
    float pu = 0.f, pv = 0.f, prf = 0.f;
    float sp = 0.f;
    unsigned int mb[4];
    float wbuf[16];
#pragma unroll
    for (int i = 0; i < 16; ++i) wbuf[i] = wp[(size_t)i * 110592];
    for (int tb = 0; tb < 128; tb += 16) {
#pragma unroll
        for (int j = 0; j < 16; ++j) {
            int t = tb + j;
            float w = wbuf[j];
            if (t + 16 < 128) wbuf[j] = wp[(size_t)(t + 16) * 110592];
            float cnt = dpp_add_xor2(dpp_add_xor1(sp));
            float ps = dyn_step(88.0f * cnt, pu, pv, prf);
            unsigned long long bal = __ballot(((lane & 3) == 0) && (ps > 0.5f));
            unsigned int m = compress4(bal);
            int sl = (t >> 1) & 3;
            mb[sl] = (t & 1) ? (mb[sl] | (m << 16)) : m;
            if ((t & 7) == 7 && lane == 0)
                *(uint4*)(so + (t & ~7)) = make_uint4(mb[0], mb[1], mb[2], mb[3]);
            sp = dyn_step(w, u, v, rf);
        }
    }
}

// k_mb2: st2 -> pb2 row masks [t][b][y+1][oc] (6 bits << 1). 589824 thr.
__global__ __launch_bounds__(256) void k_mb2(const unsigned short* __restrict__ st2,
                                             unsigned short* __restrict__ pb2) {
    int gid = blockIdx.x * 256 + threadIdx.x;
    int oc = gid & 15; int r = gid >> 4;
    int y = r % 6; r /= 6;
    int b = r % 48; int t = r / 48;
    int img = b * 16 + oc;
    int g4 = img >> 2, lI = img & 3;
    int Q0 = lI * 36 + y * 6;
    int w0 = Q0 >> 4, off = Q0 & 15;
    unsigned int v0 = st2[(size_t)(g4 * 9 + w0) * 128 + t];
    unsigned int v1 = (off > 10) ? (unsigned int)st2[(size_t)(g4 * 9 + w0 + 1) * 128 + t] : 0u;
    unsigned int m = ((v0 >> off) | (v1 << (16 - off))) & 0x3Fu;
    pb2[((size_t)(t * 48 + b) * 8 + y + 1) * 16 + oc] = (unsigned short)(m << 1);
}

// ---------------------------------------------------------------------------
// k_wsum3: conv3 wsum (16->32ch, 3x3, 6->6). QUAD-MAJOR: pix = q*4+s,
// q = py*3+px. t-chunk 16 (grid 768).
// ---------------------------------------------------------------------------
__global__ __launch_bounds__(576) void k_wsum3(const unsigned short* __restrict__ pb2,
                                               const float* __restrict__ w3,
                                               float* __restrict__ ws) {
    __shared__ float wsh[576];
    __shared__ float tbl[6816];
    int tid = threadIdx.x;
    int tch = blockIdx.x & 7;
    int gb = blockIdx.x >> 3;             // 0..95 = ocg*12 + bg
    int ocg = gb / 12, bg = gb % 12;
    {
        int oc_t = ocg * 4 + tid / 144;
        wsh[tid] = w3[oc_t * 144 + (tid % 144)];
    }
    __syncthreads();
    for (int e = tid; e < 6144; e += 576) {
        int osel = e / 1536;
        int pr = (e / 192) % 8;
        int ky = (e / 64) % 3;
        int i = e & 63;
        int lo = i & 7, hi = i >> 3;
        float val = 0.f;
#pragma unroll
        for (int k = 0; k < 3; ++k)
            val += ((lo >> k) & 1) ? wsh[osel * 144 + (2 * pr) * 9 + ky * 3 + k] : 0.f;
#pragma unroll
        for (int k = 0; k < 3; ++k)
            val += ((hi >> k) & 1) ? wsh[osel * 144 + (2 * pr + 1) * 9 + ky * 3 + k] : 0.f;
        tbl[osel * 1704 + (pr * 3 + ky) * 71 + lo + 9 * hi] = val;
    }
    __syncthreads();
    int osel = tid / 144;
    int rem = tid % 144;
    int bsel = rem / 36;
    int pix = rem % 36;
    int q = pix >> 2, s = pix & 3;
    int ox = (q % 3) * 2 + (s & 1);
    int oy = (q / 3) * 2 + (s >> 1);
    int oc = ocg * 4 + osel;
    int b = bg * 4 + bsel;
    const float* tb = tbl + osel * 1704;
    float* op = ws + (b * 32 + oc) * 36 + pix;
    for (int t = tch * 16; t < tch * 16 + 16; ++t) {
        float acc = 0.f;
        if (t > 0) {
            const uint4* rp = (const uint4*)(pb2 + (((size_t)(t - 1) * 48 + b) * 8 + oy) * 16);
#pragma unroll
            for (int ky = 0; ky < 3; ++ky) {
                uint4 rA = rp[ky * 2];
                uint4 rB = rp[ky * 2 + 1];
                unsigned int wd[8] = {rA.x, rA.y, rA.z, rA.w, rB.x, rB.y, rB.z, rB.w};
#pragma unroll
                for (int pr = 0; pr < 8; ++pr) {
                    unsigned int lo = (wd[pr] >> ox) & 7u;
                    unsigned int hi = (wd[pr] >> (16 + ox)) & 7u;
                    acc += tb[(pr * 3 + ky) * 71 + (int)(lo + 9u * hi)];
                }
            }
        }
        op[(size_t)t * 55296] = acc;
    }
}

// ---------------------------------------------------------------------------
// k_scan3: conv3 LIF + pool3 LIF. 864 waves; staging st3[wave*128 + t].
// ---------------------------------------------------------------------------
__global__ __launch_bounds__(256) void k_scan3(const float* __restrict__ ws,
                                               unsigned short* __restrict__ st3) {
    int wv = blockIdx.x * 4 + (threadIdx.x >> 6);   // 0..863
    int lane = threadIdx.x & 63;
    const float* wp = ws + wv * 64 + lane;
    unsigned short* so = st3 + (size_t)wv * 128;
    float u = 0.f, v = 0.f, rf = 0.f;
    float pu = 0.f, pv = 0.f, prf = 0.f;
    float sp = 0.f;
    unsigned int mb[4];
    float wbuf[16];
#pragma unroll
    for (int i = 0; i < 16; ++i) wbuf[i] = wp[(size_t)i * 55296];
    for (int tb = 0; tb < 128; tb += 16) {
#pragma unroll
        for (int j = 0; j < 16; ++j) {
            int t = tb + j;
            float w = wbuf[j];
            if (t + 16 < 128) wbuf[j] = wp[(size_t)(t + 16) * 55296];
            float cnt = dpp_add_xor2(dpp_add_xor1(sp));
            float ps = dyn_step(88.0f * cnt, pu, pv, prf);
            unsigned long long bal = __ballot(((lane & 3) == 0) && (ps > 0.5f));
            unsigned int m = compress4(bal);
            int sl = (t >> 1) & 3;
            mb[sl] = (t & 1) ? (mb[sl] | (m << 16)) : m;
            if ((t & 7) == 7 && lane == 0)
                *(uint4*)(so + (t & ~7)) = make_uint4(mb[0], mb[1], mb[2], mb[3]);
            sp = dyn_step(w, u, v, rf);
        }
    }
}

// k_mb3: st3 -> bf16 A-matrix a3[(t+1)*13824 + G] (delay-shift folded).
__global__ __launch_bounds__(256) void k_mb3(const unsigned short* __restrict__ st3,
                                             unsigned short* __restrict__ a3) {
    int gid = blockIdx.x * 256 + threadIdx.x;
    if (gid >= 1755648) return;
    int G = gid % 13824, t = gid / 13824;
    unsigned int bit = ((unsigned int)st3[(size_t)(G >> 4) * 128 + t] >> (G & 15)) & 1u;
    a3[(size_t)(t + 1) * 13824 + G] = bit ? 0x3F80 : 0;
}

// ---------------------------------------------------------------------------
// k_wsplit: wfc1[512][288] f32 -> wb[3][288][512] bf16 (bf16x3 split).
// ---------------------------------------------------------------------------
__global__ __launch_bounds__(256) void k_wsplit(const float* __restrict__ wfc1,
                                                unsigned short* __restrict__ wb) {
    int gid = blockIdx.x * 256 + threadIdx.x;
    int o = gid / 288, k = gid % 288;
    float w = wfc1[gid];
    unsigned short b0 = f2bf(w);
    float r1 = w - bf2f(b0);
    unsigned short b1 = f2bf(r1);
    float r2 = r1 - bf2f(b1);
    unsigned short b2 = f2bf(r2);
    wb[(size_t)k * 512 + o] = b0;
    wb[(size_t)147456 + k * 512 + o] = b1;
    wb[(size_t)294912 + k * 512 + o] = b2;
}

// ---------------------------------------------------------------------------
// k_fc1mm: wsf1[m][o] = A[m][k] x W[k][o] via mfma_f32_16x16x32_bf16.
// ---------------------------------------------------------------------------
__global__ __launch_bounds__(256) void k_fc1mm(const unsigned short* __restrict__ a3,
                                               const unsigned short* __restrict__ wb,
                                               float* __restrict__ wsf1) {
    __shared__ unsigned short Bs[16 * 872];
    int tid = threadIdx.x;
    int nt = blockIdx.x & 31;
    int mc = blockIdx.x >> 5;
    int n0 = nt * 16;
    for (int idx = tid; idx < 13824; idx += 256) {
        int kp = idx >> 4;
        int n = idx & 15;
        Bs[n * 872 + kp] = wb[(size_t)kp * 512 + n0 + n];
    }
    __syncthreads();
    int wave = tid >> 6;
    int lane = tid & 63;
    int ln = lane & 15, quad = lane >> 4;
#pragma unroll
    for (int i = 0; i < 4; ++i) {
        int m0 = (mc * 16 + wave * 4 + i) * 16;
        const unsigned short* arow = a3 + (size_t)(m0 + ln) * 288 + quad * 8;
        ffrag acc = {0.f, 0.f, 0.f, 0.f};
#pragma unroll
        for (int kb = 0; kb < 9; ++kb) {
            bfrag av = *(const bfrag*)(arow + kb * 32);
#pragma unroll
            for (int c = 0; c < 3; ++c) {
                bfrag bv = *(const bfrag*)(&Bs[ln * 872 + c * 288 + kb * 32 + quad * 8]);
                acc = __builtin_amdgcn_mfma_f32_16x16x32_bf16(av, bv, acc, 0, 0, 0);
            }
        }
        float* wout = wsf1 + (size_t)(m0 + quad * 4) * 512 + n0 + ln;
        wout[0] = acc[0];
        wout[512] = acc[1];
        wout[1024] = acc[2];
        wout[1536] = acc[3];
    }
}

// k_fc1s: fc1 LIF scan. Thread per (b,o); emits f32 spikes f1f[t][b*512+o].
__global__ __launch_bounds__(256) void k_fc1s(const float* __restrict__ wsf1,
                                              float* __restrict__ f1f) {
    int tid = blockIdx.x * 256 + threadIdx.x;   // 0..24575
    float u = 0.f, v = 0.f, rf = 0.f;
    float wbuf[16];
#pragma unroll
    for (int i = 0; i < 16; ++i) wbuf[i] = wsf1[(size_t)i * 24576 + tid];
    for (int tb = 0; tb < 128; tb += 16) {
#pragma unroll
        for (int j = 0; j < 16; ++j) {
            int t = tb + j;
            float w = wbuf[j];
            if (t + 16 < 128) wbuf[j] = wsf1[(size_t)(t + 16) * 24576 + tid];
            float s = dyn_step(w, u, v, rf);
            f1f[(size_t)t * 24576 + tid] = s;
        }
    }
}

// k_fc2w: fc2 wsum, parallel over t. Wave per (t,b).
__global__ __launch_bounds__(256) void k_fc2w(const float* __restrict__ f1f,
                                              const float* __restrict__ wfc2,
                                              float* __restrict__ wsf2) {
    int wv = blockIdx.x * 4 + (threadIdx.x >> 6);   // 0..6143
    int lane = threadIdx.x & 63;
    int b = wv % 48, t = wv / 48;
    int o = lane & 1, kq = lane >> 1;
    float acc = 0.f;
    if (t > 0) {
        const float* wp = wfc2 + o * 512 + kq * 16;
        const float* sp = f1f + (size_t)(t - 1) * 24576 + b * 512 + kq * 16;
#pragma unroll
        for (int i = 0; i < 16; ++i) acc += wp[i] * sp[i];
    }
#pragma unroll
    for (int m = 2; m < 64; m <<= 1) acc += __shfl_xor(acc, m, 64);
    if (lane < 2) wsf2[(size_t)t * 96 + b * 2 + o] = acc;
}

// k_fc2s: fc2 LIF scan + delay-shift into out [B,2,T]. 96 active threads.
__global__ __launch_bounds__(128) void k_fc2s(const float* __restrict__ wsf2,
                                              float* __restrict__ out) {
    int tid = threadIdx.x;
    if (tid >= 96) return;
    float* ob = out + tid * 128;       // tid = b*2+o
    ob[0] = 0.0f;
    float u = 0.f, v = 0.f, rf = 0.f;
    float wbuf[8];
#pragma unroll
    for (int i = 0; i < 8; ++i) wbuf[i] = wsf2[(size_t)i * 96 + tid];
    for (int tb = 0; tb < 128; tb += 8) {
#pragma unroll
        for (int j = 0; j < 8; ++j) {
            int t = tb + j;
            float w = wbuf[j];
            if (t + 8 < 128) wbuf[j] = wsf2[(size_t)(t + 8) * 96 + tid];
            float s = dyn_step(w, u, v, rf);
            if (t < 127) ob[t + 1] = s;
        }
    }
}

// ---------------------------------------------------------------------------
extern "C" void kernel_launch(void* const* d_in, const int* in_sizes, int n_in,
                              void* d_out, int out_size, void* d_ws, size_t ws_size,
                              hipStream_t stream) {
    const float* in   = (const float*)d_in[0];
    const float* w1   = (const float*)d_in[1];
    const float* w2   = (const float*)d_in[2];
    const float* w3   = (const float*)d_in[3];
    const float* wfc1 = (const float*)d_in[4];
    const float* wfc2 = (const float*)d_in[5];
    float* out = (float*)d_out;
    char* ws = (char*)d_ws;

    float*          slab = (float*)(ws);                       // 56,623,104 (conv wsums; wsf1 reuse)
    uint2*          xb   = (uint2*)(ws + 56623104);            //  2,752,512
    unsigned short* pb16 = (unsigned short*)(ws + 59375616);   //  1,376,256
    unsigned short* pb2  = (unsigned short*)(ws + 60751872);   //  1,572,864
    float*          f1f  = (float*)(ws + 64094208);            // 12,582,912
    unsigned short* a3   = (unsigned short*)(ws + 76677120);   //  3,538,944 [6144][288] bf16
    unsigned short* wb   = (unsigned short*)(ws + 80216064);   //    884,736 [3][288][512] bf16
    unsigned short* st1  = (unsigned short*)(ws + 81100800);   //    884,736 [3456 waves][128] u16
    unsigned short* st2  = (unsigned short*)(ws + 81985536);   //    442,368 [1728 waves][128] u16
    unsigned short* st3  = (unsigned short*)(ws + 82427904);   //    221,184 [864 waves][128] u16
    float*          wsf1 = (float*)(ws);                       // 12,582,912 (slab reuse, post-scan3)
    float*          wsf2 = (float*)(ws + 16777216);            //     49,152 (slab reuse, disjoint)
    // total 82,649,088 bytes

    hipMemsetAsync(xb, 0, 2752512, stream);     // pad rows 0/27
    hipMemsetAsync(pb16, 0, 1376256, stream);   // pad rows 0/13
    hipMemsetAsync(pb2, 0, 1572864, stream);    // pad rows 0/7
    hipMemsetAsync(a3, 0, 27648, stream);       // A rows t=0 (48*288 bf16)

    k_wsplit  <<<576, 256, 0, stream>>>(wfc1, wb);
    k_masks   <<<624, 256, 0, stream>>>(in, xb);
    k_wsum1<0><<<768, 576, 0, stream>>>(xb, w1, slab);
    k_scan1<0><<<432, 256, 0, stream>>>(slab, st1);
    k_wsum1<1><<<768, 576, 0, stream>>>(xb, w1, slab);
    k_scan1<1><<<432, 256, 0, stream>>>(slab, st1);
    k_mb1     <<<2304, 256, 0, stream>>>(st1, pb16);
    k_wsum2   <<<768, 576, 0, stream>>>(pb16, w2, slab);
    k_scan2   <<<192, 576, 0, stream>>>(slab, st2);
    k_mb2     <<<2304, 256, 0, stream>>>(st2, pb2);
    k_wsum3   <<<768, 576, 0, stream>>>(pb2, w3, slab);
    k_scan3   <<<216, 256, 0, stream>>>(slab, st3);
    k_mb3     <<<6858, 256, 0, stream>>>(st3, a3);
    k_fc1mm   <<<768, 256, 0, stream>>>(a3, wb, wsf1);
    k_fc1s    <<<96, 256, 0, stream>>>(wsf1, f1f);
    k_fc2w    <<<1536, 256, 0, stream>>>(f1f, wfc2, wsf2);
    k_fc2s    <<<1, 128, 0, stream>>>(wsf2, out);
}

// Round 11
// 569.416 us; speedup vs baseline: 4.5141x; 1.0025x over previous
//
#include <hip/hip_runtime.h>

// ---------------------------------------------------------------------------
// SNN forward, split-phase v5.
// wsum (parallel over t, LDS-LUT conv / MFMA fc) + scan (serial LIF).
// v5: wsum slabs are T16-TILED: ws[(t/16)][neuron][t%16] so each neuron's
// 16 steps share one 64B line. Scans load float4 x4 per 16 iterations with
// one-block-ahead prefetch (round-10 profile: 442KB-stride per-t loads ran
// at ~1100 cyc/iter despite 16-deep prefetch; occupancy 14%, VALU 25%).
// ---------------------------------------------------------------------------

#define THETA 5120.0f

typedef __attribute__((ext_vector_type(8))) short bfrag;   // 8 bf16 (4 VGPRs)
typedef __attribute__((ext_vector_type(4))) float ffrag;   // 4 f32 acc

__device__ __forceinline__ float dyn_step(float x, float& u, float& v, float& r) {
#pragma clang fp contract(off)
    u = 0.75f * u + 64.0f * x;          // current decay (1024/4096), W_SCALE=64
    float vn = 0.96875f * v + u;        // voltage decay (128/4096)
    vn = (r > 0.0f) ? 0.0f : vn;        // refractory clamp
    float s;
    if (vn >= THETA) { s = 1.0f; v = 0.0f; r = 1.0f; }
    else             { s = 0.0f; v = vn; r = fmaxf(r - 1.0f, 0.0f); }
    return s;
}

__device__ __forceinline__ float dpp_add_xor1(float x) {
    int y = __builtin_amdgcn_update_dpp(0, __float_as_int(x), 0xB1, 0xF, 0xF, true);
    return x + __int_as_float(y);
}
__device__ __forceinline__ float dpp_add_xor2(float x) {
    int y = __builtin_amdgcn_update_dpp(0, __float_as_int(x), 0x4E, 0xF, 0xF, true);
    return x + __int_as_float(y);
}

// compress bits at positions 4k (k=0..15) of a 64-bit word into 16 bits
__device__ __forceinline__ unsigned int compress4(unsigned long long x) {
    x &= 0x1111111111111111ull;
    x = (x | (x >> 3))  & 0x0303030303030303ull;
    x = (x | (x >> 6))  & 0x000F000F000F000Full;
    x = (x | (x >> 12)) & 0x000000FF000000FFull;
    x = (x | (x >> 24)) & 0xFFFFull;
    return (unsigned int)x;
}

__device__ __forceinline__ unsigned short f2bf(float f) {
    unsigned int u = __float_as_uint(f);
    unsigned int r = (u + 0x7FFFu + ((u >> 16) & 1u)) >> 16;   // RNE
    return (unsigned short)r;
}
__device__ __forceinline__ float bf2f(unsigned short b) {
    return __uint_as_float(((unsigned int)b) << 16);
}

__device__ __forceinline__ float f4_elem(float4 v, int j) {
    return (j == 0) ? v.x : (j == 1) ? v.y : (j == 2) ? v.z : v.w;
}

// ---------------------------------------------------------------------------
// k_masks: in [B=48,C=4,26,26,T=128] f32 -> xb uint2[t][b][pr][28 rows]
// ---------------------------------------------------------------------------
__global__ __launch_bounds__(256) void k_masks(const float* __restrict__ in,
                                               uint2* __restrict__ xb) {
    int wv = blockIdx.x * 4 + (threadIdx.x >> 6);
    int lane = threadIdx.x & 63;
    int y = wv % 26; int r = wv / 26;
    int pr = r & 1; int b = r >> 1;
    int ch = lane >> 5;
    int x = lane & 31;
    int act = x < 26;
    int xc = act ? x : 25;
    const float4* src = (const float4*)(in + (size_t)(((b * 4 + pr * 2 + ch) * 26 + y) * 26 + xc) * 128);
    uint2* dst = xb + ((size_t)b * 2 + pr) * 28 + (y + 1);
    for (int t4 = 0; t4 < 32; ++t4) {
        float4 f = src[t4];
#pragma unroll
        for (int k = 0; k < 4; ++k) {
            float fv = f4_elem(f, k);
            unsigned long long bal = __ballot(act && (fv != 0.0f));
            if (lane == 0) {
                unsigned int lo = ((unsigned int)bal & 0x03FFFFFFu) << 1;
                unsigned int hi = ((unsigned int)(bal >> 32) & 0x03FFFFFFu) << 1;
                dst[(size_t)(t4 * 4 + k) * 2688] = make_uint2(lo, hi);
            }
        }
    }
}

// ---------------------------------------------------------------------------
// k_wsum1: conv1 wsum (4->8ch, 5x5, 26->24), oc half H. LUT 10-bit windows
// at lo + 33*hi. Block 576 = one (b,oc) image; t-chunk 32 (grid 768/half).
// QUAD-MAJOR pixel order. Output T16-tiled: ws[(t>>4)*1769472 + n*16 + (t&15)].
// ---------------------------------------------------------------------------
template<int H>
__global__ __launch_bounds__(576) void k_wsum1(const uint2* __restrict__ xb,
                                               const float* __restrict__ w1,
                                               float* __restrict__ ws) {
    __shared__ float wsh[100];
    __shared__ float tbl[10550];
    int tid = threadIdx.x;
    int tch = blockIdx.x & 3;
    int img = blockIdx.x >> 2;            // 0..191
    int b = img >> 2, oc4 = img & 3;
    int oc = H * 4 + oc4;
    if (tid < 100) wsh[tid] = w1[oc * 100 + tid];
    __syncthreads();
    for (int e = tid; e < 10240; e += 576) {
        int pr = e / 5120;
        int ky = (e / 1024) % 5;
        int i = e & 1023;
        int lo = i & 31, hi = i >> 5;
        float val = 0.f;
#pragma unroll
        for (int k = 0; k < 5; ++k)
            val += ((lo >> k) & 1) ? wsh[pr * 50 + ky * 5 + k] : 0.f;
#pragma unroll
        for (int k = 0; k < 5; ++k)
            val += ((hi >> k) & 1) ? wsh[pr * 50 + 25 + ky * 5 + k] : 0.f;
        tbl[(pr * 5 + ky) * 1055 + lo + 33 * hi] = val;
    }
    __syncthreads();
    int q = tid >> 2, s = tid & 3;
    int ox = (q % 12) * 2 + (s & 1);
    int oy = (q / 12) * 2 + (s >> 1);
    float* op = ws + ((size_t)(b * 4 + oc4) * 576 + tid) * 16;
    for (int t = tch * 32; t < tch * 32 + 32; ++t) {
        const uint2* rp = xb + ((size_t)t * 48 + b) * 56 + oy;
        float acc = 0.f;
#pragma unroll
        for (int ky = 0; ky < 5; ++ky) {
            uint2 r0 = rp[ky];
            uint2 r1 = rp[28 + ky];
            acc += tbl[ky * 1055 + (int)(((r0.x >> ox) & 31u) + 33u * ((r0.y >> ox) & 31u))];
            acc += tbl[5275 + ky * 1055 + (int)(((r1.x >> ox) & 31u) + 33u * ((r1.y >> ox) & 31u))];
        }
        op[(size_t)(t >> 4) * 1769472 + (t & 15)] = acc;
    }
}

// ---------------------------------------------------------------------------
// k_scan1: conv1 LIF + pool1 LIF, oc half H. Wave = 64 neurons = 16 quads.
// T16-tiled reads: float4 x4 per 16 steps, next block prefetched. Staging
// st1[(H*1728 + wave)*128 + t]. 1728 waves/half.
// ---------------------------------------------------------------------------
template<int H>
__global__ __launch_bounds__(256) void k_scan1(const float* __restrict__ ws,
                                               unsigned short* __restrict__ st1) {
    int wv = blockIdx.x * 4 + (threadIdx.x >> 6);   // 0..1727
    int lane = threadIdx.x & 63;
    const float* bp = ws + (size_t)(wv * 64 + lane) * 16;
    unsigned short* so = st1 + ((size_t)(H * 1728 + wv)) * 128;
    float u = 0.f, v = 0.f, rf = 0.f;
    float pu = 0.f, pv = 0.f, prf = 0.f;
    float sp = 0.f;
    unsigned int mb[4];
    float4 cur[4], nxt[4];
#pragma unroll
    for (int i = 0; i < 4; ++i) cur[i] = *(const float4*)(bp + i * 4);
    for (int tb = 0; tb < 8; ++tb) {
        if (tb < 7) {
            const float* np = bp + (size_t)(tb + 1) * 1769472;
#pragma unroll
            for (int i = 0; i < 4; ++i) nxt[i] = *(const float4*)(np + i * 4);
        }
#pragma unroll
        for (int j = 0; j < 16; ++j) {
            int t = tb * 16 + j;
            float w = f4_elem(cur[j >> 2], j & 3);
            float cnt = dpp_add_xor2(dpp_add_xor1(sp));
            float ps = dyn_step(88.0f * cnt, pu, pv, prf);
            unsigned long long bal = __ballot(((lane & 3) == 0) && (ps > 0.5f));
            unsigned int m = compress4(bal);
            int sl = (t >> 1) & 3;
            mb[sl] = (t & 1) ? (mb[sl] | (m << 16)) : m;
            if ((t & 7) == 7 && lane == 0)
                *(uint4*)(so + (t & ~7)) = make_uint4(mb[0], mb[1], mb[2], mb[3]);
            sp = dyn_step(w, u, v, rf);
        }
        if (tb < 7) {
#pragma unroll
            for (int i = 0; i < 4; ++i) cur[i] = nxt[i];
        }
    }
}

// k_mb1: st1 -> pb16 row masks [t][b][y+1][oc] (12 bits << 1). 589824 thr.
__global__ __launch_bounds__(256) void k_mb1(const unsigned short* __restrict__ st1,
                                             unsigned short* __restrict__ pb16) {
    int gid = blockIdx.x * 256 + threadIdx.x;
    int oc = gid & 7; int r = gid >> 3;
    int y = r % 12; r /= 12;
    int b = r % 48; int t = r / 48;
    int base = (oc >> 2) * 1728 + (b * 4 + (oc & 3)) * 9;
    int Q0 = y * 12;
    int w0 = Q0 >> 4, off = Q0 & 15;
    unsigned int v0 = st1[(size_t)(base + w0) * 128 + t];
    unsigned int v1 = (off > 4) ? (unsigned int)st1[(size_t)(base + w0 + 1) * 128 + t] : 0u;
    unsigned int m = ((v0 >> off) | (v1 << (16 - off))) & 0xFFFu;
    pb16[((size_t)(t * 48 + b) * 14 + y + 1) * 8 + oc] = (unsigned short)(m << 1);
}

// ---------------------------------------------------------------------------
// k_wsum2: conv2 wsum (8->16ch, 3x3, 12->12). LUT 6-bit windows at lo+9*hi.
// QUAD-MAJOR pixel order. Output T16-tiled.
// ---------------------------------------------------------------------------
__global__ __launch_bounds__(576) void k_wsum2(const unsigned short* __restrict__ pb16,
                                               const float* __restrict__ w2,
                                               float* __restrict__ ws) {
    __shared__ float wsh[288];
    __shared__ float tbl[3408];
    int tid = threadIdx.x;
    int tch = blockIdx.x & 3;
    int g = blockIdx.x >> 2;              // 0..191
    if (tid < 288) {
        int oc = (g * 4 + tid / 72) & 15;
        wsh[tid] = w2[oc * 72 + (tid % 72)];
    }
    __syncthreads();
    for (int e = tid; e < 3072; e += 576) {
        int isel = e / 768;
        int pr = (e / 192) % 4;
        int ky = (e / 64) % 3;
        int i = e & 63;
        int lo = i & 7, hi = i >> 3;
        float val = 0.f;
#pragma unroll
        for (int k = 0; k < 3; ++k)
            val += ((lo >> k) & 1) ? wsh[isel * 72 + (2 * pr) * 9 + ky * 3 + k] : 0.f;
#pragma unroll
        for (int k = 0; k < 3; ++k)
            val += ((hi >> k) & 1) ? wsh[isel * 72 + (2 * pr + 1) * 9 + ky * 3 + k] : 0.f;
        tbl[isel * 852 + (pr * 3 + ky) * 71 + lo + 9 * hi] = val;
    }
    __syncthreads();
    int isel = tid / 144;
    int pix = tid % 144;
    int q = pix >> 2, s = pix & 3;
    int ox = (q % 6) * 2 + (s & 1);
    int oy = (q / 6) * 2 + (s >> 1);
    int img = g * 4 + isel;
    int b = img >> 4;
    const float* tb = tbl + isel * 852;
    float* op = ws + ((size_t)img * 144 + pix) * 16;
    for (int t = tch * 32; t < tch * 32 + 32; ++t) {
        float acc = 0.f;
        if (t > 0) {
            const uint4* rp = (const uint4*)(pb16 + (((size_t)(t - 1) * 48 + b) * 14 + oy) * 8);
#pragma unroll
            for (int ky = 0; ky < 3; ++ky) {
                uint4 row = rp[ky];
                unsigned int wd[4] = {row.x, row.y, row.z, row.w};
#pragma unroll
                for (int pr = 0; pr < 4; ++pr) {
                    unsigned int lo = (wd[pr] >> ox) & 7u;
                    unsigned int hi = (wd[pr] >> (16 + ox)) & 7u;
                    acc += tb[(pr * 3 + ky) * 71 + (int)(lo + 9u * hi)];
                }
            }
        }
        op[(size_t)(t >> 4) * 1769472 + (t & 15)] = acc;
    }
}

// ---------------------------------------------------------------------------
// k_scan2: conv2 LIF + pool2 LIF. Block 576 = 4 images (9 waves); wave = 16
// quads. T16-tiled reads. Staging st2[(g4*9 + wloc)*128 + t]. 1728 waves.
// ---------------------------------------------------------------------------
__global__ __launch_bounds__(576) void k_scan2(const float* __restrict__ ws,
                                               unsigned short* __restrict__ st2) {
    int tid = threadIdx.x;
    int wloc = tid >> 6, lane = tid & 63;
    int g4 = blockIdx.x;                  // 0..191
    const float* bp = ws + (size_t)(g4 * 576 + tid) * 16;
    unsigned short* so = st2 + ((size_t)(g4 * 9 + wloc)) * 128;
    float u = 0.f, v = 0.f, rf = 0.f;
    float pu = 0.f, pv = 0.f, prf = 0.f;
    float sp = 0.f;
    unsigned int mb[4];
    float4 cur[4], nxt[4];
#pragma unroll
    for (int i = 0; i < 4; ++i) cur[i] = *(const float4*)(bp + i * 4);
    for (int tb = 0; tb < 8; ++tb) {
        if (tb < 7) {
            const float* np = bp + (size_t)(tb + 1) * 1769472;
#pragma unroll
            for (int i = 0; i < 4; ++i) nxt[i] = *(const float4*)(np + i * 4);
        }
#pragma unroll
        for (int j = 0; j < 16; ++j) {
            int t = tb * 16 + j;
            float w = f4_elem(cur[j >> 2], j & 3);
            float cnt = dpp_add_xor2(dpp_add_xor1(sp));
            float ps = dyn_step(88.0f * cnt, pu, pv, prf);
            unsigned long long bal = __ballot(((lane & 3) == 0) && (ps > 0.5f));
            unsigned int m = compress4(bal);
            int sl = (t >> 1) & 3;
            mb[sl] = (t & 1) ? (mb[sl] | (m << 16)) : m;
            if ((t & 7) == 7 && lane == 0)
                *(uint4*)(so + (t & ~7)) = make_uint4(mb[0], mb[1], mb[2], mb[3]);
            sp = dyn_step(w, u, v, rf);
        }
        if (tb < 7) {
#pragma unroll
            for (int i = 0; i < 4; ++i) cur[i] = nxt[i];
        }
    }
}

// k_mb2: st2 -> pb2 row masks [t][b][y+1][oc] (6 bits << 1). 589824 thr.
__global__ __launch_bounds__(256) void k_mb2(const unsigned short* __restrict__ st2,
                                             unsigned short* __restrict__ pb2) {
    int gid = blockIdx.x * 256 + threadIdx.x;
    int oc = gid & 15; int r = gid >> 4;
    int y = r % 6; r /= 6;
    int b = r % 48; int t = r / 48;
    int img = b * 16 + oc;
    int g4 = img >> 2, lI = img & 3;
    int Q0 = lI * 36 + y * 6;
    int w0 = Q0 >> 4, off = Q0 & 15;
    unsigned int v0 = st2[(size_t)(g4 * 9 + w0) * 128 + t];
    unsigned int v1 = (off > 10) ? (unsigned int)st2[(size_t)(g4 * 9 + w0 + 1) * 128 + t] : 0u;
    unsigned int m = ((v0 >> off) | (v1 << (16 - off))) & 0x3Fu;
    pb2[((size_t)(t * 48 + b) * 8 + y + 1) * 16 + oc] = (unsigned short)(m << 1);
}

// ---------------------------------------------------------------------------
// k_wsum3: conv3 wsum (16->32ch, 3x3, 6->6). QUAD-MAJOR. t-chunk 16 (grid
// 768). Output T16-tiled (tile index = tch).
// ---------------------------------------------------------------------------
__global__ __launch_bounds__(576) void k_wsum3(const unsigned short* __restrict__ pb2,
                                               const float* __restrict__ w3,
                                               float* __restrict__ ws) {
    __shared__ float wsh[576];
    __shared__ float tbl[6816];
    int tid = threadIdx.x;
    int tch = blockIdx.x & 7;
    int gb = blockIdx.x >> 3;             // 0..95 = ocg*12 + bg
    int ocg = gb / 12, bg = gb % 12;
    {
        int oc_t = ocg * 4 + tid / 144;
        wsh[tid] = w3[oc_t * 144 + (tid % 144)];
    }
    __syncthreads();
    for (int e = tid; e < 6144; e += 576) {
        int osel = e / 1536;
        int pr = (e / 192) % 8;
        int ky = (e / 64) % 3;
        int i = e & 63;
        int lo = i & 7, hi = i >> 3;
        float val = 0.f;
#pragma unroll
        for (int k = 0; k < 3; ++k)
            val += ((lo >> k) & 1) ? wsh[osel * 144 + (2 * pr) * 9 + ky * 3 + k] : 0.f;
#pragma unroll
        for (int k = 0; k < 3; ++k)
            val += ((hi >> k) & 1) ? wsh[osel * 144 + (2 * pr + 1) * 9 + ky * 3 + k] : 0.f;
        tbl[osel * 1704 + (pr * 3 + ky) * 71 + lo + 9 * hi] = val;
    }
    __syncthreads();
    int osel = tid / 144;
    int rem = tid % 144;
    int bsel = rem / 36;
    int pix = rem % 36;
    int q = pix >> 2, s = pix & 3;
    int ox = (q % 3) * 2 + (s & 1);
    int oy = (q / 3) * 2 + (s >> 1);
    int oc = ocg * 4 + osel;
    int b = bg * 4 + bsel;
    const float* tb = tbl + osel * 1704;
    float* op = ws + (size_t)tch * 884736 + ((size_t)(b * 32 + oc) * 36 + pix) * 16;
    for (int t = tch * 16; t < tch * 16 + 16; ++t) {
        float acc = 0.f;
        if (t > 0) {
            const uint4* rp = (const uint4*)(pb2 + (((size_t)(t - 1) * 48 + b) * 8 + oy) * 16);
#pragma unroll
            for (int ky = 0; ky < 3; ++ky) {
                uint4 rA = rp[ky * 2];
                uint4 rB = rp[ky * 2 + 1];
                unsigned int wd[8] = {rA.x, rA.y, rA.z, rA.w, rB.x, rB.y, rB.z, rB.w};
#pragma unroll
                for (int pr = 0; pr < 8; ++pr) {
                    unsigned int lo = (wd[pr] >> ox) & 7u;
                    unsigned int hi = (wd[pr] >> (16 + ox)) & 7u;
                    acc += tb[(pr * 3 + ky) * 71 + (int)(lo + 9u * hi)];
                }
            }
        }
        op[t & 15] = acc;
    }
}

// ---------------------------------------------------------------------------
// k_scan3: conv3 LIF + pool3 LIF. 864 waves; T16-tiled reads; staging
// st3[wave*128 + t].
// ---------------------------------------------------------------------------
__global__ __launch_bounds__(256) void k_scan3(const float* __restrict__ ws,
                                               unsigned short* __restrict__ st3) {
    int wv = blockIdx.x * 4 + (threadIdx.x >> 6);   // 0..863
    int lane = threadIdx.x & 63;
    const float* bp = ws + (size_t)(wv * 64 + lane) * 16;
    unsigned short* so = st3 + (size_t)wv * 128;
    float u = 0.f, v = 0.f, rf = 0.f;
    float pu = 0.f, pv = 0.f, prf = 0.f;
    float sp = 0.f;
    unsigned int mb[4];
    float4 cur[4], nxt[4];
#pragma unroll
    for (int i = 0; i < 4; ++i) cur[i] = *(const float4*)(bp + i * 4);
    for (int tb = 0; tb < 8; ++tb) {
        if (tb < 7) {
            const float* np = bp + (size_t)(tb + 1) * 884736;
#pragma unroll
            for (int i = 0; i < 4; ++i) nxt[i] = *(const float4*)(np + i * 4);
        }
#pragma unroll
        for (int j = 0; j < 16; ++j) {
            int t = tb * 16 + j;
            float w = f4_elem(cur[j >> 2], j & 3);
            float cnt = dpp_add_xor2(dpp_add_xor1(sp));
            float ps = dyn_step(88.0f * cnt, pu, pv, prf);
            unsigned long long bal = __ballot(((lane & 3) == 0) && (ps > 0.5f));
            unsigned int m = compress4(bal);
            int sl = (t >> 1) & 3;
            mb[sl] = (t & 1) ? (mb[sl] | (m << 16)) : m;
            if ((t & 7) == 7 && lane == 0)
                *(uint4*)(so + (t & ~7)) = make_uint4(mb[0], mb[1], mb[2], mb[3]);
            sp = dyn_step(w, u, v, rf);
        }
        if (tb < 7) {
#pragma unroll
            for (int i = 0; i < 4; ++i) cur[i] = nxt[i];
        }
    }
}

// k_mb3: st3 -> bf16 A-matrix a3[(t+1)*13824 + G] (delay-shift folded).
__global__ __launch_bounds__(256) void k_mb3(const unsigned short* __restrict__ st3,
                                             unsigned short* __restrict__ a3) {
    int gid = blockIdx.x * 256 + threadIdx.x;
    if (gid >= 1755648) return;
    int G = gid % 13824, t = gid / 13824;
    unsigned int bit = ((unsigned int)st3[(size_t)(G >> 4) * 128 + t] >> (G & 15)) & 1u;
    a3[(size_t)(t + 1) * 13824 + G] = bit ? 0x3F80 : 0;
}

// ---------------------------------------------------------------------------
// k_wsplit: wfc1[512][288] f32 -> wb[3][288][512] bf16 (bf16x3 split).
// ---------------------------------------------------------------------------
__global__ __launch_bounds__(256) void k_wsplit(const float* __restrict__ wfc1,
                                                unsigned short* __restrict__ wb) {
    int gid = blockIdx.x * 256 + threadIdx.x;
    int o = gid / 288, k = gid % 288;
    float w = wfc1[gid];
    unsigned short b0 = f2bf(w);
    float r1 = w - bf2f(b0);
    unsigned short b1 = f2bf(r1);
    float r2 = r1 - bf2f(b1);
    unsigned short b2 = f2bf(r2);
    wb[(size_t)k * 512 + o] = b0;
    wb[(size_t)147456 + k * 512 + o] = b1;
    wb[(size_t)294912 + k * 512 + o] = b2;
}

// ---------------------------------------------------------------------------
// k_fc1mm: wsf1 = A x W via mfma_f32_16x16x32_bf16. Epilogue writes T16-tiled
// wsf1[(t>>4)*393216 + (b*512+o)*16 + (t&15)] for the fc1s scan.
// ---------------------------------------------------------------------------
__global__ __launch_bounds__(256) void k_fc1mm(const unsigned short* __restrict__ a3,
                                               const unsigned short* __restrict__ wb,
                                               float* __restrict__ wsf1) {
    __shared__ unsigned short Bs[16 * 872];
    int tid = threadIdx.x;
    int nt = blockIdx.x & 31;
    int mc = blockIdx.x >> 5;
    int n0 = nt * 16;
    for (int idx = tid; idx < 13824; idx += 256) {
        int kp = idx >> 4;
        int n = idx & 15;
        Bs[n * 872 + kp] = wb[(size_t)kp * 512 + n0 + n];
    }
    __syncthreads();
    int wave = tid >> 6;
    int lane = tid & 63;
    int ln = lane & 15, quad = lane >> 4;
#pragma unroll
    for (int i = 0; i < 4; ++i) {
        int m0 = (mc * 16 + wave * 4 + i) * 16;
        const unsigned short* arow = a3 + (size_t)(m0 + ln) * 288 + quad * 8;
        ffrag acc = {0.f, 0.f, 0.f, 0.f};
#pragma unroll
        for (int kb = 0; kb < 9; ++kb) {
            bfrag av = *(const bfrag*)(arow + kb * 32);
#pragma unroll
            for (int c = 0; c < 3; ++c) {
                bfrag bv = *(const bfrag*)(&Bs[ln * 872 + c * 288 + kb * 32 + quad * 8]);
                acc = __builtin_amdgcn_mfma_f32_16x16x32_bf16(av, bv, acc, 0, 0, 0);
            }
        }
#pragma unroll
        for (int r = 0; r < 4; ++r) {
            int mrow = m0 + quad * 4 + r;
            int tt = mrow / 48;
            int bb = mrow - tt * 48;
            wsf1[(size_t)(tt >> 4) * 393216 + (size_t)((bb << 9) + n0 + ln) * 16 + (tt & 15)] = acc[r];
        }
    }
}

// k_fc1s: fc1 LIF scan, T16-tiled reads. Thread per (b,o); emits f32 spikes
// f1f[t][b*512+o].
__global__ __launch_bounds__(256) void k_fc1s(const float* __restrict__ wsf1,
                                              float* __restrict__ f1f) {
    int tid = blockIdx.x * 256 + threadIdx.x;   // 0..24575
    const float* bp = wsf1 + (size_t)tid * 16;
    float u = 0.f, v = 0.f, rf = 0.f;
    float4 cur[4], nxt[4];
#pragma unroll
    for (int i = 0; i < 4; ++i) cur[i] = *(const float4*)(bp + i * 4);
    for (int tb = 0; tb < 8; ++tb) {
        if (tb < 7) {
            const float* np = bp + (size_t)(tb + 1) * 393216;
#pragma unroll
            for (int i = 0; i < 4; ++i) nxt[i] = *(const float4*)(np + i * 4);
        }
#pragma unroll
        for (int j = 0; j < 16; ++j) {
            int t = tb * 16 + j;
            float w = f4_elem(cur[j >> 2], j & 3);
            float s = dyn_step(w, u, v, rf);
            f1f[(size_t)t * 24576 + tid] = s;
        }
        if (tb < 7) {
#pragma unroll
            for (int i = 0; i < 4; ++i) cur[i] = nxt[i];
        }
    }
}

// k_fc2w: fc2 wsum, parallel over t. Wave per (t,b).
__global__ __launch_bounds__(256) void k_fc2w(const float* __restrict__ f1f,
                                              const float* __restrict__ wfc2,
                                              float* __restrict__ wsf2) {
    int wv = blockIdx.x * 4 + (threadIdx.x >> 6);   // 0..6143
    int lane = threadIdx.x & 63;
    int b = wv % 48, t = wv / 48;
    int o = lane & 1, kq = lane >> 1;
    float acc = 0.f;
    if (t > 0) {
        const float* wp = wfc2 + o * 512 + kq * 16;
        const float* sp = f1f + (size_t)(t - 1) * 24576 + b * 512 + kq * 16;
#pragma unroll
        for (int i = 0; i < 16; ++i) acc += wp[i] * sp[i];
    }
#pragma unroll
    for (int m = 2; m < 64; m <<= 1) acc += __shfl_xor(acc, m, 64);
    if (lane < 2) wsf2[(size_t)t * 96 + b * 2 + o] = acc;
}

// k_fc2s: fc2 LIF scan + delay-shift into out [B,2,T]. 96 active threads.
__global__ __launch_bounds__(128) void k_fc2s(const float* __restrict__ wsf2,
                                              float* __restrict__ out) {
    int tid = threadIdx.x;
    if (tid >= 96) return;
    float* ob = out + tid * 128;       // tid = b*2+o
    ob[0] = 0.0f;
    float u = 0.f, v = 0.f, rf = 0.f;
    float wbuf[8];
#pragma unroll
    for (int i = 0; i < 8; ++i) wbuf[i] = wsf2[(size_t)i * 96 + tid];
    for (int tb = 0; tb < 128; tb += 8) {
#pragma unroll
        for (int j = 0; j < 8; ++j) {
            int t = tb + j;
            float w = wbuf[j];
            if (t + 8 < 128) wbuf[j] = wsf2[(size_t)(t + 8) * 96 + tid];
            float s = dyn_step(w, u, v, rf);
            if (t < 127) ob[t + 1] = s;
        }
    }
}

// ---------------------------------------------------------------------------
extern "C" void kernel_launch(void* const* d_in, const int* in_sizes, int n_in,
                              void* d_out, int out_size, void* d_ws, size_t ws_size,
                              hipStream_t stream) {
    const float* in   = (const float*)d_in[0];
    const float* w1   = (const float*)d_in[1];
    const float* w2   = (const float*)d_in[2];
    const float* w3   = (const float*)d_in[3];
    const float* wfc1 = (const float*)d_in[4];
    const float* wfc2 = (const float*)d_in[5];
    float* out = (float*)d_out;
    char* ws = (char*)d_ws;

    float*          slab = (float*)(ws);                       // 56,623,104 (conv wsums; wsf1 reuse)
    uint2*          xb   = (uint2*)(ws + 56623104);            //  2,752,512
    unsigned short* pb16 = (unsigned short*)(ws + 59375616);   //  1,376,256
    unsigned short* pb2  = (unsigned short*)(ws + 60751872);   //  1,572,864
    float*          f1f  = (float*)(ws + 64094208);            // 12,582,912
    unsigned short* a3   = (unsigned short*)(ws + 76677120);   //  3,538,944 [6144][288] bf16
    unsigned short* wb   = (unsigned short*)(ws + 80216064);   //    884,736 [3][288][512] bf16
    unsigned short* st1  = (unsigned short*)(ws + 81100800);   //    884,736 [3456 waves][128] u16
    unsigned short* st2  = (unsigned short*)(ws + 81985536);   //    442,368 [1728 waves][128] u16
    unsigned short* st3  = (unsigned short*)(ws + 82427904);   //    221,184 [864 waves][128] u16
    float*          wsf1 = (float*)(ws);                       // 12,582,912 (slab reuse, post-scan3)
    float*          wsf2 = (float*)(ws + 16777216);            //     49,152 (slab reuse, disjoint)
    // total 82,649,088 bytes

    hipMemsetAsync(xb, 0, 2752512, stream);     // pad rows 0/27
    hipMemsetAsync(pb16, 0, 1376256, stream);   // pad rows 0/13
    hipMemsetAsync(pb2, 0, 1572864, stream);    // pad rows 0/7
    hipMemsetAsync(a3, 0, 27648, stream);       // A rows t=0 (48*288 bf16)

    k_wsplit  <<<576, 256, 0, stream>>>(wfc1, wb);
    k_masks   <<<624, 256, 0, stream>>>(in, xb);
    k_wsum1<0><<<768, 576, 0, stream>>>(xb, w1, slab);
    k_scan1<0><<<432, 256, 0, stream>>>(slab, st1);
    k_wsum1<1><<<768, 576, 0, stream>>>(xb, w1, slab);
    k_scan1<1><<<432, 256, 0, stream>>>(slab, st1);
    k_mb1     <<<2304, 256, 0, stream>>>(st1, pb16);
    k_wsum2   <<<768, 576, 0, stream>>>(pb16, w2, slab);
    k_scan2   <<<192, 576, 0, stream>>>(slab, st2);
    k_mb2     <<<2304, 256, 0, stream>>>(st2, pb2);
    k_wsum3   <<<768, 576, 0, stream>>>(pb2, w3, slab);
    k_scan3   <<<216, 256, 0, stream>>>(slab, st3);
    k_mb3     <<<6858, 256, 0, stream>>>(st3, a3);
    k_fc1mm   <<<768, 256, 0, stream>>>(a3, wb, wsf1);
    k_fc1s    <<<96, 256, 0, stream>>>(wsf1, f1f);
    k_fc2w    <<<1536, 256, 0, stream>>>(f1f, wfc2, wsf2);
    k_fc2s    <<<1, 128, 0, stream>>>(wsf2, out);
}

// Round 12
// 498.296 us; speedup vs baseline: 5.1584x; 1.1427x over previous
//
#include <hip/hip_runtime.h>

// ---------------------------------------------------------------------------
// SNN forward, split-phase v5.1.
// wsum (parallel over t, LDS-LUT conv / MFMA fc) + scan (serial LIF).
// T16-tiled wsum slabs for scan-side locality; v5.1 fixes the write side:
// round-11 PMC showed 8.0x WRITE_SIZE amplification (scattered 4B stores
// retire as 32B sectors on gfx950). wsum kernels now stage 8-t groups in
// LDS and flush full aligned sectors (2 lanes x 16B per neuron).
// fc1mm/fc1s back to linear coalesced layout.
// ---------------------------------------------------------------------------

#define THETA 5120.0f

typedef __attribute__((ext_vector_type(8))) short bfrag;   // 8 bf16 (4 VGPRs)
typedef __attribute__((ext_vector_type(4))) float ffrag;   // 4 f32 acc

__device__ __forceinline__ float dyn_step(float x, float& u, float& v, float& r) {
#pragma clang fp contract(off)
    u = 0.75f * u + 64.0f * x;          // current decay (1024/4096), W_SCALE=64
    float vn = 0.96875f * v + u;        // voltage decay (128/4096)
    vn = (r > 0.0f) ? 0.0f : vn;        // refractory clamp
    float s;
    if (vn >= THETA) { s = 1.0f; v = 0.0f; r = 1.0f; }
    else             { s = 0.0f; v = vn; r = fmaxf(r - 1.0f, 0.0f); }
    return s;
}

__device__ __forceinline__ float dpp_add_xor1(float x) {
    int y = __builtin_amdgcn_update_dpp(0, __float_as_int(x), 0xB1, 0xF, 0xF, true);
    return x + __int_as_float(y);
}
__device__ __forceinline__ float dpp_add_xor2(float x) {
    int y = __builtin_amdgcn_update_dpp(0, __float_as_int(x), 0x4E, 0xF, 0xF, true);
    return x + __int_as_float(y);
}

// compress bits at positions 4k (k=0..15) of a 64-bit word into 16 bits
__device__ __forceinline__ unsigned int compress4(unsigned long long x) {
    x &= 0x1111111111111111ull;
    x = (x | (x >> 3))  & 0x0303030303030303ull;
    x = (x | (x >> 6))  & 0x000F000F000F000Full;
    x = (x | (x >> 12)) & 0x000000FF000000FFull;
    x = (x | (x >> 24)) & 0xFFFFull;
    return (unsigned int)x;
}

__device__ __forceinline__ unsigned short f2bf(float f) {
    unsigned int u = __float_as_uint(f);
    unsigned int r = (u + 0x7FFFu + ((u >> 16) & 1u)) >> 16;   // RNE
    return (unsigned short)r;
}
__device__ __forceinline__ float bf2f(unsigned short b) {
    return __uint_as_float(((unsigned int)b) << 16);
}

__device__ __forceinline__ float f4_elem(float4 v, int j) {
    return (j == 0) ? v.x : (j == 1) ? v.y : (j == 2) ? v.z : v.w;
}

// ---------------------------------------------------------------------------
// k_masks: in [B=48,C=4,26,26,T=128] f32 -> xb uint2[t][b][pr][28 rows]
// ---------------------------------------------------------------------------
__global__ __launch_bounds__(256) void k_masks(const float* __restrict__ in,
                                               uint2* __restrict__ xb) {
    int wv = blockIdx.x * 4 + (threadIdx.x >> 6);
    int lane = threadIdx.x & 63;
    int y = wv % 26; int r = wv / 26;
    int pr = r & 1; int b = r >> 1;
    int ch = lane >> 5;
    int x = lane & 31;
    int act = x < 26;
    int xc = act ? x : 25;
    const float4* src = (const float4*)(in + (size_t)(((b * 4 + pr * 2 + ch) * 26 + y) * 26 + xc) * 128);
    uint2* dst = xb + ((size_t)b * 2 + pr) * 28 + (y + 1);
    for (int t4 = 0; t4 < 32; ++t4) {
        float4 f = src[t4];
#pragma unroll
        for (int k = 0; k < 4; ++k) {
            float fv = f4_elem(f, k);
            unsigned long long bal = __ballot(act && (fv != 0.0f));
            if (lane == 0) {
                unsigned int lo = ((unsigned int)bal & 0x03FFFFFFu) << 1;
                unsigned int hi = ((unsigned int)(bal >> 32) & 0x03FFFFFFu) << 1;
                dst[(size_t)(t4 * 4 + k) * 2688] = make_uint2(lo, hi);
            }
        }
    }
}

// ---------------------------------------------------------------------------
// k_wsum1: conv1 wsum (4->8ch, 5x5, 26->24), oc half H. LUT 10-bit windows
// at lo + 33*hi. Block 576 = one (b,oc) image; t-chunk 32 (grid 768/half).
// QUAD-MAJOR pixels. T16-tiled output, LDS-staged sector flush.
// ---------------------------------------------------------------------------
template<int H>
__global__ __launch_bounds__(576) void k_wsum1(const uint2* __restrict__ xb,
                                               const float* __restrict__ w1,
                                               float* __restrict__ ws) {
    __shared__ float wsh[100];
    __shared__ float tbl[10550];
    __shared__ float stg[5184];           // 576 x 9 (8-t staging, padded)
    int tid = threadIdx.x;
    int tch = blockIdx.x & 3;
    int img = blockIdx.x >> 2;            // 0..191
    int b = img >> 2, oc4 = img & 3;
    int oc = H * 4 + oc4;
    if (tid < 100) wsh[tid] = w1[oc * 100 + tid];
    __syncthreads();
    for (int e = tid; e < 10240; e += 576) {
        int pr = e / 5120;
        int ky = (e / 1024) % 5;
        int i = e & 1023;
        int lo = i & 31, hi = i >> 5;
        float val = 0.f;
#pragma unroll
        for (int k = 0; k < 5; ++k)
            val += ((lo >> k) & 1) ? wsh[pr * 50 + ky * 5 + k] : 0.f;
#pragma unroll
        for (int k = 0; k < 5; ++k)
            val += ((hi >> k) & 1) ? wsh[pr * 50 + 25 + ky * 5 + k] : 0.f;
        tbl[(pr * 5 + ky) * 1055 + lo + 33 * hi] = val;
    }
    __syncthreads();
    int q = tid >> 2, s = tid & 3;
    int ox = (q % 12) * 2 + (s & 1);
    int oy = (q / 12) * 2 + (s >> 1);
    int nb = (b * 4 + oc4) * 576;
    int l0 = tid >> 1, qq = tid & 1;
    size_t g0 = (size_t)(nb + l0) * 16 + qq * 4;
    size_t g1 = (size_t)(nb + l0 + 288) * 16 + qq * 4;
    for (int sub = 0; sub < 4; ++sub) {
        int t0 = tch * 32 + sub * 8;
#pragma unroll
        for (int j = 0; j < 8; ++j) {
            int t = t0 + j;
            const uint2* rp = xb + ((size_t)t * 48 + b) * 56 + oy;
            float acc = 0.f;
#pragma unroll
            for (int ky = 0; ky < 5; ++ky) {
                uint2 r0 = rp[ky];
                uint2 r1 = rp[28 + ky];
                acc += tbl[ky * 1055 + (int)(((r0.x >> ox) & 31u) + 33u * ((r0.y >> ox) & 31u))];
                acc += tbl[5275 + ky * 1055 + (int)(((r1.x >> ox) & 31u) + 33u * ((r1.y >> ox) & 31u))];
            }
            stg[tid * 9 + j] = acc;
        }
        __syncthreads();
        size_t base = (size_t)(t0 >> 4) * 1769472 + ((t0 >> 3) & 1) * 8;
        int r0i = l0 * 9 + qq * 4;
        int r1i = (l0 + 288) * 9 + qq * 4;
        *(float4*)(ws + base + g0) = make_float4(stg[r0i], stg[r0i + 1], stg[r0i + 2], stg[r0i + 3]);
        *(float4*)(ws + base + g1) = make_float4(stg[r1i], stg[r1i + 1], stg[r1i + 2], stg[r1i + 3]);
        __syncthreads();
    }
}

// ---------------------------------------------------------------------------
// k_scan1: conv1 LIF + pool1 LIF, oc half H. Wave = 64 neurons = 16 quads.
// T16-tiled reads. Staging st1[(H*1728 + wave)*128 + t]. 1728 waves/half.
// ---------------------------------------------------------------------------
template<int H>
__global__ __launch_bounds__(256) void k_scan1(const float* __restrict__ ws,
                                               unsigned short* __restrict__ st1) {
    int wv = blockIdx.x * 4 + (threadIdx.x >> 6);   // 0..1727
    int lane = threadIdx.x & 63;
    const float* bp = ws + (size_t)(wv * 64 + lane) * 16;
    unsigned short* so = st1 + ((size_t)(H * 1728 + wv)) * 128;
    float u = 0.f, v = 0.f, rf = 0.f;
    float pu = 0.f, pv = 0.f, prf = 0.f;
    float sp = 0.f;
    unsigned int mb[4];
    float4 cur[4], nxt[4];
#pragma unroll
    for (int i = 0; i < 4; ++i) cur[i] = *(const float4*)(bp + i * 4);
    for (int tb = 0; tb < 8; ++tb) {
        if (tb < 7) {
            const float* np = bp + (size_t)(tb + 1) * 1769472;
#pragma unroll
            for (int i = 0; i < 4; ++i) nxt[i] = *(const float4*)(np + i * 4);
        }
#pragma unroll
        for (int j = 0; j < 16; ++j) {
            int t = tb * 16 + j;
            float w = f4_elem(cur[j >> 2], j & 3);
            float cnt = dpp_add_xor2(dpp_add_xor1(sp));
            float ps = dyn_step(88.0f * cnt, pu, pv, prf);
            unsigned long long bal = __ballot(((lane & 3) == 0) && (ps > 0.5f));
            unsigned int m = compress4(bal);
            int sl = (t >> 1) & 3;
            mb[sl] = (t & 1) ? (mb[sl] | (m << 16)) : m;
            if ((t & 7) == 7 && lane == 0)
                *(uint4*)(so + (t & ~7)) = make_uint4(mb[0], mb[1], mb[2], mb[3]);
            sp = dyn_step(w, u, v, rf);
        }
        if (tb < 7) {
#pragma unroll
            for (int i = 0; i < 4; ++i) cur[i] = nxt[i];
        }
    }
}

// k_mb1: st1 -> pb16 row masks [t][b][y+1][oc] (12 bits << 1). 589824 thr.
__global__ __launch_bounds__(256) void k_mb1(const unsigned short* __restrict__ st1,
                                             unsigned short* __restrict__ pb16) {
    int gid = blockIdx.x * 256 + threadIdx.x;
    int oc = gid & 7; int r = gid >> 3;
    int y = r % 12; r /= 12;
    int b = r % 48; int t = r / 48;
    int base = (oc >> 2) * 1728 + (b * 4 + (oc & 3)) * 9;
    int Q0 = y * 12;
    int w0 = Q0 >> 4, off = Q0 & 15;
    unsigned int v0 = st1[(size_t)(base + w0) * 128 + t];
    unsigned int v1 = (off > 4) ? (unsigned int)st1[(size_t)(base + w0 + 1) * 128 + t] : 0u;
    unsigned int m = ((v0 >> off) | (v1 << (16 - off))) & 0xFFFu;
    pb16[((size_t)(t * 48 + b) * 14 + y + 1) * 8 + oc] = (unsigned short)(m << 1);
}

// ---------------------------------------------------------------------------
// k_wsum2: conv2 wsum (8->16ch, 3x3, 12->12). LUT 6-bit windows at lo+9*hi.
// QUAD-MAJOR pixels. T16-tiled output, LDS-staged sector flush.
// ---------------------------------------------------------------------------
__global__ __launch_bounds__(576) void k_wsum2(const unsigned short* __restrict__ pb16,
                                               const float* __restrict__ w2,
                                               float* __restrict__ ws) {
    __shared__ float wsh[288];
    __shared__ float tbl[3408];
    __shared__ float stg[5184];
    int tid = threadIdx.x;
    int tch = blockIdx.x & 3;
    int g = blockIdx.x >> 2;              // 0..191
    if (tid < 288) {
        int oc = (g * 4 + tid / 72) & 15;
        wsh[tid] = w2[oc * 72 + (tid % 72)];
    }
    __syncthreads();
    for (int e = tid; e < 3072; e += 576) {
        int isel = e / 768;
        int pr = (e / 192) % 4;
        int ky = (e / 64) % 3;
        int i = e & 63;
        int lo = i & 7, hi = i >> 3;
        float val = 0.f;
#pragma unroll
        for (int k = 0; k < 3; ++k)
            val += ((lo >> k) & 1) ? wsh[isel * 72 + (2 * pr) * 9 + ky * 3 + k] : 0.f;
#pragma unroll
        for (int k = 0; k < 3; ++k)
            val += ((hi >> k) & 1) ? wsh[isel * 72 + (2 * pr + 1) * 9 + ky * 3 + k] : 0.f;
        tbl[isel * 852 + (pr * 3 + ky) * 71 + lo + 9 * hi] = val;
    }
    __syncthreads();
    int isel = tid / 144;
    int pix = tid % 144;
    int q = pix >> 2, s = pix & 3;
    int ox = (q % 6) * 2 + (s & 1);
    int oy = (q / 6) * 2 + (s >> 1);
    int b = (g * 4 + isel) >> 4;
    const float* tb = tbl + isel * 852;
    int nb = g * 576;
    int l0 = tid >> 1, qq = tid & 1;
    size_t g0 = (size_t)(nb + l0) * 16 + qq * 4;
    size_t g1 = (size_t)(nb + l0 + 288) * 16 + qq * 4;
    for (int sub = 0; sub < 4; ++sub) {
        int t0 = tch * 32 + sub * 8;
#pragma unroll
        for (int j = 0; j < 8; ++j) {
            int t = t0 + j;
            float acc = 0.f;
            if (t > 0) {
                const uint4* rp = (const uint4*)(pb16 + (((size_t)(t - 1) * 48 + b) * 14 + oy) * 8);
#pragma unroll
                for (int ky = 0; ky < 3; ++ky) {
                    uint4 row = rp[ky];
                    unsigned int wd[4] = {row.x, row.y, row.z, row.w};
#pragma unroll
                    for (int pr = 0; pr < 4; ++pr) {
                        unsigned int lo = (wd[pr] >> ox) & 7u;
                        unsigned int hi = (wd[pr] >> (16 + ox)) & 7u;
                        acc += tb[(pr * 3 + ky) * 71 + (int)(lo + 9u * hi)];
                    }
                }
            }
            stg[tid * 9 + j] = acc;
        }
        __syncthreads();
        size_t base = (size_t)(t0 >> 4) * 1769472 + ((t0 >> 3) & 1) * 8;
        int r0i = l0 * 9 + qq * 4;
        int r1i = (l0 + 288) * 9 + qq * 4;
        *(float4*)(ws + base + g0) = make_float4(stg[r0i], stg[r0i + 1], stg[r0i + 2], stg[r0i + 3]);
        *(float4*)(ws + base + g1) = make_float4(stg[r1i], stg[r1i + 1], stg[r1i + 2], stg[r1i + 3]);
        __syncthreads();
    }
}

// ---------------------------------------------------------------------------
// k_scan2: conv2 LIF + pool2 LIF. Block 576 = 4 images (9 waves); wave = 16
// quads. T16-tiled reads. Staging st2[(g4*9 + wloc)*128 + t]. 1728 waves.
// ---------------------------------------------------------------------------
__global__ __launch_bounds__(576) void k_scan2(const float* __restrict__ ws,
                                               unsigned short* __restrict__ st2) {
    int tid = threadIdx.x;
    int wloc = tid >> 6, lane = tid & 63;
    int g4 = blockIdx.x;                  // 0..191
    const float* bp = ws + (size_t)(g4 * 576 + tid) * 16;
    unsigned short* so = st2 + ((size_t)(g4 * 9 + wloc)) * 128;
    float u = 0.f, v = 0.f, rf = 0.f;
    float pu = 0.f, pv = 0.f, prf = 0.f;
    float sp = 0.f;
    unsigned int mb[4];
    float4 cur[4], nxt[4];
#pragma unroll
    for (int i = 0; i < 4; ++i) cur[i] = *(const float4*)(bp + i * 4);
    for (int tb = 0; tb < 8; ++tb) {
        if (tb < 7) {
            const float* np = bp + (size_t)(tb + 1) * 1769472;
#pragma unroll
            for (int i = 0; i < 4; ++i) nxt[i] = *(const float4*)(np + i * 4);
        }
#pragma unroll
        for (int j = 0; j < 16; ++j) {
            int t = tb * 16 + j;
            float w = f4_elem(cur[j >> 2], j & 3);
            float cnt = dpp_add_xor2(dpp_add_xor1(sp));
            float ps = dyn_step(88.0f * cnt, pu, pv, prf);
            unsigned long long bal = __ballot(((lane & 3) == 0) && (ps > 0.5f));
            unsigned int m = compress4(bal);
            int sl = (t >> 1) & 3;
            mb[sl] = (t & 1) ? (mb[sl] | (m << 16)) : m;
            if ((t & 7) == 7 && lane == 0)
                *(uint4*)(so + (t & ~7)) = make_uint4(mb[0], mb[1], mb[2], mb[3]);
            sp = dyn_step(w, u, v, rf);
        }
        if (tb < 7) {
#pragma unroll
            for (int i = 0; i < 4; ++i) cur[i] = nxt[i];
        }
    }
}

// k_mb2: st2 -> pb2 row masks [t][b][y+1][oc] (6 bits << 1). 589824 thr.
__global__ __launch_bounds__(256) void k_mb2(const unsigned short* __restrict__ st2,
                                             unsigned short* __restrict__ pb2) {
    int gid = blockIdx.x * 256 + threadIdx.x;
    int oc = gid & 15; int r = gid >> 4;
    int y = r % 6; r /= 6;
    int b = r % 48; int t = r / 48;
    int img = b * 16 + oc;
    int g4 = img >> 2, lI = img & 3;
    int Q0 = lI * 36 + y * 6;
    int w0 = Q0 >> 4, off = Q0 & 15;
    unsigned int v0 = st2[(size_t)(g4 * 9 + w0) * 128 + t];
    unsigned int v1 = (off > 10) ? (unsigned int)st2[(size_t)(g4 * 9 + w0 + 1) * 128 + t] : 0u;
    unsigned int m = ((v0 >> off) | (v1 << (16 - off))) & 0x3Fu;
    pb2[((size_t)(t * 48 + b) * 8 + y + 1) * 16 + oc] = (unsigned short)(m << 1);
}

// ---------------------------------------------------------------------------
// k_wsum3: conv3 wsum (16->32ch, 3x3, 6->6). QUAD-MAJOR. t-chunk 16 (grid
// 768). T16-tiled output (tile = tch), LDS-staged sector flush.
// ---------------------------------------------------------------------------
__global__ __launch_bounds__(576) void k_wsum3(const unsigned short* __restrict__ pb2,
                                               const float* __restrict__ w3,
                                               float* __restrict__ ws) {
    __shared__ float wsh[576];
    __shared__ float tbl[6816];
    __shared__ float stg[5184];
    int tid = threadIdx.x;
    int tch = blockIdx.x & 7;
    int gb = blockIdx.x >> 3;             // 0..95 = ocg*12 + bg
    int ocg = gb / 12, bg = gb % 12;
    {
        int oc_t = ocg * 4 + tid / 144;
        wsh[tid] = w3[oc_t * 144 + (tid % 144)];
    }
    __syncthreads();
    for (int e = tid; e < 6144; e += 576) {
        int osel = e / 1536;
        int pr = (e / 192) % 8;
        int ky = (e / 64) % 3;
        int i = e & 63;
        int lo = i & 7, hi = i >> 3;
        float val = 0.f;
#pragma unroll
        for (int k = 0; k < 3; ++k)
            val += ((lo >> k) & 1) ? wsh[osel * 144 + (2 * pr) * 9 + ky * 3 + k] : 0.f;
#pragma unroll
        for (int k = 0; k < 3; ++k)
            val += ((hi >> k) & 1) ? wsh[osel * 144 + (2 * pr + 1) * 9 + ky * 3 + k] : 0.f;
        tbl[osel * 1704 + (pr * 3 + ky) * 71 + lo + 9 * hi] = val;
    }
    __syncthreads();
    int osel = tid / 144;
    int rem = tid % 144;
    int bsel = rem / 36;
    int pix = rem % 36;
    int q = pix >> 2, s = pix & 3;
    int ox = (q % 3) * 2 + (s & 1);
    int oy = (q / 3) * 2 + (s >> 1);
    int oc = ocg * 4 + osel;
    int b = bg * 4 + bsel;
    const float* tb = tbl + osel * 1704;
    // flush addresses for this thread's two staged rows
    int l0 = tid >> 1, qq = tid & 1;
    auto nglob = [&](int l) {
        int os = l / 144; int rm = l % 144;
        int bs = rm / 36; int px = rm % 36;
        return ((bg * 4 + bs) * 32 + ocg * 4 + os) * 36 + px;
    };
    size_t g0 = (size_t)nglob(l0) * 16 + qq * 4;
    size_t g1 = (size_t)nglob(l0 + 288) * 16 + qq * 4;
    for (int sub = 0; sub < 2; ++sub) {
        int t0 = tch * 16 + sub * 8;
#pragma unroll
        for (int j = 0; j < 8; ++j) {
            int t = t0 + j;
            float acc = 0.f;
            if (t > 0) {
                const uint4* rp = (const uint4*)(pb2 + (((size_t)(t - 1) * 48 + b) * 8 + oy) * 16);
#pragma unroll
                for (int ky = 0; ky < 3; ++ky) {
                    uint4 rA = rp[ky * 2];
                    uint4 rB = rp[ky * 2 + 1];
                    unsigned int wd[8] = {rA.x, rA.y, rA.z, rA.w, rB.x, rB.y, rB.z, rB.w};
#pragma unroll
                    for (int pr = 0; pr < 8; ++pr) {
                        unsigned int lo = (wd[pr] >> ox) & 7u;
                        unsigned int hi = (wd[pr] >> (16 + ox)) & 7u;
                        acc += tb[(pr * 3 + ky) * 71 + (int)(lo + 9u * hi)];
                    }
                }
            }
            stg[tid * 9 + j] = acc;
        }
        __syncthreads();
        size_t base = (size_t)tch * 884736 + sub * 8;
        int r0i = l0 * 9 + qq * 4;
        int r1i = (l0 + 288) * 9 + qq * 4;
        *(float4*)(ws + base + g0) = make_float4(stg[r0i], stg[r0i + 1], stg[r0i + 2], stg[r0i + 3]);
        *(float4*)(ws + base + g1) = make_float4(stg[r1i], stg[r1i + 1], stg[r1i + 2], stg[r1i + 3]);
        __syncthreads();
    }
}

// ---------------------------------------------------------------------------
// k_scan3: conv3 LIF + pool3 LIF. 864 waves; T16-tiled reads; staging
// st3[wave*128 + t].
// ---------------------------------------------------------------------------
__global__ __launch_bounds__(256) void k_scan3(const float* __restrict__ ws,
                                               unsigned short* __restrict__ st3) {
    int wv = blockIdx.x * 4 + (threadIdx.x >> 6);   // 0..863
    int lane = threadIdx.x & 63;
    const float* bp = ws + (size_t)(wv * 64 + lane) * 16;
    unsigned short* so = st3 + (size_t)wv * 128;
    float u = 0.f, v = 0.f, rf = 0.f;
    float pu = 0.f, pv = 0.f, prf = 0.f;
    float sp = 0.f;
    unsigned int mb[4];
    float4 cur[4], nxt[4];
#pragma unroll
    for (int i = 0; i < 4; ++i) cur[i] = *(const float4*)(bp + i * 4);
    for (int tb = 0; tb < 8; ++tb) {
        if (tb < 7) {
            const float* np = bp + (size_t)(tb + 1) * 884736;
#pragma unroll
            for (int i = 0; i < 4; ++i) nxt[i] = *(const float4*)(np + i * 4);
        }
#pragma unroll
        for (int j = 0; j < 16; ++j) {
            int t = tb * 16 + j;
            float w = f4_elem(cur[j >> 2], j & 3);
            float cnt = dpp_add_xor2(dpp_add_xor1(sp));
            float ps = dyn_step(88.0f * cnt, pu, pv, prf);
            unsigned long long bal = __ballot(((lane & 3) == 0) && (ps > 0.5f));
            unsigned int m = compress4(bal);
            int sl = (t >> 1) & 3;
            mb[sl] = (t & 1) ? (mb[sl] | (m << 16)) : m;
            if ((t & 7) == 7 && lane == 0)
                *(uint4*)(so + (t & ~7)) = make_uint4(mb[0], mb[1], mb[2], mb[3]);
            sp = dyn_step(w, u, v, rf);
        }
        if (tb < 7) {
#pragma unroll
            for (int i = 0; i < 4; ++i) cur[i] = nxt[i];
        }
    }
}

// k_mb3: st3 -> bf16 A-matrix a3[(t+1)*13824 + G] (delay-shift folded).
__global__ __launch_bounds__(256) void k_mb3(const unsigned short* __restrict__ st3,
                                             unsigned short* __restrict__ a3) {
    int gid = blockIdx.x * 256 + threadIdx.x;
    if (gid >= 1755648) return;
    int G = gid % 13824, t = gid / 13824;
    unsigned int bit = ((unsigned int)st3[(size_t)(G >> 4) * 128 + t] >> (G & 15)) & 1u;
    a3[(size_t)(t + 1) * 13824 + G] = bit ? 0x3F80 : 0;
}

// ---------------------------------------------------------------------------
// k_wsplit: wfc1[512][288] f32 -> wb[3][288][512] bf16 (bf16x3 split).
// ---------------------------------------------------------------------------
__global__ __launch_bounds__(256) void k_wsplit(const float* __restrict__ wfc1,
                                                unsigned short* __restrict__ wb) {
    int gid = blockIdx.x * 256 + threadIdx.x;
    int o = gid / 288, k = gid % 288;
    float w = wfc1[gid];
    unsigned short b0 = f2bf(w);
    float r1 = w - bf2f(b0);
    unsigned short b1 = f2bf(r1);
    float r2 = r1 - bf2f(b1);
    unsigned short b2 = f2bf(r2);
    wb[(size_t)k * 512 + o] = b0;
    wb[(size_t)147456 + k * 512 + o] = b1;
    wb[(size_t)294912 + k * 512 + o] = b2;
}

// ---------------------------------------------------------------------------
// k_fc1mm: wsf1[m][o] = A x W via mfma_f32_16x16x32_bf16. Linear coalesced
// epilogue (wsf1[m*512+n]).
// ---------------------------------------------------------------------------
__global__ __launch_bounds__(256) void k_fc1mm(const unsigned short* __restrict__ a3,
                                               const unsigned short* __restrict__ wb,
                                               float* __restrict__ wsf1) {
    __shared__ unsigned short Bs[16 * 872];
    int tid = threadIdx.x;
    int nt = blockIdx.x & 31;
    int mc = blockIdx.x >> 5;
    int n0 = nt * 16;
    for (int idx = tid; idx < 13824; idx += 256) {
        int kp = idx >> 4;
        int n = idx & 15;
        Bs[n * 872 + kp] = wb[(size_t)kp * 512 + n0 + n];
    }
    __syncthreads();
    int wave = tid >> 6;
    int lane = tid & 63;
    int ln = lane & 15, quad = lane >> 4;
#pragma unroll
    for (int i = 0; i < 4; ++i) {
        int m0 = (mc * 16 + wave * 4 + i) * 16;
        const unsigned short* arow = a3 + (size_t)(m0 + ln) * 288 + quad * 8;
        ffrag acc = {0.f, 0.f, 0.f, 0.f};
#pragma unroll
        for (int kb = 0; kb < 9; ++kb) {
            bfrag av = *(const bfrag*)(arow + kb * 32);
#pragma unroll
            for (int c = 0; c < 3; ++c) {
                bfrag bv = *(const bfrag*)(&Bs[ln * 872 + c * 288 + kb * 32 + quad * 8]);
                acc = __builtin_amdgcn_mfma_f32_16x16x32_bf16(av, bv, acc, 0, 0, 0);
            }
        }
        float* wout = wsf1 + (size_t)(m0 + quad * 4) * 512 + n0 + ln;
        wout[0] = acc[0];
        wout[512] = acc[1];
        wout[1024] = acc[2];
        wout[1536] = acc[3];
    }
}

// k_fc1s: fc1 LIF scan, linear strided reads + 16-deep prefetch.
__global__ __launch_bounds__(256) void k_fc1s(const float* __restrict__ wsf1,
                                              float* __restrict__ f1f) {
    int tid = blockIdx.x * 256 + threadIdx.x;   // 0..24575
    float u = 0.f, v = 0.f, rf = 0.f;
    float wbuf[16];
#pragma unroll
    for (int i = 0; i < 16; ++i) wbuf[i] = wsf1[(size_t)i * 24576 + tid];
    for (int tb = 0; tb < 128; tb += 16) {
#pragma unroll
        for (int j = 0; j < 16; ++j) {
            int t = tb + j;
            float w = wbuf[j];
            if (t + 16 < 128) wbuf[j] = wsf1[(size_t)(t + 16) * 24576 + tid];
            float s = dyn_step(w, u, v, rf);
            f1f[(size_t)t * 24576 + tid] = s;
        }
    }
}

// k_fc2w: fc2 wsum, parallel over t. Wave per (t,b).
__global__ __launch_bounds__(256) void k_fc2w(const float* __restrict__ f1f,
                                              const float* __restrict__ wfc2,
                                              float* __restrict__ wsf2) {
    int wv = blockIdx.x * 4 + (threadIdx.x >> 6);   // 0..6143
    int lane = threadIdx.x & 63;
    int b = wv % 48, t = wv / 48;
    int o = lane & 1, kq = lane >> 1;
    float acc = 0.f;
    if (t > 0) {
        const float* wp = wfc2 + o * 512 + kq * 16;
        const float* sp = f1f + (size_t)(t - 1) * 24576 + b * 512 + kq * 16;
#pragma unroll
        for (int i = 0; i < 16; ++i) acc += wp[i] * sp[i];
    }
#pragma unroll
    for (int m = 2; m < 64; m <<= 1) acc += __shfl_xor(acc, m, 64);
    if (lane < 2) wsf2[(size_t)t * 96 + b * 2 + o] = acc;
}

// k_fc2s: fc2 LIF scan + delay-shift into out [B,2,T]. 96 active threads.
__global__ __launch_bounds__(128) void k_fc2s(const float* __restrict__ wsf2,
                                              float* __restrict__ out) {
    int tid = threadIdx.x;
    if (tid >= 96) return;
    float* ob = out + tid * 128;       // tid = b*2+o
    ob[0] = 0.0f;
    float u = 0.f, v = 0.f, rf = 0.f;
    float wbuf[8];
#pragma unroll
    for (int i = 0; i < 8; ++i) wbuf[i] = wsf2[(size_t)i * 96 + tid];
    for (int tb = 0; tb < 128; tb += 8) {
#pragma unroll
        for (int j = 0; j < 8; ++j) {
            int t = tb + j;
            float w = wbuf[j];
            if (t + 8 < 128) wbuf[j] = wsf2[(size_t)(t + 8) * 96 + tid];
            float s = dyn_step(w, u, v, rf);
            if (t < 127) ob[t + 1] = s;
        }
    }
}

// ---------------------------------------------------------------------------
extern "C" void kernel_launch(void* const* d_in, const int* in_sizes, int n_in,
                              void* d_out, int out_size, void* d_ws, size_t ws_size,
                              hipStream_t stream) {
    const float* in   = (const float*)d_in[0];
    const float* w1   = (const float*)d_in[1];
    const float* w2   = (const float*)d_in[2];
    const float* w3   = (const float*)d_in[3];
    const float* wfc1 = (const float*)d_in[4];
    const float* wfc2 = (const float*)d_in[5];
    float* out = (float*)d_out;
    char* ws = (char*)d_ws;

    float*          slab = (float*)(ws);                       // 56,623,104 (conv wsums; wsf1 reuse)
    uint2*          xb   = (uint2*)(ws + 56623104);            //  2,752,512
    unsigned short* pb16 = (unsigned short*)(ws + 59375616);   //  1,376,256
    unsigned short* pb2  = (unsigned short*)(ws + 60751872);   //  1,572,864
    float*          f1f  = (float*)(ws + 64094208);            // 12,582,912
    unsigned short* a3   = (unsigned short*)(ws + 76677120);   //  3,538,944 [6144][288] bf16
    unsigned short* wb   = (unsigned short*)(ws + 80216064);   //    884,736 [3][288][512] bf16
    unsigned short* st1  = (unsigned short*)(ws + 81100800);   //    884,736 [3456 waves][128] u16
    unsigned short* st2  = (unsigned short*)(ws + 81985536);   //    442,368 [1728 waves][128] u16
    unsigned short* st3  = (unsigned short*)(ws + 82427904);   //    221,184 [864 waves][128] u16
    float*          wsf1 = (float*)(ws);                       // 12,582,912 (slab reuse, post-scan3)
    float*          wsf2 = (float*)(ws + 16777216);            //     49,152 (slab reuse, disjoint)
    // total 82,649,088 bytes

    hipMemsetAsync(xb, 0, 2752512, stream);     // pad rows 0/27
    hipMemsetAsync(pb16, 0, 1376256, stream);   // pad rows 0/13
    hipMemsetAsync(pb2, 0, 1572864, stream);    // pad rows 0/7
    hipMemsetAsync(a3, 0, 27648, stream);       // A rows t=0 (48*288 bf16)

    k_wsplit  <<<576, 256, 0, stream>>>(wfc1, wb);
    k_masks   <<<624, 256, 0, stream>>>(in, xb);
    k_wsum1<0><<<768, 576, 0, stream>>>(xb, w1, slab);
    k_scan1<0><<<432, 256, 0, stream>>>(slab, st1);
    k_wsum1<1><<<768, 576, 0, stream>>>(xb, w1, slab);
    k_scan1<1><<<432, 256, 0, stream>>>(slab, st1);
    k_mb1     <<<2304, 256, 0, stream>>>(st1, pb16);
    k_wsum2   <<<768, 576, 0, stream>>>(pb16, w2, slab);
    k_scan2   <<<192, 576, 0, stream>>>(slab, st2);
    k_mb2     <<<2304, 256, 0, stream>>>(st2, pb2);
    k_wsum3   <<<768, 576, 0, stream>>>(pb2, w3, slab);
    k_scan3   <<<216, 256, 0, stream>>>(slab, st3);
    k_mb3     <<<6858, 256, 0, stream>>>(st3, a3);
    k_fc1mm   <<<768, 256, 0, stream>>>(a3, wb, wsf1);
    k_fc1s    <<<96, 256, 0, stream>>>(wsf1, f1f);
    k_fc2w    <<<1536, 256, 0, stream>>>(f1f, wfc2, wsf2);
    k_fc2s    <<<1, 128, 0, stream>>>(wsf2, out);
}